// Round 1
// baseline (1339.847 us; speedup 1.0000x reference)
//
#include <hip/hip_runtime.h>
#include <hip/hip_bf16.h>
#include <math.h>

// ---------------------------------------------------------------------------
// GAT 3-layer forward on MI355X.
// Strategy:
//   1. Build dest-CSR of (edges + self loops) in workspace (count/scan/scatter).
//   2. Per layer: tiled f32 GEMM xp = h @ W; small kernel for alpha_src/dst;
//      one-wave-per-node attention aggregation with online softmax (no atomics).
//   3. Final log_softmax over 10 classes.
// ---------------------------------------------------------------------------

#define LEAKY(v) ((v) > 0.f ? (v) : 0.2f * (v))

// ---------------- CSR build ----------------

__global__ void init_deg_k(int* deg, int N) {
    int i = blockIdx.x * blockDim.x + threadIdx.x;
    if (i < N) deg[i] = 1;  // self loop
}

__global__ void count_k(const int* __restrict__ dst, int E, int* deg) {
    int i = blockIdx.x * blockDim.x + threadIdx.x;
    if (i < E) atomicAdd(&deg[dst[i]], 1);
}

// exclusive scan, 1024 elements per block (256 threads x 4)
__global__ void scan1_k(const int* __restrict__ in, int* out, int* bsums, int N) {
    __shared__ int sh[256];
    int tid = threadIdx.x;
    int base = blockIdx.x * 1024 + tid * 4;
    int v[4]; int s = 0;
#pragma unroll
    for (int j = 0; j < 4; j++) { v[j] = (base + j < N) ? in[base + j] : 0; s += v[j]; }
    sh[tid] = s; __syncthreads();
    for (int off = 1; off < 256; off <<= 1) {
        int t = (tid >= off) ? sh[tid - off] : 0;
        __syncthreads();
        sh[tid] += t;
        __syncthreads();
    }
    int run = sh[tid] - s;  // exclusive prefix for this thread
#pragma unroll
    for (int j = 0; j < 4; j++) { if (base + j < N) out[base + j] = run; run += v[j]; }
    if (tid == 255) bsums[blockIdx.x] = sh[255];
}

__global__ void scan2_k(const int* __restrict__ bsums, int* boffs, int nb, int* total_out) {
    __shared__ int sh[256];
    int tid = threadIdx.x;
    int v = (tid < nb) ? bsums[tid] : 0;
    sh[tid] = v; __syncthreads();
    for (int off = 1; off < 256; off <<= 1) {
        int t = (tid >= off) ? sh[tid - off] : 0;
        __syncthreads();
        sh[tid] += t;
        __syncthreads();
    }
    if (tid < nb) boffs[tid] = sh[tid] - v;
    if (tid == 255) *total_out = sh[255];
}

__global__ void scan3_k(int* out, const int* __restrict__ boffs, int N) {
    int i = blockIdx.x * blockDim.x + threadIdx.x;
    if (i < N) out[i] += boffs[i >> 10];
}

__global__ void copy_k(const int* __restrict__ a, int* b, int N) {
    int i = blockIdx.x * blockDim.x + threadIdx.x;
    if (i < N) b[i] = a[i];
}

__global__ void scatter_edges_k(const int* __restrict__ src, const int* __restrict__ dst,
                                int E, int* cursor, int* cols) {
    int i = blockIdx.x * blockDim.x + threadIdx.x;
    if (i < E) {
        int d = dst[i];
        int p = atomicAdd(&cursor[d], 1);
        cols[p] = src[i];
    }
}

__global__ void scatter_loops_k(int N, int* cursor, int* cols) {
    int i = blockIdx.x * blockDim.x + threadIdx.x;
    if (i < N) {
        int p = atomicAdd(&cursor[i], 1);
        cols[p] = i;
    }
}

// ---------------- GEMM (f32, tiled, vector ALU) ----------------
// block = dim3(BN/TN, BM/TM); K must be a multiple of BK.
template <int BM, int BN, int BK, int TM, int TN>
__global__ void gemm_k(const float* __restrict__ A, const float* __restrict__ B,
                       float* __restrict__ C, int M, int Nc, int K) {
    __shared__ float As[BK][BM + 1];
    __shared__ float Bs[BK][BN + 1];
    int tx = threadIdx.x, ty = threadIdx.y;
    int tid = ty * blockDim.x + tx;
    const int nthreads = (BM / TM) * (BN / TN);
    int row0 = blockIdx.x * BM, col0 = blockIdx.y * BN;
    float acc[TM][TN];
#pragma unroll
    for (int i = 0; i < TM; i++)
#pragma unroll
        for (int j = 0; j < TN; j++) acc[i][j] = 0.f;

    for (int k0 = 0; k0 < K; k0 += BK) {
        for (int i = tid; i < BM * BK; i += nthreads) {
            int r = i / BK, kk = i % BK;
            int gr = row0 + r;
            As[kk][r] = (gr < M) ? A[(long)gr * K + (k0 + kk)] : 0.f;
        }
        for (int i = tid; i < BK * BN; i += nthreads) {
            int kk = i / BN, c = i % BN;
            int gc = col0 + c;
            Bs[kk][c] = (gc < Nc) ? B[(long)(k0 + kk) * Nc + gc] : 0.f;
        }
        __syncthreads();
#pragma unroll
        for (int kk = 0; kk < BK; ++kk) {
            float a[TM], b[TN];
#pragma unroll
            for (int i = 0; i < TM; i++) a[i] = As[kk][ty * TM + i];
#pragma unroll
            for (int j = 0; j < TN; j++) b[j] = Bs[kk][tx * TN + j];
#pragma unroll
            for (int i = 0; i < TM; i++)
#pragma unroll
                for (int j = 0; j < TN; j++) acc[i][j] = fmaf(a[i], b[j], acc[i][j]);
        }
        __syncthreads();
    }
#pragma unroll
    for (int i = 0; i < TM; i++) {
        int gr = row0 + ty * TM + i;
        if (gr >= M) continue;
#pragma unroll
        for (int j = 0; j < TN; j++) {
            int gc = col0 + tx * TN + j;
            if (gc < Nc) C[(long)gr * Nc + gc] = acc[i][j];
        }
    }
}

// ---------------- alpha_src / alpha_dst ----------------
template <int H, int C>
__global__ void alpha_k(const float* __restrict__ xp, const float* __restrict__ a_s,
                        const float* __restrict__ a_d, float* __restrict__ out_s,
                        float* __restrict__ out_d, int NH) {
    int i = blockIdx.x * blockDim.x + threadIdx.x;
    if (i >= NH) return;
    int h = i % H;
    const float* v = xp + (long)i * C;
    float ss = 0.f, sd = 0.f;
#pragma unroll
    for (int c = 0; c < C; c++) {
        float x = v[c];
        ss = fmaf(x, a_s[h * C + c], ss);
        sd = fmaf(x, a_d[h * C + c], sd);
    }
    out_s[i] = ss;
    out_d[i] = sd;
}

// ---------------- attention aggregation: one wave per node ----------------
template <int H, int C, bool DO_ELU>
__global__ void agg_k(const float* __restrict__ xp, const float* __restrict__ asrc,
                      const float* __restrict__ adst, const int* __restrict__ offs,
                      const int* __restrict__ cols, const float* __restrict__ bias,
                      float* __restrict__ out, int N) {
    constexpr int HC = H * C;
    constexpr int VPT = (HC + 63) / 64;
    int gtid = blockIdx.x * blockDim.x + threadIdx.x;
    int n = gtid >> 6;
    int lane = threadIdx.x & 63;
    if (n >= N) return;
    int start = offs[n], end = offs[n + 1];

    float ad[H];
#pragma unroll
    for (int h = 0; h < H; h++) ad[h] = adst[n * H + h];

    // phase 1: online softmax stats, edges striped across lanes
    float m[H], s[H];
#pragma unroll
    for (int h = 0; h < H; h++) { m[h] = -1e30f; s[h] = 0.f; }
    for (int e = start + lane; e < end; e += 64) {
        int src = cols[e];
#pragma unroll
        for (int h = 0; h < H; h++) {
            float v = asrc[src * H + h] + ad[h];
            v = LEAKY(v);
            float mo = fmaxf(m[h], v);
            s[h] = s[h] * __expf(m[h] - mo) + __expf(v - mo);
            m[h] = mo;
        }
    }
    // butterfly merge of (m, s) across the wave
#pragma unroll
    for (int off = 32; off >= 1; off >>= 1) {
#pragma unroll
        for (int h = 0; h < H; h++) {
            float mo = __shfl_xor(m[h], off, 64);
            float so = __shfl_xor(s[h], off, 64);
            float mn = fmaxf(m[h], mo);
            s[h] = s[h] * __expf(m[h] - mn) + so * __expf(mo - mn);
            m[h] = mn;
        }
    }

    // phase 2: weighted gather-accumulate, features striped across lanes
    float acc[VPT];
#pragma unroll
    for (int i = 0; i < VPT; i++) acc[i] = 0.f;
    for (int e = start; e < end; ++e) {
        int src = cols[e];
        long rowb = (long)src * HC;
#pragma unroll
        for (int i = 0; i < VPT; i++) {
            int hc = lane + 64 * i;
            if (hc < HC) {
                int h = hc / C;
                float v = asrc[src * H + h] + ad[h];
                v = LEAKY(v);
                float w = __expf(v - m[h]);
                acc[i] += w * xp[rowb + hc];
            }
        }
    }
#pragma unroll
    for (int i = 0; i < VPT; i++) {
        int hc = lane + 64 * i;
        if (hc < HC) {
            int h = hc / C;
            float o = acc[i] / (s[h] + 1e-16f) + bias[hc];
            if (DO_ELU) o = o > 0.f ? o : __expf(o) - 1.f;
            out[(long)n * HC + hc] = o;
        }
    }
}

// ---------------- log_softmax over 10 classes ----------------
__global__ void logsoftmax_k(const float* __restrict__ in, float* __restrict__ out, int N) {
    int n = blockIdx.x * blockDim.x + threadIdx.x;
    if (n >= N) return;
    float v[10];
    float mx = -1e30f;
#pragma unroll
    for (int j = 0; j < 10; j++) { v[j] = in[n * 10 + j]; mx = fmaxf(mx, v[j]); }
    float s = 0.f;
#pragma unroll
    for (int j = 0; j < 10; j++) s += __expf(v[j] - mx);
    float ls = __logf(s) + mx;
#pragma unroll
    for (int j = 0; j < 10; j++) out[n * 10 + j] = v[j] - ls;
}

// ---------------- launch ----------------

static inline size_t alignup(size_t x) { return (x + 255) & ~(size_t)255; }

extern "C" void kernel_launch(void* const* d_in, const int* in_sizes, int n_in,
                              void* d_out, int out_size, void* d_ws, size_t ws_size,
                              hipStream_t stream) {
    const float* x   = (const float*)d_in[0];
    const int*   ei  = (const int*)d_in[1];
    const float* W1  = (const float*)d_in[2];
    const float* a1s = (const float*)d_in[3];
    const float* a1d = (const float*)d_in[4];
    const float* b1  = (const float*)d_in[5];
    const float* W2  = (const float*)d_in[6];
    const float* a2s = (const float*)d_in[7];
    const float* a2d = (const float*)d_in[8];
    const float* b2  = (const float*)d_in[9];
    const float* W3  = (const float*)d_in[10];
    const float* a3s = (const float*)d_in[11];
    const float* a3d = (const float*)d_in[12];
    const float* b3  = (const float*)d_in[13];
    float* out = (float*)d_out;

    const int N = in_sizes[0] / 256;
    const int E = in_sizes[1] / 2;
    const int* src = ei;
    const int* dst = ei + E;

    char* p = (char*)d_ws;
    int* offs   = (int*)p; p += alignup(sizeof(int) * (size_t)(N + 1));
    int* cursor = (int*)p; p += alignup(sizeof(int) * (size_t)N);
    int* bsums  = (int*)p; p += alignup(sizeof(int) * 256);
    int* boffs  = (int*)p; p += alignup(sizeof(int) * 256);
    int* cols   = (int*)p; p += alignup(sizeof(int) * (size_t)(E + N));
    float* xp   = (float*)p; p += alignup(sizeof(float) * (size_t)N * 128);
    float* hbuf = (float*)p; p += alignup(sizeof(float) * (size_t)N * 128);
    float* as_  = (float*)p; p += alignup(sizeof(float) * (size_t)N * 8);
    float* ad_  = (float*)p; p += alignup(sizeof(float) * (size_t)N * 8);

    const int TB = 256;
    const int nb = (N + 1023) / 1024;

    // CSR build (dest-sorted adjacency, includes self loops)
    init_deg_k<<<(N + TB - 1) / TB, TB, 0, stream>>>(cursor, N);
    count_k<<<(E + TB - 1) / TB, TB, 0, stream>>>(dst, E, cursor);
    scan1_k<<<nb, 256, 0, stream>>>(cursor, offs, bsums, N);
    scan2_k<<<1, 256, 0, stream>>>(bsums, boffs, nb, offs + N);
    scan3_k<<<(N + TB - 1) / TB, TB, 0, stream>>>(offs, boffs, N);
    copy_k<<<(N + TB - 1) / TB, TB, 0, stream>>>(offs, cursor, N);
    scatter_edges_k<<<(E + TB - 1) / TB, TB, 0, stream>>>(src, dst, E, cursor, cols);
    scatter_loops_k<<<(N + TB - 1) / TB, TB, 0, stream>>>(N, cursor, cols);

    // ---- layer 1: 256 -> 128 (H=8, C=16), ELU
    gemm_k<128, 128, 16, 8, 8><<<dim3((N + 127) / 128, 1), dim3(16, 16), 0, stream>>>(
        x, W1, xp, N, 128, 256);
    alpha_k<8, 16><<<(N * 8 + TB - 1) / TB, TB, 0, stream>>>(xp, a1s, a1d, as_, ad_, N * 8);
    agg_k<8, 16, true><<<(N * 64 + TB - 1) / TB, TB, 0, stream>>>(
        xp, as_, ad_, offs, cols, b1, hbuf, N);

    // ---- layer 2: 128 -> 64 (H=8, C=8), ELU
    gemm_k<128, 64, 16, 8, 4><<<dim3((N + 127) / 128, 1), dim3(16, 16), 0, stream>>>(
        hbuf, W2, xp, N, 64, 128);
    alpha_k<8, 8><<<(N * 8 + TB - 1) / TB, TB, 0, stream>>>(xp, a2s, a2d, as_, ad_, N * 8);
    agg_k<8, 8, true><<<(N * 64 + TB - 1) / TB, TB, 0, stream>>>(
        xp, as_, ad_, offs, cols, b2, hbuf, N);

    // ---- layer 3: 64 -> 10 (H=1, C=10), no activation
    gemm_k<64, 16, 16, 4, 1><<<dim3((N + 63) / 64, 1), dim3(16, 16), 0, stream>>>(
        hbuf, W3, xp, N, 10, 64);
    alpha_k<1, 10><<<(N + TB - 1) / TB, TB, 0, stream>>>(xp, a3s, a3d, as_, ad_, N);
    agg_k<1, 10, false><<<(N * 64 + TB - 1) / TB, TB, 0, stream>>>(
        xp, as_, ad_, offs, cols, b3, hbuf, N);

    // ---- log_softmax
    logsoftmax_k<<<(N + TB - 1) / TB, TB, 0, stream>>>(hbuf, out, N);
}

// Round 2
// 992.699 us; speedup vs baseline: 1.3497x; 1.3497x over previous
//
#include <hip/hip_runtime.h>
#include <hip/hip_bf16.h>
#include <math.h>

// ---------------------------------------------------------------------------
// GAT 3-layer forward on MI355X.
//   1. Dest-CSR build (count/scan/scatter) in workspace.
//   2. Per layer: tiled f32 GEMM xp = h @ W; alpha_src/dst; wave-per-node
//      attention aggregation with cooperative weight computation:
//      phase 1 = 8 edge-slots x 8 heads online softmax (3-level shfl reduce),
//      phase 2 = per-chunk weights computed once, broadcast via ds_bpermute.
//   3. Final log_softmax over 10 classes.
// ---------------------------------------------------------------------------

#define LEAKY(v) ((v) > 0.f ? (v) : 0.2f * (v))

// ---------------- CSR build ----------------

__global__ void init_deg_k(int* deg, int N) {
    int i = blockIdx.x * blockDim.x + threadIdx.x;
    if (i < N) deg[i] = 1;  // self loop
}

__global__ void count_k(const int* __restrict__ dst, int E, int* deg) {
    int i = blockIdx.x * blockDim.x + threadIdx.x;
    if (i < E) atomicAdd(&deg[dst[i]], 1);
}

// exclusive scan, 1024 elements per block (256 threads x 4)
__global__ void scan1_k(const int* __restrict__ in, int* out, int* bsums, int N) {
    __shared__ int sh[256];
    int tid = threadIdx.x;
    int base = blockIdx.x * 1024 + tid * 4;
    int v[4]; int s = 0;
#pragma unroll
    for (int j = 0; j < 4; j++) { v[j] = (base + j < N) ? in[base + j] : 0; s += v[j]; }
    sh[tid] = s; __syncthreads();
    for (int off = 1; off < 256; off <<= 1) {
        int t = (tid >= off) ? sh[tid - off] : 0;
        __syncthreads();
        sh[tid] += t;
        __syncthreads();
    }
    int run = sh[tid] - s;  // exclusive prefix for this thread
#pragma unroll
    for (int j = 0; j < 4; j++) { if (base + j < N) out[base + j] = run; run += v[j]; }
    if (tid == 255) bsums[blockIdx.x] = sh[255];
}

__global__ void scan2_k(const int* __restrict__ bsums, int* boffs, int nb, int* total_out) {
    __shared__ int sh[256];
    int tid = threadIdx.x;
    int v = (tid < nb) ? bsums[tid] : 0;
    sh[tid] = v; __syncthreads();
    for (int off = 1; off < 256; off <<= 1) {
        int t = (tid >= off) ? sh[tid - off] : 0;
        __syncthreads();
        sh[tid] += t;
        __syncthreads();
    }
    if (tid < nb) boffs[tid] = sh[tid] - v;
    if (tid == 255) *total_out = sh[255];
}

__global__ void scan3_k(int* out, const int* __restrict__ boffs, int N) {
    int i = blockIdx.x * blockDim.x + threadIdx.x;
    if (i < N) out[i] += boffs[i >> 10];
}

__global__ void copy_k(const int* __restrict__ a, int* b, int N) {
    int i = blockIdx.x * blockDim.x + threadIdx.x;
    if (i < N) b[i] = a[i];
}

__global__ void scatter_edges_k(const int* __restrict__ src, const int* __restrict__ dst,
                                int E, int* cursor, int* cols) {
    int i = blockIdx.x * blockDim.x + threadIdx.x;
    if (i < E) {
        int d = dst[i];
        int p = atomicAdd(&cursor[d], 1);
        cols[p] = src[i];
    }
}

__global__ void scatter_loops_k(int N, int* cursor, int* cols) {
    int i = blockIdx.x * blockDim.x + threadIdx.x;
    if (i < N) {
        int p = atomicAdd(&cursor[i], 1);
        cols[p] = i;
    }
}

// ---------------- GEMM (f32, tiled, vector ALU) ----------------
template <int BM, int BN, int BK, int TM, int TN>
__global__ void gemm_k(const float* __restrict__ A, const float* __restrict__ B,
                       float* __restrict__ C, int M, int Nc, int K) {
    __shared__ float As[BK][BM + 1];
    __shared__ float Bs[BK][BN + 1];
    int tx = threadIdx.x, ty = threadIdx.y;
    int tid = ty * blockDim.x + tx;
    const int nthreads = (BM / TM) * (BN / TN);
    int row0 = blockIdx.x * BM, col0 = blockIdx.y * BN;
    float acc[TM][TN];
#pragma unroll
    for (int i = 0; i < TM; i++)
#pragma unroll
        for (int j = 0; j < TN; j++) acc[i][j] = 0.f;

    for (int k0 = 0; k0 < K; k0 += BK) {
        for (int i = tid; i < BM * BK; i += nthreads) {
            int r = i / BK, kk = i % BK;
            int gr = row0 + r;
            As[kk][r] = (gr < M) ? A[(long)gr * K + (k0 + kk)] : 0.f;
        }
        for (int i = tid; i < BK * BN; i += nthreads) {
            int kk = i / BN, c = i % BN;
            int gc = col0 + c;
            Bs[kk][c] = (gc < Nc) ? B[(long)(k0 + kk) * Nc + gc] : 0.f;
        }
        __syncthreads();
#pragma unroll
        for (int kk = 0; kk < BK; ++kk) {
            float a[TM], b[TN];
#pragma unroll
            for (int i = 0; i < TM; i++) a[i] = As[kk][ty * TM + i];
#pragma unroll
            for (int j = 0; j < TN; j++) b[j] = Bs[kk][tx * TN + j];
#pragma unroll
            for (int i = 0; i < TM; i++)
#pragma unroll
                for (int j = 0; j < TN; j++) acc[i][j] = fmaf(a[i], b[j], acc[i][j]);
        }
        __syncthreads();
    }
#pragma unroll
    for (int i = 0; i < TM; i++) {
        int gr = row0 + ty * TM + i;
        if (gr >= M) continue;
#pragma unroll
        for (int j = 0; j < TN; j++) {
            int gc = col0 + tx * TN + j;
            if (gc < Nc) C[(long)gr * Nc + gc] = acc[i][j];
        }
    }
}

// ---------------- alpha_src / alpha_dst ----------------
template <int H, int C>
__global__ void alpha_k(const float* __restrict__ xp, const float* __restrict__ a_s,
                        const float* __restrict__ a_d, float* __restrict__ out_s,
                        float* __restrict__ out_d, int NH) {
    int i = blockIdx.x * blockDim.x + threadIdx.x;
    if (i >= NH) return;
    int h = i % H;
    const float* v = xp + (long)i * C;
    float ss = 0.f, sd = 0.f;
#pragma unroll
    for (int c = 0; c < C; c++) {
        float x = v[c];
        ss = fmaf(x, a_s[h * C + c], ss);
        sd = fmaf(x, a_d[h * C + c], sd);
    }
    out_s[i] = ss;
    out_d[i] = sd;
}

// ---------------- attention aggregation, H=8: one wave per node ----------------
// Phase 1: lane = j*8 + h, 8 edge-slots x 8 heads. Phase 2: per 8-edge chunk,
// weight lanes compute normalized w once; feature lanes bpermute it.
template <int C, bool DO_ELU>
__global__ void agg8_k(const float* __restrict__ xp, const float* __restrict__ asrc,
                       const float* __restrict__ adst, const int* __restrict__ offs,
                       const int* __restrict__ cols, const float* __restrict__ bias,
                       float* __restrict__ out, int N) {
    constexpr int HC = 8 * C;
    constexpr int VPL = HC / 64;  // floats per lane: 2 (C=16) or 1 (C=8)
    int gtid = blockIdx.x * blockDim.x + threadIdx.x;
    int n = gtid >> 6;
    if (n >= N) return;
    int lane = threadIdx.x & 63;
    int j = lane >> 3, h = lane & 7;
    int start = offs[n], end = offs[n + 1];

    float ad_l = adst[n * 8 + h];

    // phase 1: online softmax stats for head h over edge-slots j, j+8, ...
    float m = -1e30f, s = 0.f;
    for (int e = start + j; e < end; e += 8) {
        int src = cols[e];
        float v = asrc[src * 8 + h] + ad_l;
        v = LEAKY(v);
        float mo = fmaxf(m, v);
        s = s * __expf(m - mo) + __expf(v - mo);
        m = mo;
    }
#pragma unroll
    for (int off = 8; off <= 32; off <<= 1) {
        float mo = __shfl_xor(m, off, 64);
        float so = __shfl_xor(s, off, 64);
        float mn = fmaxf(m, mo);
        s = s * __expf(m - mn) + so * __expf(mo - mn);
        m = mn;
    }
    float rs = 1.f / (s + 1e-16f);

    // phase 2: feature lane owns feats [lane*VPL, lane*VPL+VPL); head = h2
    int h2 = (lane * VPL) / C;
    float acc[VPL];
#pragma unroll
    for (int i = 0; i < VPL; i++) acc[i] = 0.f;

    for (int c0 = start; c0 < end; c0 += 8) {
        int e = c0 + j;
        float w_l = 0.f; int src_l = 0;
        if (e < end) {
            src_l = cols[e];
            float v = asrc[src_l * 8 + h] + ad_l;
            v = LEAKY(v);
            w_l = __expf(v - m) * rs;  // normalized weight for edge e, head h
        }
        int nj = end - c0; if (nj > 8) nj = 8;
        if (nj == 8) {
#pragma unroll
            for (int j2 = 0; j2 < 8; j2++) {
                int srcj = __shfl(src_l, j2 * 8, 64);
                float w = __shfl(w_l, j2 * 8 + h2, 64);
                if (VPL == 2) {
                    const float2* row = (const float2*)(xp + (long)srcj * HC) + lane;
                    float2 v2 = *row;
                    acc[0] = fmaf(w, v2.x, acc[0]);
                    acc[VPL - 1] = fmaf(w, v2.y, acc[VPL - 1]);
                } else {
                    acc[0] = fmaf(w, xp[(long)srcj * HC + lane], acc[0]);
                }
            }
        } else {
            for (int j2 = 0; j2 < nj; j2++) {
                int srcj = __shfl(src_l, j2 * 8, 64);
                float w = __shfl(w_l, j2 * 8 + h2, 64);
                if (VPL == 2) {
                    const float2* row = (const float2*)(xp + (long)srcj * HC) + lane;
                    float2 v2 = *row;
                    acc[0] = fmaf(w, v2.x, acc[0]);
                    acc[VPL - 1] = fmaf(w, v2.y, acc[VPL - 1]);
                } else {
                    acc[0] = fmaf(w, xp[(long)srcj * HC + lane], acc[0]);
                }
            }
        }
    }
#pragma unroll
    for (int i = 0; i < VPL; i++) {
        int hc = lane * VPL + i;
        float o = acc[i] + bias[hc];
        if (DO_ELU) o = o > 0.f ? o : __expf(o) - 1.f;
        out[(long)n * HC + hc] = o;
    }
}

// ---------------- attention aggregation, H=1 C=10 (layer 3) ----------------
__global__ void agg1h_k(const float* __restrict__ xp, const float* __restrict__ asrc,
                        const float* __restrict__ adst, const int* __restrict__ offs,
                        const int* __restrict__ cols, const float* __restrict__ bias,
                        float* __restrict__ out, int N) {
    int gtid = blockIdx.x * blockDim.x + threadIdx.x;
    int n = gtid >> 6;
    if (n >= N) return;
    int lane = threadIdx.x & 63;
    int start = offs[n], end = offs[n + 1];
    float ad = adst[n];

    // phase 1: edges striped over all 64 lanes
    float m = -1e30f, s = 0.f;
    for (int e = start + lane; e < end; e += 64) {
        float v = asrc[cols[e]] + ad;
        v = LEAKY(v);
        float mo = fmaxf(m, v);
        s = s * __expf(m - mo) + __expf(v - mo);
        m = mo;
    }
#pragma unroll
    for (int off = 1; off <= 32; off <<= 1) {
        float mo = __shfl_xor(m, off, 64);
        float so = __shfl_xor(s, off, 64);
        float mn = fmaxf(m, mo);
        s = s * __expf(m - mn) + so * __expf(mo - mn);
        m = mn;
    }
    float rs = 1.f / (s + 1e-16f);

    // phase 2: 6 edges x 10 features per iteration (lanes 60-63 idle)
    int j = lane / 10, c = lane - j * 10;
    float acc = 0.f;
    for (int c0 = start; c0 < end; c0 += 6) {
        int e = c0 + j;
        if (j < 6 && e < end) {
            int src = cols[e];
            float v = asrc[src] + ad;
            v = LEAKY(v);
            float w = __expf(v - m) * rs;
            acc = fmaf(w, xp[src * 10 + c], acc);
        }
    }
    float tot = acc;
#pragma unroll
    for (int k = 1; k < 6; k++) tot += __shfl(acc, lane + 10 * k, 64);
    if (lane < 10) out[n * 10 + lane] = tot + bias[lane];
}

// ---------------- log_softmax over 10 classes ----------------
__global__ void logsoftmax_k(const float* __restrict__ in, float* __restrict__ out, int N) {
    int n = blockIdx.x * blockDim.x + threadIdx.x;
    if (n >= N) return;
    float v[10];
    float mx = -1e30f;
#pragma unroll
    for (int j = 0; j < 10; j++) { v[j] = in[n * 10 + j]; mx = fmaxf(mx, v[j]); }
    float s = 0.f;
#pragma unroll
    for (int j = 0; j < 10; j++) s += __expf(v[j] - mx);
    float ls = __logf(s) + mx;
#pragma unroll
    for (int j = 0; j < 10; j++) out[n * 10 + j] = v[j] - ls;
}

// ---------------- launch ----------------

static inline size_t alignup(size_t x) { return (x + 255) & ~(size_t)255; }

extern "C" void kernel_launch(void* const* d_in, const int* in_sizes, int n_in,
                              void* d_out, int out_size, void* d_ws, size_t ws_size,
                              hipStream_t stream) {
    const float* x   = (const float*)d_in[0];
    const int*   ei  = (const int*)d_in[1];
    const float* W1  = (const float*)d_in[2];
    const float* a1s = (const float*)d_in[3];
    const float* a1d = (const float*)d_in[4];
    const float* b1  = (const float*)d_in[5];
    const float* W2  = (const float*)d_in[6];
    const float* a2s = (const float*)d_in[7];
    const float* a2d = (const float*)d_in[8];
    const float* b2  = (const float*)d_in[9];
    const float* W3  = (const float*)d_in[10];
    const float* a3s = (const float*)d_in[11];
    const float* a3d = (const float*)d_in[12];
    const float* b3  = (const float*)d_in[13];
    float* out = (float*)d_out;

    const int N = in_sizes[0] / 256;
    const int E = in_sizes[1] / 2;
    const int* src = ei;
    const int* dst = ei + E;

    char* p = (char*)d_ws;
    int* offs   = (int*)p; p += alignup(sizeof(int) * (size_t)(N + 1));
    int* cursor = (int*)p; p += alignup(sizeof(int) * (size_t)N);
    int* bsums  = (int*)p; p += alignup(sizeof(int) * 256);
    int* boffs  = (int*)p; p += alignup(sizeof(int) * 256);
    int* cols   = (int*)p; p += alignup(sizeof(int) * (size_t)(E + N));
    float* xp   = (float*)p; p += alignup(sizeof(float) * (size_t)N * 128);
    float* hbuf = (float*)p; p += alignup(sizeof(float) * (size_t)N * 128);
    float* as_  = (float*)p; p += alignup(sizeof(float) * (size_t)N * 8);
    float* ad_  = (float*)p; p += alignup(sizeof(float) * (size_t)N * 8);

    const int TB = 256;
    const int nb = (N + 1023) / 1024;

    // CSR build (dest-sorted adjacency, includes self loops)
    init_deg_k<<<(N + TB - 1) / TB, TB, 0, stream>>>(cursor, N);
    count_k<<<(E + TB - 1) / TB, TB, 0, stream>>>(dst, E, cursor);
    scan1_k<<<nb, 256, 0, stream>>>(cursor, offs, bsums, N);
    scan2_k<<<1, 256, 0, stream>>>(bsums, boffs, nb, offs + N);
    scan3_k<<<(N + TB - 1) / TB, TB, 0, stream>>>(offs, boffs, N);
    copy_k<<<(N + TB - 1) / TB, TB, 0, stream>>>(offs, cursor, N);
    scatter_edges_k<<<(E + TB - 1) / TB, TB, 0, stream>>>(src, dst, E, cursor, cols);
    scatter_loops_k<<<(N + TB - 1) / TB, TB, 0, stream>>>(N, cursor, cols);

    // ---- layer 1: 256 -> 128 (H=8, C=16), ELU
    gemm_k<128, 128, 16, 8, 8><<<dim3((N + 127) / 128, 1), dim3(16, 16), 0, stream>>>(
        x, W1, xp, N, 128, 256);
    alpha_k<8, 16><<<(N * 8 + TB - 1) / TB, TB, 0, stream>>>(xp, a1s, a1d, as_, ad_, N * 8);
    agg8_k<16, true><<<(N * 64 + TB - 1) / TB, TB, 0, stream>>>(
        xp, as_, ad_, offs, cols, b1, hbuf, N);

    // ---- layer 2: 128 -> 64 (H=8, C=8), ELU
    gemm_k<128, 64, 16, 8, 4><<<dim3((N + 127) / 128, 1), dim3(16, 16), 0, stream>>>(
        hbuf, W2, xp, N, 64, 128);
    alpha_k<8, 8><<<(N * 8 + TB - 1) / TB, TB, 0, stream>>>(xp, a2s, a2d, as_, ad_, N * 8);
    agg8_k<8, true><<<(N * 64 + TB - 1) / TB, TB, 0, stream>>>(
        xp, as_, ad_, offs, cols, b2, hbuf, N);

    // ---- layer 3: 64 -> 10 (H=1, C=10), no activation
    gemm_k<64, 16, 16, 4, 1><<<dim3((N + 63) / 64, 1), dim3(16, 16), 0, stream>>>(
        hbuf, W3, xp, N, 10, 64);
    alpha_k<1, 10><<<(N + TB - 1) / TB, TB, 0, stream>>>(xp, a3s, a3d, as_, ad_, N);
    agg1h_k<<<(N * 64 + TB - 1) / TB, TB, 0, stream>>>(
        xp, as_, ad_, offs, cols, b3, hbuf, N);

    // ---- log_softmax
    logsoftmax_k<<<(N + TB - 1) / TB, TB, 0, stream>>>(hbuf, out, N);
}

// Round 3
// 782.007 us; speedup vs baseline: 1.7133x; 1.2694x over previous
//
#include <hip/hip_runtime.h>
#include <hip/hip_bf16.h>
#include <math.h>

// ---------------------------------------------------------------------------
// GAT 3-layer forward on MI355X.
//   1. Dest-CSR build (count/scan/scatter) in workspace.
//   2. Layers 1/2: split-bf16 MFMA GEMM (A=Ah+Al, B=Bh+Bl; AhBh+AlBh+AhBl
//      => fp32-level accuracy at MFMA rate). Layer 3 stays f32 vector (tiny).
//   3. Wave-per-node attention aggregation (cooperative weights, shfl bcast).
//   4. Final log_softmax over 10 classes.
// ---------------------------------------------------------------------------

#define LEAKY(v) ((v) > 0.f ? (v) : 0.2f * (v))

typedef __bf16 bf16_t;
typedef __bf16 bf16x8 __attribute__((ext_vector_type(8)));
typedef __bf16 bf16x4 __attribute__((ext_vector_type(4)));
typedef float f32x4 __attribute__((ext_vector_type(4)));

// ---------------- CSR build ----------------

__global__ void init_deg_k(int* deg, int N) {
    int i = blockIdx.x * blockDim.x + threadIdx.x;
    if (i < N) deg[i] = 1;  // self loop
}

__global__ void count_k(const int* __restrict__ dst, int E, int* deg) {
    int i = blockIdx.x * blockDim.x + threadIdx.x;
    if (i < E) atomicAdd(&deg[dst[i]], 1);
}

// exclusive scan, 1024 elements per block (256 threads x 4)
__global__ void scan1_k(const int* __restrict__ in, int* out, int* bsums, int N) {
    __shared__ int sh[256];
    int tid = threadIdx.x;
    int base = blockIdx.x * 1024 + tid * 4;
    int v[4]; int s = 0;
#pragma unroll
    for (int j = 0; j < 4; j++) { v[j] = (base + j < N) ? in[base + j] : 0; s += v[j]; }
    sh[tid] = s; __syncthreads();
    for (int off = 1; off < 256; off <<= 1) {
        int t = (tid >= off) ? sh[tid - off] : 0;
        __syncthreads();
        sh[tid] += t;
        __syncthreads();
    }
    int run = sh[tid] - s;
#pragma unroll
    for (int j = 0; j < 4; j++) { if (base + j < N) out[base + j] = run; run += v[j]; }
    if (tid == 255) bsums[blockIdx.x] = sh[255];
}

__global__ void scan2_k(const int* __restrict__ bsums, int* boffs, int nb, int* total_out) {
    __shared__ int sh[256];
    int tid = threadIdx.x;
    int v = (tid < nb) ? bsums[tid] : 0;
    sh[tid] = v; __syncthreads();
    for (int off = 1; off < 256; off <<= 1) {
        int t = (tid >= off) ? sh[tid - off] : 0;
        __syncthreads();
        sh[tid] += t;
        __syncthreads();
    }
    if (tid < nb) boffs[tid] = sh[tid] - v;
    if (tid == 255) *total_out = sh[255];
}

__global__ void scan3_k(int* out, const int* __restrict__ boffs, int N) {
    int i = blockIdx.x * blockDim.x + threadIdx.x;
    if (i < N) out[i] += boffs[i >> 10];
}

__global__ void copy_k(const int* __restrict__ a, int* b, int N) {
    int i = blockIdx.x * blockDim.x + threadIdx.x;
    if (i < N) b[i] = a[i];
}

__global__ void scatter_edges_k(const int* __restrict__ src, const int* __restrict__ dst,
                                int E, int* cursor, int* cols) {
    int i = blockIdx.x * blockDim.x + threadIdx.x;
    if (i < E) {
        int d = dst[i];
        int p = atomicAdd(&cursor[d], 1);
        cols[p] = src[i];
    }
}

__global__ void scatter_loops_k(int N, int* cursor, int* cols) {
    int i = blockIdx.x * blockDim.x + threadIdx.x;
    if (i < N) {
        int p = atomicAdd(&cursor[i], 1);
        cols[p] = i;
    }
}

// ---------------- W pre-pack into MFMA B-fragment order (hi|lo) ----------------
// Fragment layout for mfma_f32_16x16x32_bf16 B-operand (B^T = NxK):
// lane = quad*16 + nl holds B^T[n = ntile*16+nl][k = kstep*32 + quad*8 + j], j=0..7.
// Storage: Bf[((kstep*NT + ntile)*64 + lane)*16] = 8 hi then 8 lo.
__global__ void prep_w_k(const float* __restrict__ W, short* __restrict__ Bfs,
                         int K, int N, int NT, int total) {
    int idx = blockIdx.x * blockDim.x + threadIdx.x;
    if (idx >= total) return;  // total = (K/32)*NT*64
    int lane = idx & 63;
    int t = idx >> 6;
    int ntile = t % NT, kstep = t / NT;
    int quad = lane >> 4, nl = lane & 15;
    int n = ntile * 16 + nl;
    bf16_t* dst = (bf16_t*)Bfs + (size_t)idx * 16;
#pragma unroll
    for (int j = 0; j < 8; j++) {
        int k = kstep * 32 + quad * 8 + j;
        float v = W[k * N + n];
        bf16_t h = (bf16_t)v;
        bf16_t l = (bf16_t)(v - (float)h);
        dst[j] = h;
        dst[8 + j] = l;
    }
}

// ---------------- split-bf16 MFMA GEMM ----------------
// C[M,N] = A[M,K] @ W[K,N], W pre-packed as Bf. BK=32 per step, 3 MFMAs/tile
// (hi*hi + lo*hi + hi*lo). 4 waves: NWM x (4/NWM) arrangement, wave tile
// (WMT*16) x (WNT*16).
template <int BM, int WMT, int WNT, int NWM>
__global__ __launch_bounds__(256) void mfma_gemm_k(
        const float* __restrict__ A, const short* __restrict__ Bfs,
        float* __restrict__ C, int M, int N, int K, int NT) {
    constexpr int NWN = 4 / NWM;
    constexpr int BN = 16 * WNT * NWN;
    constexpr int KPAD = 40;  // 32 + 8: breaks LDS bank aliasing on b128 reads
    __shared__ __align__(16) bf16_t As_hi[BM * KPAD];
    __shared__ __align__(16) bf16_t As_lo[BM * KPAD];
    const bf16_t* Bf = (const bf16_t*)Bfs;

    int tid = threadIdx.x;
    int wave = tid >> 6, lane = tid & 63;
    int quad = lane >> 4, l16 = lane & 15;
    int wm = wave % NWM, wn = wave / NWM;
    int row0 = blockIdx.x * BM;
    int ntile0 = blockIdx.y * (BN / 16) + wn * WNT;

    f32x4 acc[WMT][WNT];
#pragma unroll
    for (int i = 0; i < WMT; i++)
#pragma unroll
        for (int j = 0; j < WNT; j++) acc[i][j] = (f32x4){0.f, 0.f, 0.f, 0.f};

    const int nk = K >> 5;
    const int rA = tid >> 3, kq = tid & 7;  // 8 threads/row, 32 rows/pass

    for (int ks = 0; ks < nk; ks++) {
        // stage A tile (BM x 32 f32) -> split hi/lo bf16 in LDS
#pragma unroll
        for (int rr = rA; rr < BM; rr += 32) {
            int grow = row0 + rr;
            f32x4 v = (f32x4){0.f, 0.f, 0.f, 0.f};
            if (grow < M)
                v = *(const f32x4*)(A + (size_t)grow * K + ks * 32 + kq * 4);
            bf16x4 h, l;
#pragma unroll
            for (int j = 0; j < 4; j++) {
                bf16_t hh = (bf16_t)v[j];
                h[j] = hh;
                l[j] = (bf16_t)(v[j] - (float)hh);
            }
            *(bf16x4*)&As_hi[rr * KPAD + kq * 4] = h;
            *(bf16x4*)&As_lo[rr * KPAD + kq * 4] = l;
        }
        __syncthreads();

        bf16x8 ah[WMT], al[WMT];
#pragma unroll
        for (int i = 0; i < WMT; i++) {
            int rowl = wm * (WMT * 16) + i * 16 + l16;
            ah[i] = *(const bf16x8*)&As_hi[rowl * KPAD + quad * 8];
            al[i] = *(const bf16x8*)&As_lo[rowl * KPAD + quad * 8];
        }
        bf16x8 bh[WNT], bl[WNT];
#pragma unroll
        for (int j = 0; j < WNT; j++) {
            size_t base = ((size_t)(ks * NT + ntile0 + j) * 64 + lane) * 16;
            bh[j] = *(const bf16x8*)&Bf[base];
            bl[j] = *(const bf16x8*)&Bf[base + 8];
        }
#pragma unroll
        for (int i = 0; i < WMT; i++)
#pragma unroll
            for (int j = 0; j < WNT; j++) {
                acc[i][j] = __builtin_amdgcn_mfma_f32_16x16x32_bf16(ah[i], bh[j], acc[i][j], 0, 0, 0);
                acc[i][j] = __builtin_amdgcn_mfma_f32_16x16x32_bf16(al[i], bh[j], acc[i][j], 0, 0, 0);
                acc[i][j] = __builtin_amdgcn_mfma_f32_16x16x32_bf16(ah[i], bl[j], acc[i][j], 0, 0, 0);
            }
        __syncthreads();
    }

    // store: D[row = quad*4 + r][col = l16] per 16x16 tile
#pragma unroll
    for (int i = 0; i < WMT; i++) {
        int rbase = row0 + wm * (WMT * 16) + i * 16 + quad * 4;
#pragma unroll
        for (int j = 0; j < WNT; j++) {
            int gcol = (ntile0 + j) * 16 + l16;
#pragma unroll
            for (int r2 = 0; r2 < 4; r2++) {
                int grow = rbase + r2;
                if (grow < M) C[(size_t)grow * N + gcol] = acc[i][j][r2];
            }
        }
    }
}

// ---------------- GEMM (f32, tiled, vector ALU) — layer 3 only ----------------
template <int BM, int BN, int BK, int TM, int TN>
__global__ void gemm_k(const float* __restrict__ A, const float* __restrict__ B,
                       float* __restrict__ C, int M, int Nc, int K) {
    __shared__ float As[BK][BM + 1];
    __shared__ float Bs[BK][BN + 1];
    int tx = threadIdx.x, ty = threadIdx.y;
    int tid = ty * blockDim.x + tx;
    const int nthreads = (BM / TM) * (BN / TN);
    int row0 = blockIdx.x * BM, col0 = blockIdx.y * BN;
    float acc[TM][TN];
#pragma unroll
    for (int i = 0; i < TM; i++)
#pragma unroll
        for (int j = 0; j < TN; j++) acc[i][j] = 0.f;

    for (int k0 = 0; k0 < K; k0 += BK) {
        for (int i = tid; i < BM * BK; i += nthreads) {
            int r = i / BK, kk = i % BK;
            int gr = row0 + r;
            As[kk][r] = (gr < M) ? A[(long)gr * K + (k0 + kk)] : 0.f;
        }
        for (int i = tid; i < BK * BN; i += nthreads) {
            int kk = i / BN, c = i % BN;
            int gc = col0 + c;
            Bs[kk][c] = (gc < Nc) ? B[(long)(k0 + kk) * Nc + gc] : 0.f;
        }
        __syncthreads();
#pragma unroll
        for (int kk = 0; kk < BK; ++kk) {
            float a[TM], b[TN];
#pragma unroll
            for (int i = 0; i < TM; i++) a[i] = As[kk][ty * TM + i];
#pragma unroll
            for (int j = 0; j < TN; j++) b[j] = Bs[kk][tx * TN + j];
#pragma unroll
            for (int i = 0; i < TM; i++)
#pragma unroll
                for (int j = 0; j < TN; j++) acc[i][j] = fmaf(a[i], b[j], acc[i][j]);
        }
        __syncthreads();
    }
#pragma unroll
    for (int i = 0; i < TM; i++) {
        int gr = row0 + ty * TM + i;
        if (gr >= M) continue;
#pragma unroll
        for (int j = 0; j < TN; j++) {
            int gc = col0 + tx * TN + j;
            if (gc < Nc) C[(long)gr * Nc + gc] = acc[i][j];
        }
    }
}

// ---------------- alpha_src / alpha_dst ----------------
template <int H, int C>
__global__ void alpha_k(const float* __restrict__ xp, const float* __restrict__ a_s,
                        const float* __restrict__ a_d, float* __restrict__ out_s,
                        float* __restrict__ out_d, int NH) {
    int i = blockIdx.x * blockDim.x + threadIdx.x;
    if (i >= NH) return;
    int h = i % H;
    const float* v = xp + (long)i * C;
    float ss = 0.f, sd = 0.f;
#pragma unroll
    for (int c = 0; c < C; c++) {
        float x = v[c];
        ss = fmaf(x, a_s[h * C + c], ss);
        sd = fmaf(x, a_d[h * C + c], sd);
    }
    out_s[i] = ss;
    out_d[i] = sd;
}

// ---------------- attention aggregation, H=8: one wave per node ----------------
template <int C, bool DO_ELU>
__global__ void agg8_k(const float* __restrict__ xp, const float* __restrict__ asrc,
                       const float* __restrict__ adst, const int* __restrict__ offs,
                       const int* __restrict__ cols, const float* __restrict__ bias,
                       float* __restrict__ out, int N) {
    constexpr int HC = 8 * C;
    constexpr int VPL = HC / 64;  // floats per lane: 2 (C=16) or 1 (C=8)
    int gtid = blockIdx.x * blockDim.x + threadIdx.x;
    int n = gtid >> 6;
    if (n >= N) return;
    int lane = threadIdx.x & 63;
    int j = lane >> 3, h = lane & 7;
    int start = offs[n], end = offs[n + 1];

    float ad_l = adst[n * 8 + h];

    // phase 1: online softmax stats for head h over edge-slots j, j+8, ...
    float m = -1e30f, s = 0.f;
    for (int e = start + j; e < end; e += 8) {
        int src = cols[e];
        float v = asrc[src * 8 + h] + ad_l;
        v = LEAKY(v);
        float mo = fmaxf(m, v);
        s = s * __expf(m - mo) + __expf(v - mo);
        m = mo;
    }
#pragma unroll
    for (int off = 8; off <= 32; off <<= 1) {
        float mo = __shfl_xor(m, off, 64);
        float so = __shfl_xor(s, off, 64);
        float mn = fmaxf(m, mo);
        s = s * __expf(m - mn) + so * __expf(mo - mn);
        m = mn;
    }
    float rs = 1.f / (s + 1e-16f);

    // phase 2: feature lane owns feats [lane*VPL, lane*VPL+VPL); head = h2
    int h2 = (lane * VPL) / C;
    float acc[VPL];
#pragma unroll
    for (int i = 0; i < VPL; i++) acc[i] = 0.f;

    for (int c0 = start; c0 < end; c0 += 8) {
        int e = c0 + j;
        float w_l = 0.f; int src_l = 0;
        if (e < end) {
            src_l = cols[e];
            float v = asrc[src_l * 8 + h] + ad_l;
            v = LEAKY(v);
            w_l = __expf(v - m) * rs;
        }
        int nj = end - c0; if (nj > 8) nj = 8;
        if (nj == 8) {
#pragma unroll
            for (int j2 = 0; j2 < 8; j2++) {
                int srcj = __shfl(src_l, j2 * 8, 64);
                float w = __shfl(w_l, j2 * 8 + h2, 64);
                if (VPL == 2) {
                    const float2* row = (const float2*)(xp + (long)srcj * HC) + lane;
                    float2 v2 = *row;
                    acc[0] = fmaf(w, v2.x, acc[0]);
                    acc[VPL - 1] = fmaf(w, v2.y, acc[VPL - 1]);
                } else {
                    acc[0] = fmaf(w, xp[(long)srcj * HC + lane], acc[0]);
                }
            }
        } else {
            for (int j2 = 0; j2 < nj; j2++) {
                int srcj = __shfl(src_l, j2 * 8, 64);
                float w = __shfl(w_l, j2 * 8 + h2, 64);
                if (VPL == 2) {
                    const float2* row = (const float2*)(xp + (long)srcj * HC) + lane;
                    float2 v2 = *row;
                    acc[0] = fmaf(w, v2.x, acc[0]);
                    acc[VPL - 1] = fmaf(w, v2.y, acc[VPL - 1]);
                } else {
                    acc[0] = fmaf(w, xp[(long)srcj * HC + lane], acc[0]);
                }
            }
        }
    }
#pragma unroll
    for (int i = 0; i < VPL; i++) {
        int hc = lane * VPL + i;
        float o = acc[i] + bias[hc];
        if (DO_ELU) o = o > 0.f ? o : __expf(o) - 1.f;
        out[(long)n * HC + hc] = o;
    }
}

// ---------------- attention aggregation, H=1 C=10 (layer 3) ----------------
__global__ void agg1h_k(const float* __restrict__ xp, const float* __restrict__ asrc,
                        const float* __restrict__ adst, const int* __restrict__ offs,
                        const int* __restrict__ cols, const float* __restrict__ bias,
                        float* __restrict__ out, int N) {
    int gtid = blockIdx.x * blockDim.x + threadIdx.x;
    int n = gtid >> 6;
    if (n >= N) return;
    int lane = threadIdx.x & 63;
    int start = offs[n], end = offs[n + 1];
    float ad = adst[n];

    float m = -1e30f, s = 0.f;
    for (int e = start + lane; e < end; e += 64) {
        float v = asrc[cols[e]] + ad;
        v = LEAKY(v);
        float mo = fmaxf(m, v);
        s = s * __expf(m - mo) + __expf(v - mo);
        m = mo;
    }
#pragma unroll
    for (int off = 1; off <= 32; off <<= 1) {
        float mo = __shfl_xor(m, off, 64);
        float so = __shfl_xor(s, off, 64);
        float mn = fmaxf(m, mo);
        s = s * __expf(m - mn) + so * __expf(mo - mn);
        m = mn;
    }
    float rs = 1.f / (s + 1e-16f);

    int j = lane / 10, c = lane - j * 10;
    float acc = 0.f;
    for (int c0 = start; c0 < end; c0 += 6) {
        int e = c0 + j;
        if (j < 6 && e < end) {
            int src = cols[e];
            float v = asrc[src] + ad;
            v = LEAKY(v);
            float w = __expf(v - m) * rs;
            acc = fmaf(w, xp[src * 10 + c], acc);
        }
    }
    float tot = acc;
#pragma unroll
    for (int k = 1; k < 6; k++) tot += __shfl(acc, lane + 10 * k, 64);
    if (lane < 10) out[n * 10 + lane] = tot + bias[lane];
}

// ---------------- log_softmax over 10 classes ----------------
__global__ void logsoftmax_k(const float* __restrict__ in, float* __restrict__ out, int N) {
    int n = blockIdx.x * blockDim.x + threadIdx.x;
    if (n >= N) return;
    float v[10];
    float mx = -1e30f;
#pragma unroll
    for (int j = 0; j < 10; j++) { v[j] = in[n * 10 + j]; mx = fmaxf(mx, v[j]); }
    float s = 0.f;
#pragma unroll
    for (int j = 0; j < 10; j++) s += __expf(v[j] - mx);
    float ls = __logf(s) + mx;
#pragma unroll
    for (int j = 0; j < 10; j++) out[n * 10 + j] = v[j] - ls;
}

// ---------------- launch ----------------

static inline size_t alignup(size_t x) { return (x + 255) & ~(size_t)255; }

extern "C" void kernel_launch(void* const* d_in, const int* in_sizes, int n_in,
                              void* d_out, int out_size, void* d_ws, size_t ws_size,
                              hipStream_t stream) {
    const float* x   = (const float*)d_in[0];
    const int*   ei  = (const int*)d_in[1];
    const float* W1  = (const float*)d_in[2];
    const float* a1s = (const float*)d_in[3];
    const float* a1d = (const float*)d_in[4];
    const float* b1  = (const float*)d_in[5];
    const float* W2  = (const float*)d_in[6];
    const float* a2s = (const float*)d_in[7];
    const float* a2d = (const float*)d_in[8];
    const float* b2  = (const float*)d_in[9];
    const float* W3  = (const float*)d_in[10];
    const float* a3s = (const float*)d_in[11];
    const float* a3d = (const float*)d_in[12];
    const float* b3  = (const float*)d_in[13];
    float* out = (float*)d_out;

    const int N = in_sizes[0] / 256;
    const int E = in_sizes[1] / 2;
    const int* src = ei;
    const int* dst = ei + E;

    char* p = (char*)d_ws;
    int* offs   = (int*)p; p += alignup(sizeof(int) * (size_t)(N + 1));
    int* cursor = (int*)p; p += alignup(sizeof(int) * (size_t)N);
    int* bsums  = (int*)p; p += alignup(sizeof(int) * 256);
    int* boffs  = (int*)p; p += alignup(sizeof(int) * 256);
    int* cols   = (int*)p; p += alignup(sizeof(int) * (size_t)(E + N));
    float* xp   = (float*)p; p += alignup(sizeof(float) * (size_t)N * 128);
    float* hbuf = (float*)p; p += alignup(sizeof(float) * (size_t)N * 128);
    float* as_  = (float*)p; p += alignup(sizeof(float) * (size_t)N * 8);
    float* ad_  = (float*)p; p += alignup(sizeof(float) * (size_t)N * 8);
    short* Bf1  = (short*)p; p += alignup(sizeof(short) * 8 * 8 * 64 * 16);  // K=256,N=128
    short* Bf2  = (short*)p; p += alignup(sizeof(short) * 4 * 4 * 64 * 16);  // K=128,N=64

    const int TB = 256;
    const int nb = (N + 1023) / 1024;

    // CSR build (dest-sorted adjacency, includes self loops)
    init_deg_k<<<(N + TB - 1) / TB, TB, 0, stream>>>(cursor, N);
    count_k<<<(E + TB - 1) / TB, TB, 0, stream>>>(dst, E, cursor);
    scan1_k<<<nb, 256, 0, stream>>>(cursor, offs, bsums, N);
    scan2_k<<<1, 256, 0, stream>>>(bsums, boffs, nb, offs + N);
    scan3_k<<<(N + TB - 1) / TB, TB, 0, stream>>>(offs, boffs, N);
    copy_k<<<(N + TB - 1) / TB, TB, 0, stream>>>(offs, cursor, N);
    scatter_edges_k<<<(E + TB - 1) / TB, TB, 0, stream>>>(src, dst, E, cursor, cols);
    scatter_loops_k<<<(N + TB - 1) / TB, TB, 0, stream>>>(N, cursor, cols);

    // W pre-pack (fragment order, hi|lo)
    prep_w_k<<<(4096 + TB - 1) / TB, TB, 0, stream>>>(W1, Bf1, 256, 128, 8, 4096);
    prep_w_k<<<(1024 + TB - 1) / TB, TB, 0, stream>>>(W2, Bf2, 128, 64, 4, 1024);

    // ---- layer 1: 256 -> 128 (H=8, C=16), ELU
    mfma_gemm_k<128, 4, 4, 2><<<dim3((N + 127) / 128, 1), 256, 0, stream>>>(
        x, Bf1, xp, N, 128, 256, 8);
    alpha_k<8, 16><<<(N * 8 + TB - 1) / TB, TB, 0, stream>>>(xp, a1s, a1d, as_, ad_, N * 8);
    agg8_k<16, true><<<(N * 64 + TB - 1) / TB, TB, 0, stream>>>(
        xp, as_, ad_, offs, cols, b1, hbuf, N);

    // ---- layer 2: 128 -> 64 (H=8, C=8), ELU
    mfma_gemm_k<128, 2, 4, 4><<<dim3((N + 127) / 128, 1), 256, 0, stream>>>(
        hbuf, Bf2, xp, N, 64, 128, 4);
    alpha_k<8, 8><<<(N * 8 + TB - 1) / TB, TB, 0, stream>>>(xp, a2s, a2d, as_, ad_, N * 8);
    agg8_k<8, true><<<(N * 64 + TB - 1) / TB, TB, 0, stream>>>(
        xp, as_, ad_, offs, cols, b2, hbuf, N);

    // ---- layer 3: 64 -> 10 (H=1, C=10), no activation
    gemm_k<64, 16, 16, 4, 1><<<dim3((N + 63) / 64, 1), dim3(16, 16), 0, stream>>>(
        hbuf, W3, xp, N, 10, 64);
    alpha_k<1, 10><<<(N + TB - 1) / TB, TB, 0, stream>>>(xp, a3s, a3d, as_, ad_, N);
    agg1h_k<<<(N * 64 + TB - 1) / TB, TB, 0, stream>>>(
        xp, as_, ad_, offs, cols, b3, hbuf, N);

    // ---- log_softmax
    logsoftmax_k<<<(N + TB - 1) / TB, TB, 0, stream>>>(hbuf, out, N);
}

// Round 4
// 726.864 us; speedup vs baseline: 1.8433x; 1.0759x over previous
//
#include <hip/hip_runtime.h>
#include <hip/hip_bf16.h>
#include <math.h>

// ---------------------------------------------------------------------------
// GAT 3-layer forward on MI355X.
//   1. Dest-CSR build (count/scan/scatter) in workspace.
//   2. Layer 1: split-bf16 MFMA GEMM (A=Ah+Al: AhBh+AlBh+AhBl ~ fp32 accuracy).
//      Layer 2: A is bf16 (agg output) -> 2-MFMA variant. Layer 3: f32 vector.
//      GEMMs write f32 C (exact alphas) + bf16 copy (gather operand).
//   3. Wave-per-node aggregation gathers bf16 rows (halved fetch bytes);
//      alphas exact f32. Layer-3 agg fuses log_softmax, writes d_out.
// ---------------------------------------------------------------------------

#define LEAKY(v) ((v) > 0.f ? (v) : 0.2f * (v))

typedef __bf16 bf16_t;
typedef __bf16 bf16x8 __attribute__((ext_vector_type(8)));
typedef __bf16 bf16x4 __attribute__((ext_vector_type(4)));
typedef float f32x4 __attribute__((ext_vector_type(4)));

static __device__ __forceinline__ unsigned short bf_bits(float f) {
    bf16_t b = (bf16_t)f;
    return __builtin_bit_cast(unsigned short, b);
}
static __device__ __forceinline__ float bf_to_f(unsigned short u) {
    return __uint_as_float(((unsigned int)u) << 16);
}

// ---------------- CSR build ----------------

__global__ void init_deg_k(int* deg, int N) {
    int i = blockIdx.x * blockDim.x + threadIdx.x;
    if (i < N) deg[i] = 1;  // self loop
}

__global__ void count_k(const int* __restrict__ dst, int E, int* deg) {
    int i = blockIdx.x * blockDim.x + threadIdx.x;
    if (i < E) atomicAdd(&deg[dst[i]], 1);
}

// exclusive scan, 1024 elements per block (256 threads x 4)
__global__ void scan1_k(const int* __restrict__ in, int* out, int* bsums, int N) {
    __shared__ int sh[256];
    int tid = threadIdx.x;
    int base = blockIdx.x * 1024 + tid * 4;
    int v[4]; int s = 0;
#pragma unroll
    for (int j = 0; j < 4; j++) { v[j] = (base + j < N) ? in[base + j] : 0; s += v[j]; }
    sh[tid] = s; __syncthreads();
    for (int off = 1; off < 256; off <<= 1) {
        int t = (tid >= off) ? sh[tid - off] : 0;
        __syncthreads();
        sh[tid] += t;
        __syncthreads();
    }
    int run = sh[tid] - s;
#pragma unroll
    for (int j = 0; j < 4; j++) { if (base + j < N) out[base + j] = run; run += v[j]; }
    if (tid == 255) bsums[blockIdx.x] = sh[255];
}

__global__ void scan2_k(const int* __restrict__ bsums, int* boffs, int nb, int* total_out) {
    __shared__ int sh[256];
    int tid = threadIdx.x;
    int v = (tid < nb) ? bsums[tid] : 0;
    sh[tid] = v; __syncthreads();
    for (int off = 1; off < 256; off <<= 1) {
        int t = (tid >= off) ? sh[tid - off] : 0;
        __syncthreads();
        sh[tid] += t;
        __syncthreads();
    }
    if (tid < nb) boffs[tid] = sh[tid] - v;
    if (tid == 255) *total_out = sh[255];
}

__global__ void scan3_k(int* out, const int* __restrict__ boffs, int N) {
    int i = blockIdx.x * blockDim.x + threadIdx.x;
    if (i < N) out[i] += boffs[i >> 10];
}

__global__ void copy_k(const int* __restrict__ a, int* b, int N) {
    int i = blockIdx.x * blockDim.x + threadIdx.x;
    if (i < N) b[i] = a[i];
}

__global__ void scatter_edges_k(const int* __restrict__ src, const int* __restrict__ dst,
                                int E, int* cursor, int* cols) {
    int i = blockIdx.x * blockDim.x + threadIdx.x;
    if (i < E) {
        int d = dst[i];
        int p = atomicAdd(&cursor[d], 1);
        cols[p] = src[i];
    }
}

__global__ void scatter_loops_k(int N, int* cursor, int* cols) {
    int i = blockIdx.x * blockDim.x + threadIdx.x;
    if (i < N) {
        int p = atomicAdd(&cursor[i], 1);
        cols[p] = i;
    }
}

// ---------------- W pre-pack into MFMA B-fragment order (hi|lo) ----------------
__global__ void prep_w_k(const float* __restrict__ W, short* __restrict__ Bfs,
                         int K, int N, int NT, int total) {
    int idx = blockIdx.x * blockDim.x + threadIdx.x;
    if (idx >= total) return;  // total = (K/32)*NT*64
    int lane = idx & 63;
    int t = idx >> 6;
    int ntile = t % NT, kstep = t / NT;
    int quad = lane >> 4, nl = lane & 15;
    int n = ntile * 16 + nl;
    bf16_t* dst = (bf16_t*)Bfs + (size_t)idx * 16;
#pragma unroll
    for (int j = 0; j < 8; j++) {
        int k = kstep * 32 + quad * 8 + j;
        float v = W[k * N + n];
        bf16_t h = (bf16_t)v;
        bf16_t l = (bf16_t)(v - (float)h);
        dst[j] = h;
        dst[8 + j] = l;
    }
}

// ---------------- split-bf16 MFMA GEMM ----------------
// ABF16=false: A f32, split hi/lo, 3 MFMAs/tile. ABF16=true: A bf16, 2 MFMAs.
// Writes C (f32) and Cb (bf16 copy).
template <int BM, int WMT, int WNT, int NWM, bool ABF16>
__global__ __launch_bounds__(256) void mfma_gemm_k(
        const void* __restrict__ Av, const short* __restrict__ Bfs,
        float* __restrict__ C, unsigned short* __restrict__ Cb,
        int M, int N, int K, int NT) {
    constexpr int NWN = 4 / NWM;
    constexpr int BN = 16 * WNT * NWN;
    constexpr int KPAD = 40;  // 32 + 8: breaks LDS bank aliasing on b128 reads
    __shared__ __align__(16) bf16_t As_hi[BM * KPAD];
    __shared__ __align__(16) bf16_t As_lo[ABF16 ? 16 : BM * KPAD];
    const bf16_t* Bf = (const bf16_t*)Bfs;

    int tid = threadIdx.x;
    int wave = tid >> 6, lane = tid & 63;
    int quad = lane >> 4, l16 = lane & 15;
    int wm = wave % NWM, wn = wave / NWM;
    int row0 = blockIdx.x * BM;
    int ntile0 = blockIdx.y * (BN / 16) + wn * WNT;

    f32x4 acc[WMT][WNT];
#pragma unroll
    for (int i = 0; i < WMT; i++)
#pragma unroll
        for (int j = 0; j < WNT; j++) acc[i][j] = (f32x4){0.f, 0.f, 0.f, 0.f};

    const int nk = K >> 5;
    const int rA = tid >> 3, kq = tid & 7;  // 8 threads/row, 32 rows/pass

    for (int ks = 0; ks < nk; ks++) {
#pragma unroll
        for (int rr = rA; rr < BM; rr += 32) {
            int grow = row0 + rr;
            if (!ABF16) {
                const float* A = (const float*)Av;
                f32x4 v = (f32x4){0.f, 0.f, 0.f, 0.f};
                if (grow < M)
                    v = *(const f32x4*)(A + (size_t)grow * K + ks * 32 + kq * 4);
                bf16x4 h, l;
#pragma unroll
                for (int j = 0; j < 4; j++) {
                    bf16_t hh = (bf16_t)v[j];
                    h[j] = hh;
                    l[j] = (bf16_t)(v[j] - (float)hh);
                }
                *(bf16x4*)&As_hi[rr * KPAD + kq * 4] = h;
                *(bf16x4*)&As_lo[rr * KPAD + kq * 4] = l;
            } else {
                const unsigned short* A = (const unsigned short*)Av;
                ushort4 v = make_ushort4(0, 0, 0, 0);
                if (grow < M)
                    v = *(const ushort4*)(A + (size_t)grow * K + ks * 32 + kq * 4);
                *(ushort4*)&As_hi[rr * KPAD + kq * 4] = v;
            }
        }
        __syncthreads();

        bf16x8 ah[WMT], al[WMT];
#pragma unroll
        for (int i = 0; i < WMT; i++) {
            int rowl = wm * (WMT * 16) + i * 16 + l16;
            ah[i] = *(const bf16x8*)&As_hi[rowl * KPAD + quad * 8];
            if (!ABF16) al[i] = *(const bf16x8*)&As_lo[rowl * KPAD + quad * 8];
        }
        bf16x8 bh[WNT], bl[WNT];
#pragma unroll
        for (int j = 0; j < WNT; j++) {
            size_t base = ((size_t)(ks * NT + ntile0 + j) * 64 + lane) * 16;
            bh[j] = *(const bf16x8*)&Bf[base];
            bl[j] = *(const bf16x8*)&Bf[base + 8];
        }
#pragma unroll
        for (int i = 0; i < WMT; i++)
#pragma unroll
            for (int j = 0; j < WNT; j++) {
                acc[i][j] = __builtin_amdgcn_mfma_f32_16x16x32_bf16(ah[i], bh[j], acc[i][j], 0, 0, 0);
                if (!ABF16)
                    acc[i][j] = __builtin_amdgcn_mfma_f32_16x16x32_bf16(al[i], bh[j], acc[i][j], 0, 0, 0);
                acc[i][j] = __builtin_amdgcn_mfma_f32_16x16x32_bf16(ah[i], bl[j], acc[i][j], 0, 0, 0);
            }
        __syncthreads();
    }

    // store: D[row = quad*4 + r][col = l16] per 16x16 tile
#pragma unroll
    for (int i = 0; i < WMT; i++) {
        int rbase = row0 + wm * (WMT * 16) + i * 16 + quad * 4;
#pragma unroll
        for (int j = 0; j < WNT; j++) {
            int gcol = (ntile0 + j) * 16 + l16;
#pragma unroll
            for (int r2 = 0; r2 < 4; r2++) {
                int grow = rbase + r2;
                if (grow < M) {
                    float v = acc[i][j][r2];
                    C[(size_t)grow * N + gcol] = v;
                    Cb[(size_t)grow * N + gcol] = bf_bits(v);
                }
            }
        }
    }
}

// ---------------- GEMM (f32 vector, bf16 A) — layer 3 only ----------------
template <int BM, int BN, int BK, int TM, int TN>
__global__ void gemm_k(const unsigned short* __restrict__ Ab, const float* __restrict__ B,
                       float* __restrict__ C, unsigned short* __restrict__ Cb,
                       int M, int Nc, int K) {
    __shared__ float As[BK][BM + 1];
    __shared__ float Bs[BK][BN + 1];
    int tx = threadIdx.x, ty = threadIdx.y;
    int tid = ty * blockDim.x + tx;
    const int nthreads = (BM / TM) * (BN / TN);
    int row0 = blockIdx.x * BM, col0 = blockIdx.y * BN;
    float acc[TM][TN];
#pragma unroll
    for (int i = 0; i < TM; i++)
#pragma unroll
        for (int j = 0; j < TN; j++) acc[i][j] = 0.f;

    for (int k0 = 0; k0 < K; k0 += BK) {
        for (int i = tid; i < BM * BK; i += nthreads) {
            int r = i / BK, kk = i % BK;
            int gr = row0 + r;
            As[kk][r] = (gr < M) ? bf_to_f(Ab[(size_t)gr * K + (k0 + kk)]) : 0.f;
        }
        for (int i = tid; i < BK * BN; i += nthreads) {
            int kk = i / BN, c = i % BN;
            int gc = col0 + c;
            Bs[kk][c] = (gc < Nc) ? B[(long)(k0 + kk) * Nc + gc] : 0.f;
        }
        __syncthreads();
#pragma unroll
        for (int kk = 0; kk < BK; ++kk) {
            float a[TM], b[TN];
#pragma unroll
            for (int i = 0; i < TM; i++) a[i] = As[kk][ty * TM + i];
#pragma unroll
            for (int j = 0; j < TN; j++) b[j] = Bs[kk][tx * TN + j];
#pragma unroll
            for (int i = 0; i < TM; i++)
#pragma unroll
                for (int j = 0; j < TN; j++) acc[i][j] = fmaf(a[i], b[j], acc[i][j]);
        }
        __syncthreads();
    }
#pragma unroll
    for (int i = 0; i < TM; i++) {
        int gr = row0 + ty * TM + i;
        if (gr >= M) continue;
#pragma unroll
        for (int j = 0; j < TN; j++) {
            int gc = col0 + tx * TN + j;
            if (gc < Nc) {
                C[(long)gr * Nc + gc] = acc[i][j];
                Cb[(long)gr * Nc + gc] = bf_bits(acc[i][j]);
            }
        }
    }
}

// ---------------- alpha_src / alpha_dst (reads exact f32 xp) ----------------
template <int H, int C>
__global__ void alpha_k(const float* __restrict__ xp, const float* __restrict__ a_s,
                        const float* __restrict__ a_d, float* __restrict__ out_s,
                        float* __restrict__ out_d, int NH) {
    int i = blockIdx.x * blockDim.x + threadIdx.x;
    if (i >= NH) return;
    int h = i % H;
    const float* v = xp + (long)i * C;
    float ss = 0.f, sd = 0.f;
#pragma unroll
    for (int c = 0; c < C; c++) {
        float x = v[c];
        ss = fmaf(x, a_s[h * C + c], ss);
        sd = fmaf(x, a_d[h * C + c], sd);
    }
    out_s[i] = ss;
    out_d[i] = sd;
}

// ---------------- attention aggregation, H=8: one wave per node ----------------
// Gathers bf16 feature rows; writes bf16 output rows.
template <int C, bool DO_ELU>
__global__ void agg8_k(const unsigned short* __restrict__ xpb,
                       const float* __restrict__ asrc, const float* __restrict__ adst,
                       const int* __restrict__ offs, const int* __restrict__ cols,
                       const float* __restrict__ bias, unsigned short* __restrict__ outb,
                       int N) {
    constexpr int HC = 8 * C;
    constexpr int VPL = HC / 64;  // feats per lane: 2 (C=16) or 1 (C=8)
    int gtid = blockIdx.x * blockDim.x + threadIdx.x;
    int n = gtid >> 6;
    if (n >= N) return;
    int lane = threadIdx.x & 63;
    int j = lane >> 3, h = lane & 7;
    int start = offs[n], end = offs[n + 1];

    float ad_l = adst[n * 8 + h];

    // phase 1: online softmax stats for head h over edge-slots j, j+8, ...
    float m = -1e30f, s = 0.f;
    for (int e = start + j; e < end; e += 8) {
        int src = cols[e];
        float v = asrc[src * 8 + h] + ad_l;
        v = LEAKY(v);
        float mo = fmaxf(m, v);
        s = s * __expf(m - mo) + __expf(v - mo);
        m = mo;
    }
#pragma unroll
    for (int off = 8; off <= 32; off <<= 1) {
        float mo = __shfl_xor(m, off, 64);
        float so = __shfl_xor(s, off, 64);
        float mn = fmaxf(m, mo);
        s = s * __expf(m - mn) + so * __expf(mo - mn);
        m = mn;
    }
    float rs = 1.f / (s + 1e-16f);

    // phase 2: feature lane owns feats [lane*VPL, lane*VPL+VPL); head = lane/8
    int h2 = lane >> 3;
    float acc[VPL];
#pragma unroll
    for (int i = 0; i < VPL; i++) acc[i] = 0.f;

    for (int c0 = start; c0 < end; c0 += 8) {
        int e = c0 + j;
        float w_l = 0.f; int src_l = 0;
        if (e < end) {
            src_l = cols[e];
            float v = asrc[src_l * 8 + h] + ad_l;
            v = LEAKY(v);
            w_l = __expf(v - m) * rs;
        }
        int nj = end - c0; if (nj > 8) nj = 8;
        if (nj == 8) {
#pragma unroll
            for (int j2 = 0; j2 < 8; j2++) {
                int srcj = __shfl(src_l, j2 * 8, 64);
                float w = __shfl(w_l, j2 * 8 + h2, 64);
                if (VPL == 2) {
                    unsigned int u = ((const unsigned int*)(xpb + (size_t)srcj * HC))[lane];
                    acc[0] = fmaf(w, __uint_as_float(u << 16), acc[0]);
                    acc[VPL - 1] = fmaf(w, __uint_as_float(u & 0xffff0000u), acc[VPL - 1]);
                } else {
                    acc[0] = fmaf(w, bf_to_f(xpb[(size_t)srcj * HC + lane]), acc[0]);
                }
            }
        } else {
            for (int j2 = 0; j2 < nj; j2++) {
                int srcj = __shfl(src_l, j2 * 8, 64);
                float w = __shfl(w_l, j2 * 8 + h2, 64);
                if (VPL == 2) {
                    unsigned int u = ((const unsigned int*)(xpb + (size_t)srcj * HC))[lane];
                    acc[0] = fmaf(w, __uint_as_float(u << 16), acc[0]);
                    acc[VPL - 1] = fmaf(w, __uint_as_float(u & 0xffff0000u), acc[VPL - 1]);
                } else {
                    acc[0] = fmaf(w, bf_to_f(xpb[(size_t)srcj * HC + lane]), acc[0]);
                }
            }
        }
    }
    if (VPL == 2) {
        float o0 = acc[0] + bias[2 * lane];
        float o1 = acc[VPL - 1] + bias[2 * lane + 1];
        if (DO_ELU) {
            o0 = o0 > 0.f ? o0 : __expf(o0) - 1.f;
            o1 = o1 > 0.f ? o1 : __expf(o1) - 1.f;
        }
        unsigned int packed = (unsigned int)bf_bits(o0) | ((unsigned int)bf_bits(o1) << 16);
        ((unsigned int*)(outb + (size_t)n * HC))[lane] = packed;
    } else {
        float o = acc[0] + bias[lane];
        if (DO_ELU) o = o > 0.f ? o : __expf(o) - 1.f;
        outb[(size_t)n * HC + lane] = bf_bits(o);
    }
}

// ---------------- aggregation H=1 C=10 + fused log_softmax (layer 3) ----------------
__global__ void agg1h_k(const unsigned short* __restrict__ xpb,
                        const float* __restrict__ asrc, const float* __restrict__ adst,
                        const int* __restrict__ offs, const int* __restrict__ cols,
                        const float* __restrict__ bias, float* __restrict__ out, int N) {
    int gtid = blockIdx.x * blockDim.x + threadIdx.x;
    int n = gtid >> 6;
    if (n >= N) return;
    int lane = threadIdx.x & 63;
    int start = offs[n], end = offs[n + 1];
    float ad = adst[n];

    float m = -1e30f, s = 0.f;
    for (int e = start + lane; e < end; e += 64) {
        float v = asrc[cols[e]] + ad;
        v = LEAKY(v);
        float mo = fmaxf(m, v);
        s = s * __expf(m - mo) + __expf(v - mo);
        m = mo;
    }
#pragma unroll
    for (int off = 1; off <= 32; off <<= 1) {
        float mo = __shfl_xor(m, off, 64);
        float so = __shfl_xor(s, off, 64);
        float mn = fmaxf(m, mo);
        s = s * __expf(m - mn) + so * __expf(mo - mn);
        m = mn;
    }
    float rs = 1.f / (s + 1e-16f);

    int j = lane / 10, c = lane - j * 10;
    float acc = 0.f;
    for (int c0 = start; c0 < end; c0 += 6) {
        int e = c0 + j;
        if (j < 6 && e < end) {
            int src = cols[e];
            float v = asrc[src] + ad;
            v = LEAKY(v);
            float w = __expf(v - m) * rs;
            acc = fmaf(w, bf_to_f(xpb[(size_t)src * 10 + c]), acc);
        }
    }
    float tot = acc;
#pragma unroll
    for (int k = 1; k < 6; k++) tot += __shfl(acc, lane + 10 * k, 64);

    // fused log_softmax over the 10 classes (valid in lanes 0-9)
    float z = tot + bias[lane < 10 ? lane : 0];
    float mx = -1e30f;
#pragma unroll
    for (int k = 0; k < 10; k++) mx = fmaxf(mx, __shfl(z, k, 64));
    float se = 0.f;
#pragma unroll
    for (int k = 0; k < 10; k++) se += __expf(__shfl(z, k, 64) - mx);
    if (lane < 10) out[(size_t)n * 10 + lane] = z - (__logf(se) + mx);
}

// ---------------- launch ----------------

static inline size_t alignup(size_t x) { return (x + 255) & ~(size_t)255; }

extern "C" void kernel_launch(void* const* d_in, const int* in_sizes, int n_in,
                              void* d_out, int out_size, void* d_ws, size_t ws_size,
                              hipStream_t stream) {
    const float* x   = (const float*)d_in[0];
    const int*   ei  = (const int*)d_in[1];
    const float* W1  = (const float*)d_in[2];
    const float* a1s = (const float*)d_in[3];
    const float* a1d = (const float*)d_in[4];
    const float* b1  = (const float*)d_in[5];
    const float* W2  = (const float*)d_in[6];
    const float* a2s = (const float*)d_in[7];
    const float* a2d = (const float*)d_in[8];
    const float* b2  = (const float*)d_in[9];
    const float* W3  = (const float*)d_in[10];
    const float* a3s = (const float*)d_in[11];
    const float* a3d = (const float*)d_in[12];
    const float* b3  = (const float*)d_in[13];
    float* out = (float*)d_out;

    const int N = in_sizes[0] / 256;
    const int E = in_sizes[1] / 2;
    const int* src = ei;
    const int* dst = ei + E;

    char* p = (char*)d_ws;
    int* offs    = (int*)p; p += alignup(sizeof(int) * (size_t)(N + 1));
    int* cursor  = (int*)p; p += alignup(sizeof(int) * (size_t)N);
    int* bsums   = (int*)p; p += alignup(sizeof(int) * 256);
    int* boffs   = (int*)p; p += alignup(sizeof(int) * 256);
    int* cols    = (int*)p; p += alignup(sizeof(int) * (size_t)(E + N));
    unsigned short* xpb   = (unsigned short*)p; p += alignup(2 * (size_t)N * 128);
    unsigned short* hbufb = (unsigned short*)p; p += alignup(2 * (size_t)N * 128);
    float* xp    = (float*)p; p += alignup(sizeof(float) * (size_t)N * 128);
    float* as_   = (float*)p; p += alignup(sizeof(float) * (size_t)N * 8);
    float* ad_   = (float*)p; p += alignup(sizeof(float) * (size_t)N * 8);
    short* Bf1   = (short*)p; p += alignup(sizeof(short) * 8 * 8 * 64 * 16);  // K=256,N=128
    short* Bf2   = (short*)p; p += alignup(sizeof(short) * 4 * 4 * 64 * 16);  // K=128,N=64

    const int TB = 256;
    const int nb = (N + 1023) / 1024;

    // CSR build (dest-sorted adjacency, includes self loops)
    init_deg_k<<<(N + TB - 1) / TB, TB, 0, stream>>>(cursor, N);
    count_k<<<(E + TB - 1) / TB, TB, 0, stream>>>(dst, E, cursor);
    scan1_k<<<nb, 256, 0, stream>>>(cursor, offs, bsums, N);
    scan2_k<<<1, 256, 0, stream>>>(bsums, boffs, nb, offs + N);
    scan3_k<<<(N + TB - 1) / TB, TB, 0, stream>>>(offs, boffs, N);
    copy_k<<<(N + TB - 1) / TB, TB, 0, stream>>>(offs, cursor, N);
    scatter_edges_k<<<(E + TB - 1) / TB, TB, 0, stream>>>(src, dst, E, cursor, cols);
    scatter_loops_k<<<(N + TB - 1) / TB, TB, 0, stream>>>(N, cursor, cols);

    // W pre-pack (fragment order, hi|lo)
    prep_w_k<<<(4096 + TB - 1) / TB, TB, 0, stream>>>(W1, Bf1, 256, 128, 8, 4096);
    prep_w_k<<<(1024 + TB - 1) / TB, TB, 0, stream>>>(W2, Bf2, 128, 64, 4, 1024);

    // ---- layer 1: 256 -> 128 (H=8, C=16), ELU
    mfma_gemm_k<128, 4, 4, 2, false><<<dim3((N + 127) / 128, 1), 256, 0, stream>>>(
        x, Bf1, xp, xpb, N, 128, 256, 8);
    alpha_k<8, 16><<<(N * 8 + TB - 1) / TB, TB, 0, stream>>>(xp, a1s, a1d, as_, ad_, N * 8);
    agg8_k<16, true><<<(N * 64 + TB - 1) / TB, TB, 0, stream>>>(
        xpb, as_, ad_, offs, cols, b1, hbufb, N);

    // ---- layer 2: 128 -> 64 (H=8, C=8), ELU  (A is bf16 agg output)
    mfma_gemm_k<128, 2, 4, 4, true><<<dim3((N + 127) / 128, 1), 256, 0, stream>>>(
        hbufb, Bf2, xp, xpb, N, 64, 128, 4);
    alpha_k<8, 8><<<(N * 8 + TB - 1) / TB, TB, 0, stream>>>(xp, a2s, a2d, as_, ad_, N * 8);
    agg8_k<8, true><<<(N * 64 + TB - 1) / TB, TB, 0, stream>>>(
        xpb, as_, ad_, offs, cols, b2, hbufb, N);

    // ---- layer 3: 64 -> 10 (H=1, C=10) + fused log_softmax
    gemm_k<64, 16, 16, 4, 1><<<dim3((N + 63) / 64, 1), dim3(16, 16), 0, stream>>>(
        hbufb, W3, xp, xpb, N, 10, 64);
    alpha_k<1, 10><<<(N + TB - 1) / TB, TB, 0, stream>>>(xp, a3s, a3d, as_, ad_, N);
    agg1h_k<<<(N * 64 + TB - 1) / TB, TB, 0, stream>>>(
        xpb, as_, ad_, offs, cols, b3, out, N);
}

// Round 5
// 594.176 us; speedup vs baseline: 2.2550x; 1.2233x over previous
//
#include <hip/hip_runtime.h>
#include <hip/hip_bf16.h>
#include <math.h>

// ---------------------------------------------------------------------------
// GAT 3-layer forward on MI355X.
//   1. Dest-CSR via 2-pass bucketed counting sort (coalesced writes; the old
//      per-edge random 4B scatter caused 16x write amplification @ ~820GB/s).
//      Self-loops are implicit in the aggregation kernels.
//   2. Layer 1: split-bf16 MFMA GEMM (fp32-level accuracy). Layer 2: bf16-A
//      MFMA. Layer 3: f32 vector. GEMMs write f32 C (exact alphas) + bf16 copy.
//   3. Wave-per-node aggregation gathers bf16 rows; layer-3 agg fuses
//      log_softmax and writes d_out.
// ---------------------------------------------------------------------------

#define LEAKY(v) ((v) > 0.f ? (v) : 0.2f * (v))

typedef __bf16 bf16_t;
typedef __bf16 bf16x8 __attribute__((ext_vector_type(8)));
typedef __bf16 bf16x4 __attribute__((ext_vector_type(4)));
typedef float f32x4 __attribute__((ext_vector_type(4)));

static __device__ __forceinline__ unsigned short bf_bits(float f) {
    bf16_t b = (bf16_t)f;
    return __builtin_bit_cast(unsigned short, b);
}
static __device__ __forceinline__ float bf_to_f(unsigned short u) {
    return __uint_as_float(((unsigned int)u) << 16);
}

// ---------------- CSR build: 2-pass bucket sort ----------------
// Bucket = dst >> 8 (256 nodes/bucket). N=100000 -> NB=391 (NB_MAX=400).
// staged word = src | (dst_local << 17)   (src < 2^17, dst_local < 256).
constexpr int NB_MAX = 400;
constexpr int BCAP = 5120;  // capacity per bucket region; mean load 4096

__global__ void zero_k(int* a, int n) {
    int i = blockIdx.x * blockDim.x + threadIdx.x;
    if (i < n) a[i] = 0;
}

// Pass 1: partition edges into bucket regions with block-local grouping.
__global__ __launch_bounds__(256) void partition_k(
        const int* __restrict__ src, const int* __restrict__ dst, int E, int NB,
        int* __restrict__ bcur, unsigned* __restrict__ staged) {
    __shared__ int hist[NB_MAX];
    __shared__ int bstart[NB_MAX + 1];
    __shared__ int cur[NB_MAX];
    __shared__ int gbase[NB_MAX];
    __shared__ unsigned words[4096];
    int tid = threadIdx.x;
    int e0 = blockIdx.x * 4096;
    int cnt = E - e0; if (cnt > 4096) cnt = 4096;
    if (cnt <= 0) return;

    for (int b = tid; b < NB; b += 256) hist[b] = 0;
    __syncthreads();
    for (int i = tid; i < cnt; i += 256) atomicAdd(&hist[dst[e0 + i] >> 8], 1);
    __syncthreads();
    if (tid == 0) {
        int run = 0;
        for (int b = 0; b < NB; b++) { bstart[b] = run; run += hist[b]; }
        bstart[NB] = run;
    }
    __syncthreads();
    for (int b = tid; b < NB; b += 256) {
        cur[b] = bstart[b];
        gbase[b] = hist[b] ? atomicAdd(&bcur[b], hist[b]) : 0;
    }
    __syncthreads();
    // group into LDS by bucket
    for (int i = tid; i < cnt; i += 256) {
        int s = src[e0 + i], d = dst[e0 + i];
        int b = d >> 8;
        unsigned w = (unsigned)s | ((unsigned)(d & 255) << 17);
        int p = atomicAdd(&cur[b], 1);
        words[p] = w;
    }
    __syncthreads();
    // linear sweep -> coalesced runs into global bucket regions
    for (int i = tid; i < cnt; i += 256) {
        int lo = 0, hi = NB;  // find b: bstart[b] <= i < bstart[b+1]
        while (hi - lo > 1) { int mid = (lo + hi) >> 1; if (bstart[mid] <= i) lo = mid; else hi = mid; }
        staged[(size_t)lo * BCAP + gbase[lo] + (i - bstart[lo])] = words[i];
    }
}

// tiny exclusive scan over NB bucket counts (one wave)
__global__ void scan_nb_k(const int* __restrict__ bcur, int* __restrict__ ebase, int NB) {
    int lane = threadIdx.x;  // 64 threads
    int CH = (NB + 63) / 64;
    int b0 = lane * CH;
    int v[8]; int s = 0;
#pragma unroll 8
    for (int k = 0; k < CH; k++) { int b = b0 + k; int t = (b < NB) ? bcur[b] : 0; if (k < 8) v[k] = t; s += t; }
    int orig = s;
    for (int off = 1; off < 64; off <<= 1) {
        int t = __shfl_up(s, off, 64);
        if (lane >= off) s += t;
    }
    int run = s - orig;  // exclusive
    for (int k = 0; k < CH; k++) { int b = b0 + k; if (b < NB) { ebase[b] = run; run += v[k]; } }
    if (lane == 63) ebase[NB] = run;
}

// Pass 2: per-bucket node-level counting sort -> offs + cols (coalesced writes).
__global__ __launch_bounds__(256) void buildcsr_k(
        const unsigned* __restrict__ staged, const int* __restrict__ bcur,
        const int* __restrict__ ebase, int* __restrict__ offs, int* __restrict__ cols,
        int N, int NB) {
    __shared__ int h[256], hs[256], curl[256];
    __shared__ int colsl[BCAP];
    int b = blockIdx.x, tid = threadIdx.x;
    int n0 = b << 8;
    int ecnt = bcur[b];
    int base_g = ebase[b];
    const unsigned* sb = staged + (size_t)b * BCAP;

    h[tid] = 0;
    __syncthreads();
    for (int i = tid; i < ecnt; i += 256) atomicAdd(&h[sb[i] >> 17], 1);
    __syncthreads();
    int val = h[tid];
    hs[tid] = val; __syncthreads();
    for (int off = 1; off < 256; off <<= 1) {
        int t = (tid >= off) ? hs[tid - off] : 0;
        __syncthreads();
        hs[tid] += t;
        __syncthreads();
    }
    int excl = hs[tid] - val;
    curl[tid] = excl;
    if (n0 + tid < N) offs[n0 + tid] = base_g + excl;
    if (b == NB - 1 && tid == 0) offs[N] = base_g + ecnt;
    __syncthreads();
    for (int i = tid; i < ecnt; i += 256) {
        unsigned w = sb[i];
        int p = atomicAdd(&curl[w >> 17], 1);
        colsl[p] = (int)(w & 0x1FFFFu);
    }
    __syncthreads();
    for (int i = tid; i < ecnt; i += 256) cols[base_g + i] = colsl[i];
}

// ---------------- W pre-pack into MFMA B-fragment order (hi|lo) ----------------
__global__ void prep_w_k(const float* __restrict__ W, short* __restrict__ Bfs,
                         int K, int N, int NT, int total) {
    int idx = blockIdx.x * blockDim.x + threadIdx.x;
    if (idx >= total) return;  // total = (K/32)*NT*64
    int lane = idx & 63;
    int t = idx >> 6;
    int ntile = t % NT, kstep = t / NT;
    int quad = lane >> 4, nl = lane & 15;
    int n = ntile * 16 + nl;
    bf16_t* dst = (bf16_t*)Bfs + (size_t)idx * 16;
#pragma unroll
    for (int j = 0; j < 8; j++) {
        int k = kstep * 32 + quad * 8 + j;
        float v = W[k * N + n];
        bf16_t h = (bf16_t)v;
        bf16_t l = (bf16_t)(v - (float)h);
        dst[j] = h;
        dst[8 + j] = l;
    }
}

// ---------------- split-bf16 MFMA GEMM ----------------
template <int BM, int WMT, int WNT, int NWM, bool ABF16>
__global__ __launch_bounds__(256) void mfma_gemm_k(
        const void* __restrict__ Av, const short* __restrict__ Bfs,
        float* __restrict__ C, unsigned short* __restrict__ Cb,
        int M, int N, int K, int NT) {
    constexpr int NWN = 4 / NWM;
    constexpr int BN = 16 * WNT * NWN;
    constexpr int KPAD = 40;  // 32 + 8: breaks LDS bank aliasing on b128 reads
    __shared__ __align__(16) bf16_t As_hi[BM * KPAD];
    __shared__ __align__(16) bf16_t As_lo[ABF16 ? 16 : BM * KPAD];
    const bf16_t* Bf = (const bf16_t*)Bfs;

    int tid = threadIdx.x;
    int wave = tid >> 6, lane = tid & 63;
    int quad = lane >> 4, l16 = lane & 15;
    int wm = wave % NWM, wn = wave / NWM;
    int row0 = blockIdx.x * BM;
    int ntile0 = blockIdx.y * (BN / 16) + wn * WNT;

    f32x4 acc[WMT][WNT];
#pragma unroll
    for (int i = 0; i < WMT; i++)
#pragma unroll
        for (int j = 0; j < WNT; j++) acc[i][j] = (f32x4){0.f, 0.f, 0.f, 0.f};

    const int nk = K >> 5;
    const int rA = tid >> 3, kq = tid & 7;  // 8 threads/row, 32 rows/pass

    for (int ks = 0; ks < nk; ks++) {
#pragma unroll
        for (int rr = rA; rr < BM; rr += 32) {
            int grow = row0 + rr;
            if (!ABF16) {
                const float* A = (const float*)Av;
                f32x4 v = (f32x4){0.f, 0.f, 0.f, 0.f};
                if (grow < M)
                    v = *(const f32x4*)(A + (size_t)grow * K + ks * 32 + kq * 4);
                bf16x4 h, l;
#pragma unroll
                for (int j = 0; j < 4; j++) {
                    bf16_t hh = (bf16_t)v[j];
                    h[j] = hh;
                    l[j] = (bf16_t)(v[j] - (float)hh);
                }
                *(bf16x4*)&As_hi[rr * KPAD + kq * 4] = h;
                *(bf16x4*)&As_lo[rr * KPAD + kq * 4] = l;
            } else {
                const unsigned short* A = (const unsigned short*)Av;
                ushort4 v = make_ushort4(0, 0, 0, 0);
                if (grow < M)
                    v = *(const ushort4*)(A + (size_t)grow * K + ks * 32 + kq * 4);
                *(ushort4*)&As_hi[rr * KPAD + kq * 4] = v;
            }
        }
        __syncthreads();

        bf16x8 ah[WMT], al[WMT];
#pragma unroll
        for (int i = 0; i < WMT; i++) {
            int rowl = wm * (WMT * 16) + i * 16 + l16;
            ah[i] = *(const bf16x8*)&As_hi[rowl * KPAD + quad * 8];
            if (!ABF16) al[i] = *(const bf16x8*)&As_lo[rowl * KPAD + quad * 8];
        }
        bf16x8 bh[WNT], bl[WNT];
#pragma unroll
        for (int j = 0; j < WNT; j++) {
            size_t base = ((size_t)(ks * NT + ntile0 + j) * 64 + lane) * 16;
            bh[j] = *(const bf16x8*)&Bf[base];
            bl[j] = *(const bf16x8*)&Bf[base + 8];
        }
#pragma unroll
        for (int i = 0; i < WMT; i++)
#pragma unroll
            for (int j = 0; j < WNT; j++) {
                acc[i][j] = __builtin_amdgcn_mfma_f32_16x16x32_bf16(ah[i], bh[j], acc[i][j], 0, 0, 0);
                if (!ABF16)
                    acc[i][j] = __builtin_amdgcn_mfma_f32_16x16x32_bf16(al[i], bh[j], acc[i][j], 0, 0, 0);
                acc[i][j] = __builtin_amdgcn_mfma_f32_16x16x32_bf16(ah[i], bl[j], acc[i][j], 0, 0, 0);
            }
        __syncthreads();
    }

    // store: D[row = quad*4 + r][col = l16] per 16x16 tile
#pragma unroll
    for (int i = 0; i < WMT; i++) {
        int rbase = row0 + wm * (WMT * 16) + i * 16 + quad * 4;
#pragma unroll
        for (int j = 0; j < WNT; j++) {
            int gcol = (ntile0 + j) * 16 + l16;
#pragma unroll
            for (int r2 = 0; r2 < 4; r2++) {
                int grow = rbase + r2;
                if (grow < M) {
                    float v = acc[i][j][r2];
                    C[(size_t)grow * N + gcol] = v;
                    Cb[(size_t)grow * N + gcol] = bf_bits(v);
                }
            }
        }
    }
}

// ---------------- GEMM (f32 vector, bf16 A) — layer 3 only ----------------
template <int BM, int BN, int BK, int TM, int TN>
__global__ void gemm_k(const unsigned short* __restrict__ Ab, const float* __restrict__ B,
                       float* __restrict__ C, unsigned short* __restrict__ Cb,
                       int M, int Nc, int K) {
    __shared__ float As[BK][BM + 1];
    __shared__ float Bs[BK][BN + 1];
    int tx = threadIdx.x, ty = threadIdx.y;
    int tid = ty * blockDim.x + tx;
    const int nthreads = (BM / TM) * (BN / TN);
    int row0 = blockIdx.x * BM, col0 = blockIdx.y * BN;
    float acc[TM][TN];
#pragma unroll
    for (int i = 0; i < TM; i++)
#pragma unroll
        for (int j = 0; j < TN; j++) acc[i][j] = 0.f;

    for (int k0 = 0; k0 < K; k0 += BK) {
        for (int i = tid; i < BM * BK; i += nthreads) {
            int r = i / BK, kk = i % BK;
            int gr = row0 + r;
            As[kk][r] = (gr < M) ? bf_to_f(Ab[(size_t)gr * K + (k0 + kk)]) : 0.f;
        }
        for (int i = tid; i < BK * BN; i += nthreads) {
            int kk = i / BN, c = i % BN;
            int gc = col0 + c;
            Bs[kk][c] = (gc < Nc) ? B[(long)(k0 + kk) * Nc + gc] : 0.f;
        }
        __syncthreads();
#pragma unroll
        for (int kk = 0; kk < BK; ++kk) {
            float a[TM], b[TN];
#pragma unroll
            for (int i = 0; i < TM; i++) a[i] = As[kk][ty * TM + i];
#pragma unroll
            for (int j = 0; j < TN; j++) b[j] = Bs[kk][tx * TN + j];
#pragma unroll
            for (int i = 0; i < TM; i++)
#pragma unroll
                for (int j = 0; j < TN; j++) acc[i][j] = fmaf(a[i], b[j], acc[i][j]);
        }
        __syncthreads();
    }
#pragma unroll
    for (int i = 0; i < TM; i++) {
        int gr = row0 + ty * TM + i;
        if (gr >= M) continue;
#pragma unroll
        for (int j = 0; j < TN; j++) {
            int gc = col0 + tx * TN + j;
            if (gc < Nc) {
                C[(long)gr * Nc + gc] = acc[i][j];
                Cb[(long)gr * Nc + gc] = bf_bits(acc[i][j]);
            }
        }
    }
}

// ---------------- alpha_src / alpha_dst (reads exact f32 xp) ----------------
template <int H, int C>
__global__ void alpha_k(const float* __restrict__ xp, const float* __restrict__ a_s,
                        const float* __restrict__ a_d, float* __restrict__ out_s,
                        float* __restrict__ out_d, int NH) {
    int i = blockIdx.x * blockDim.x + threadIdx.x;
    if (i >= NH) return;
    int h = i % H;
    const float* v = xp + (long)i * C;
    float ss = 0.f, sd = 0.f;
#pragma unroll
    for (int c = 0; c < C; c++) {
        float x = v[c];
        ss = fmaf(x, a_s[h * C + c], ss);
        sd = fmaf(x, a_d[h * C + c], sd);
    }
    out_s[i] = ss;
    out_d[i] = sd;
}

// ---------------- attention aggregation, H=8: one wave per node ----------------
// cols holds real edges only; the self-loop is implicit.
template <int C, bool DO_ELU>
__global__ void agg8_k(const unsigned short* __restrict__ xpb,
                       const float* __restrict__ asrc, const float* __restrict__ adst,
                       const int* __restrict__ offs, const int* __restrict__ cols,
                       const float* __restrict__ bias, unsigned short* __restrict__ outb,
                       int N) {
    constexpr int HC = 8 * C;
    constexpr int VPL = HC / 64;  // feats per lane: 2 (C=16) or 1 (C=8)
    int gtid = blockIdx.x * blockDim.x + threadIdx.x;
    int n = gtid >> 6;
    if (n >= N) return;
    int lane = threadIdx.x & 63;
    int j = lane >> 3, h = lane & 7;
    int start = offs[n], end = offs[n + 1];

    float ad_l = adst[n * 8 + h];
    float vs = asrc[n * 8 + h] + ad_l;  // self-loop logit for head h
    vs = LEAKY(vs);

    // phase 1: online softmax stats for head h over edge-slots j, j+8, ...
    // j==0 lanes seed with the implicit self-loop.
    float m, s;
    if (j == 0) { m = vs; s = 1.f; } else { m = -1e30f; s = 0.f; }
    for (int e = start + j; e < end; e += 8) {
        int src = cols[e];
        float v = asrc[src * 8 + h] + ad_l;
        v = LEAKY(v);
        float mo = fmaxf(m, v);
        s = s * __expf(m - mo) + __expf(v - mo);
        m = mo;
    }
#pragma unroll
    for (int off = 8; off <= 32; off <<= 1) {
        float mo = __shfl_xor(m, off, 64);
        float so = __shfl_xor(s, off, 64);
        float mn = fmaxf(m, mo);
        s = s * __expf(m - mn) + so * __expf(mo - mn);
        m = mn;
    }
    float rs = 1.f / (s + 1e-16f);
    float wself_l = __expf(vs - m) * rs;  // per-head self weight (all lanes)

    // phase 2: feature lane owns feats [lane*VPL, lane*VPL+VPL); head = lane/8
    int h2 = lane >> 3;
    float acc[VPL];
#pragma unroll
    for (int i = 0; i < VPL; i++) acc[i] = 0.f;

    // implicit self contribution
    {
        float wself = __shfl(wself_l, h2, 64);
        if (VPL == 2) {
            unsigned int u = ((const unsigned int*)(xpb + (size_t)n * HC))[lane];
            acc[0] = fmaf(wself, __uint_as_float(u << 16), acc[0]);
            acc[VPL - 1] = fmaf(wself, __uint_as_float(u & 0xffff0000u), acc[VPL - 1]);
        } else {
            acc[0] = fmaf(wself, bf_to_f(xpb[(size_t)n * HC + lane]), acc[0]);
        }
    }

    for (int c0 = start; c0 < end; c0 += 8) {
        int e = c0 + j;
        float w_l = 0.f; int src_l = 0;
        if (e < end) {
            src_l = cols[e];
            float v = asrc[src_l * 8 + h] + ad_l;
            v = LEAKY(v);
            w_l = __expf(v - m) * rs;
        }
        int nj = end - c0; if (nj > 8) nj = 8;
        if (nj == 8) {
#pragma unroll
            for (int j2 = 0; j2 < 8; j2++) {
                int srcj = __shfl(src_l, j2 * 8, 64);
                float w = __shfl(w_l, j2 * 8 + h2, 64);
                if (VPL == 2) {
                    unsigned int u = ((const unsigned int*)(xpb + (size_t)srcj * HC))[lane];
                    acc[0] = fmaf(w, __uint_as_float(u << 16), acc[0]);
                    acc[VPL - 1] = fmaf(w, __uint_as_float(u & 0xffff0000u), acc[VPL - 1]);
                } else {
                    acc[0] = fmaf(w, bf_to_f(xpb[(size_t)srcj * HC + lane]), acc[0]);
                }
            }
        } else {
            for (int j2 = 0; j2 < nj; j2++) {
                int srcj = __shfl(src_l, j2 * 8, 64);
                float w = __shfl(w_l, j2 * 8 + h2, 64);
                if (VPL == 2) {
                    unsigned int u = ((const unsigned int*)(xpb + (size_t)srcj * HC))[lane];
                    acc[0] = fmaf(w, __uint_as_float(u << 16), acc[0]);
                    acc[VPL - 1] = fmaf(w, __uint_as_float(u & 0xffff0000u), acc[VPL - 1]);
                } else {
                    acc[0] = fmaf(w, bf_to_f(xpb[(size_t)srcj * HC + lane]), acc[0]);
                }
            }
        }
    }
    if (VPL == 2) {
        float o0 = acc[0] + bias[2 * lane];
        float o1 = acc[VPL - 1] + bias[2 * lane + 1];
        if (DO_ELU) {
            o0 = o0 > 0.f ? o0 : __expf(o0) - 1.f;
            o1 = o1 > 0.f ? o1 : __expf(o1) - 1.f;
        }
        unsigned int packed = (unsigned int)bf_bits(o0) | ((unsigned int)bf_bits(o1) << 16);
        ((unsigned int*)(outb + (size_t)n * HC))[lane] = packed;
    } else {
        float o = acc[0] + bias[lane];
        if (DO_ELU) o = o > 0.f ? o : __expf(o) - 1.f;
        outb[(size_t)n * HC + lane] = bf_bits(o);
    }
}

// ---------------- aggregation H=1 C=10 + fused log_softmax (layer 3) ----------------
__global__ void agg1h_k(const unsigned short* __restrict__ xpb,
                        const float* __restrict__ asrc, const float* __restrict__ adst,
                        const int* __restrict__ offs, const int* __restrict__ cols,
                        const float* __restrict__ bias, float* __restrict__ out, int N) {
    int gtid = blockIdx.x * blockDim.x + threadIdx.x;
    int n = gtid >> 6;
    if (n >= N) return;
    int lane = threadIdx.x & 63;
    int start = offs[n], end = offs[n + 1];
    float ad = adst[n];
    float vs = asrc[n] + ad;  // implicit self-loop
    vs = LEAKY(vs);

    float m, s;
    if (lane == 0) { m = vs; s = 1.f; } else { m = -1e30f; s = 0.f; }
    for (int e = start + lane; e < end; e += 64) {
        float v = asrc[cols[e]] + ad;
        v = LEAKY(v);
        float mo = fmaxf(m, v);
        s = s * __expf(m - mo) + __expf(v - mo);
        m = mo;
    }
#pragma unroll
    for (int off = 1; off <= 32; off <<= 1) {
        float mo = __shfl_xor(m, off, 64);
        float so = __shfl_xor(s, off, 64);
        float mn = fmaxf(m, mo);
        s = s * __expf(m - mn) + so * __expf(mo - mn);
        m = mn;
    }
    float rs = 1.f / (s + 1e-16f);
    float wself = __expf(vs - m) * rs;

    int j = lane / 10, c = lane - j * 10;
    float acc = 0.f;
    if (j == 0) acc = wself * bf_to_f(xpb[(size_t)n * 10 + c]);  // self term
    for (int c0 = start; c0 < end; c0 += 6) {
        int e = c0 + j;
        if (j < 6 && e < end) {
            int src = cols[e];
            float v = asrc[src] + ad;
            v = LEAKY(v);
            float w = __expf(v - m) * rs;
            acc = fmaf(w, bf_to_f(xpb[(size_t)src * 10 + c]), acc);
        }
    }
    float tot = acc;
#pragma unroll
    for (int k = 1; k < 6; k++) tot += __shfl(acc, lane + 10 * k, 64);

    // fused log_softmax over the 10 classes (valid in lanes 0-9)
    float z = tot + bias[lane < 10 ? lane : 0];
    float mx = -1e30f;
#pragma unroll
    for (int k = 0; k < 10; k++) mx = fmaxf(mx, __shfl(z, k, 64));
    float se = 0.f;
#pragma unroll
    for (int k = 0; k < 10; k++) se += __expf(__shfl(z, k, 64) - mx);
    if (lane < 10) out[(size_t)n * 10 + lane] = z - (__logf(se) + mx);
}

// ---------------- launch ----------------

static inline size_t alignup(size_t x) { return (x + 255) & ~(size_t)255; }

extern "C" void kernel_launch(void* const* d_in, const int* in_sizes, int n_in,
                              void* d_out, int out_size, void* d_ws, size_t ws_size,
                              hipStream_t stream) {
    const float* x   = (const float*)d_in[0];
    const int*   ei  = (const int*)d_in[1];
    const float* W1  = (const float*)d_in[2];
    const float* a1s = (const float*)d_in[3];
    const float* a1d = (const float*)d_in[4];
    const float* b1  = (const float*)d_in[5];
    const float* W2  = (const float*)d_in[6];
    const float* a2s = (const float*)d_in[7];
    const float* a2d = (const float*)d_in[8];
    const float* b2  = (const float*)d_in[9];
    const float* W3  = (const float*)d_in[10];
    const float* a3s = (const float*)d_in[11];
    const float* a3d = (const float*)d_in[12];
    const float* b3  = (const float*)d_in[13];
    float* out = (float*)d_out;

    const int N = in_sizes[0] / 256;
    const int E = in_sizes[1] / 2;
    const int* src = ei;
    const int* dst = ei + E;
    const int NB = (N + 255) >> 8;  // 391 for N=100000 (<= NB_MAX)

    char* p = (char*)d_ws;
    int* offs    = (int*)p; p += alignup(sizeof(int) * (size_t)(N + 1));
    int* bcur    = (int*)p; p += alignup(sizeof(int) * (size_t)(NB_MAX + 1));
    int* ebase   = (int*)p; p += alignup(sizeof(int) * (size_t)(NB_MAX + 1));
    int* cols    = (int*)p; p += alignup(sizeof(int) * (size_t)E);
    unsigned short* xpb   = (unsigned short*)p; p += alignup(2 * (size_t)N * 128);
    unsigned short* hbufb = (unsigned short*)p; p += alignup(2 * (size_t)N * 128);
    float* xp    = (float*)p; p += alignup(sizeof(float) * (size_t)N * 128);
    float* as_   = (float*)p; p += alignup(sizeof(float) * (size_t)N * 8);
    float* ad_   = (float*)p; p += alignup(sizeof(float) * (size_t)N * 8);
    short* Bf1   = (short*)p; p += alignup(sizeof(short) * 8 * 8 * 64 * 16);  // K=256,N=128
    short* Bf2   = (short*)p; p += alignup(sizeof(short) * 4 * 4 * 64 * 16);  // K=128,N=64
    // staged bucket regions alias xp: CSR build finishes before gemm1 writes xp.
    unsigned* staged = (unsigned*)xp;  // NB * BCAP * 4B = 8 MB << 51.2 MB

    const int TB = 256;

    // CSR build: bucketed counting sort (self-loops implicit in agg)
    zero_k<<<(NB + TB - 1) / TB, TB, 0, stream>>>(bcur, NB);
    partition_k<<<(E + 4095) / 4096, 256, 0, stream>>>(src, dst, E, NB, bcur, staged);
    scan_nb_k<<<1, 64, 0, stream>>>(bcur, ebase, NB);
    buildcsr_k<<<NB, 256, 0, stream>>>(staged, bcur, ebase, offs, cols, N, NB);

    // W pre-pack (fragment order, hi|lo)
    prep_w_k<<<(4096 + TB - 1) / TB, TB, 0, stream>>>(W1, Bf1, 256, 128, 8, 4096);
    prep_w_k<<<(1024 + TB - 1) / TB, TB, 0, stream>>>(W2, Bf2, 128, 64, 4, 1024);

    // ---- layer 1: 256 -> 128 (H=8, C=16), ELU
    mfma_gemm_k<128, 4, 4, 2, false><<<dim3((N + 127) / 128, 1), 256, 0, stream>>>(
        x, Bf1, xp, xpb, N, 128, 256, 8);
    alpha_k<8, 16><<<(N * 8 + TB - 1) / TB, TB, 0, stream>>>(xp, a1s, a1d, as_, ad_, N * 8);
    agg8_k<16, true><<<(N * 64 + TB - 1) / TB, TB, 0, stream>>>(
        xpb, as_, ad_, offs, cols, b1, hbufb, N);

    // ---- layer 2: 128 -> 64 (H=8, C=8), ELU  (A is bf16 agg output)
    mfma_gemm_k<128, 2, 4, 4, true><<<dim3((N + 127) / 128, 1), 256, 0, stream>>>(
        hbufb, Bf2, xp, xpb, N, 64, 128, 4);
    alpha_k<8, 8><<<(N * 8 + TB - 1) / TB, TB, 0, stream>>>(xp, a2s, a2d, as_, ad_, N * 8);
    agg8_k<8, true><<<(N * 64 + TB - 1) / TB, TB, 0, stream>>>(
        xpb, as_, ad_, offs, cols, b2, hbufb, N);

    // ---- layer 3: 64 -> 10 (H=1, C=10) + fused log_softmax
    gemm_k<64, 16, 16, 4, 1><<<dim3((N + 63) / 64, 1), dim3(16, 16), 0, stream>>>(
        hbufb, W3, xp, xpb, N, 10, 64);
    alpha_k<1, 10><<<(N + TB - 1) / TB, TB, 0, stream>>>(xp, a3s, a3d, as_, ad_, N);
    agg1h_k<<<(N * 64 + TB - 1) / TB, TB, 0, stream>>>(
        xpb, as_, ad_, offs, cols, b3, out, N);
}

// Round 6
// 576.828 us; speedup vs baseline: 2.3228x; 1.0301x over previous
//
#include <hip/hip_runtime.h>
#include <hip/hip_bf16.h>
#include <math.h>

// ---------------------------------------------------------------------------
// GAT 3-layer forward on MI355X.
//   1. Dest-CSR via 2-pass bucketed counting sort (coalesced writes).
//      Self-loops are implicit in the aggregation kernels.
//   2. Layer 1: split-bf16 MFMA GEMM (fp32-level accuracy). Layer 2: bf16-A
//      MFMA. Layer 3: f32 vector. GEMMs write f32 C (exact alphas) + bf16 copy.
//   3. Wave-per-node aggregation gathers bf16 rows. Weight broadcast uses raw
//      ds_bpermute w/ folded offsets; wave-uniform src rows via readlane so
//      gather addresses are scalar. Layer-2 processes 2 edges/iter (half-wave
//      per 128B row). Layer-3 agg fuses log_softmax, writes d_out.
// ---------------------------------------------------------------------------

#define LEAKY(v) ((v) > 0.f ? (v) : 0.2f * (v))

typedef __bf16 bf16_t;
typedef __bf16 bf16x8 __attribute__((ext_vector_type(8)));
typedef __bf16 bf16x4 __attribute__((ext_vector_type(4)));
typedef float f32x4 __attribute__((ext_vector_type(4)));

static __device__ __forceinline__ unsigned short bf_bits(float f) {
    bf16_t b = (bf16_t)f;
    return __builtin_bit_cast(unsigned short, b);
}
static __device__ __forceinline__ float bf_to_f(unsigned short u) {
    return __uint_as_float(((unsigned int)u) << 16);
}
static __device__ __forceinline__ float bperm_f(int byteaddr, float v) {
    return __uint_as_float((unsigned)__builtin_amdgcn_ds_bpermute(byteaddr, (int)__float_as_uint(v)));
}

// ---------------- CSR build: 2-pass bucket sort ----------------
// Bucket = dst >> 8 (256 nodes/bucket). N=100000 -> NB=391 (NB_MAX=400).
// staged word = src | (dst_local << 17)   (src < 2^17, dst_local < 256).
constexpr int NB_MAX = 400;
constexpr int BCAP = 5120;  // capacity per bucket region; mean load 4096

__global__ void zero_k(int* a, int n) {
    int i = blockIdx.x * blockDim.x + threadIdx.x;
    if (i < n) a[i] = 0;
}

// Pass 1: partition edges into bucket regions with block-local grouping.
__global__ __launch_bounds__(256) void partition_k(
        const int* __restrict__ src, const int* __restrict__ dst, int E, int NB,
        int* __restrict__ bcur, unsigned* __restrict__ staged) {
    __shared__ int hist[NB_MAX];
    __shared__ int bstart[NB_MAX + 1];
    __shared__ int cur[NB_MAX];
    __shared__ int gbase[NB_MAX];
    __shared__ unsigned words[4096];
    int tid = threadIdx.x;
    int e0 = blockIdx.x * 4096;
    int cnt = E - e0; if (cnt > 4096) cnt = 4096;
    if (cnt <= 0) return;

    for (int b = tid; b < NB; b += 256) hist[b] = 0;
    __syncthreads();
    for (int i = tid; i < cnt; i += 256) atomicAdd(&hist[dst[e0 + i] >> 8], 1);
    __syncthreads();
    if (tid == 0) {
        int run = 0;
        for (int b = 0; b < NB; b++) { bstart[b] = run; run += hist[b]; }
        bstart[NB] = run;
    }
    __syncthreads();
    for (int b = tid; b < NB; b += 256) {
        cur[b] = bstart[b];
        gbase[b] = hist[b] ? atomicAdd(&bcur[b], hist[b]) : 0;
    }
    __syncthreads();
    // group into LDS by bucket
    for (int i = tid; i < cnt; i += 256) {
        int s = src[e0 + i], d = dst[e0 + i];
        int b = d >> 8;
        unsigned w = (unsigned)s | ((unsigned)(d & 255) << 17);
        int p = atomicAdd(&cur[b], 1);
        words[p] = w;
    }
    __syncthreads();
    // linear sweep -> coalesced runs into global bucket regions
    for (int i = tid; i < cnt; i += 256) {
        int lo = 0, hi = NB;  // find b: bstart[b] <= i < bstart[b+1]
        while (hi - lo > 1) { int mid = (lo + hi) >> 1; if (bstart[mid] <= i) lo = mid; else hi = mid; }
        staged[(size_t)lo * BCAP + gbase[lo] + (i - bstart[lo])] = words[i];
    }
}

// tiny exclusive scan over NB bucket counts (one wave)
__global__ void scan_nb_k(const int* __restrict__ bcur, int* __restrict__ ebase, int NB) {
    int lane = threadIdx.x;  // 64 threads
    int CH = (NB + 63) / 64;
    int b0 = lane * CH;
    int v[8]; int s = 0;
#pragma unroll 8
    for (int k = 0; k < CH; k++) { int b = b0 + k; int t = (b < NB) ? bcur[b] : 0; if (k < 8) v[k] = t; s += t; }
    int orig = s;
    for (int off = 1; off < 64; off <<= 1) {
        int t = __shfl_up(s, off, 64);
        if (lane >= off) s += t;
    }
    int run = s - orig;  // exclusive
    for (int k = 0; k < CH; k++) { int b = b0 + k; if (b < NB) { ebase[b] = run; run += v[k]; } }
    if (lane == 63) ebase[NB] = run;
}

// Pass 2: per-bucket node-level counting sort -> offs + cols (coalesced writes).
__global__ __launch_bounds__(256) void buildcsr_k(
        const unsigned* __restrict__ staged, const int* __restrict__ bcur,
        const int* __restrict__ ebase, int* __restrict__ offs, int* __restrict__ cols,
        int N, int NB) {
    __shared__ int h[256], hs[256], curl[256];
    __shared__ int colsl[BCAP];
    int b = blockIdx.x, tid = threadIdx.x;
    int n0 = b << 8;
    int ecnt = bcur[b];
    int base_g = ebase[b];
    const unsigned* sb = staged + (size_t)b * BCAP;

    h[tid] = 0;
    __syncthreads();
    for (int i = tid; i < ecnt; i += 256) atomicAdd(&h[sb[i] >> 17], 1);
    __syncthreads();
    int val = h[tid];
    hs[tid] = val; __syncthreads();
    for (int off = 1; off < 256; off <<= 1) {
        int t = (tid >= off) ? hs[tid - off] : 0;
        __syncthreads();
        hs[tid] += t;
        __syncthreads();
    }
    int excl = hs[tid] - val;
    curl[tid] = excl;
    if (n0 + tid < N) offs[n0 + tid] = base_g + excl;
    if (b == NB - 1 && tid == 0) offs[N] = base_g + ecnt;
    __syncthreads();
    for (int i = tid; i < ecnt; i += 256) {
        unsigned w = sb[i];
        int p = atomicAdd(&curl[w >> 17], 1);
        colsl[p] = (int)(w & 0x1FFFFu);
    }
    __syncthreads();
    for (int i = tid; i < ecnt; i += 256) cols[base_g + i] = colsl[i];
}

// ---------------- W pre-pack into MFMA B-fragment order (hi|lo) ----------------
__global__ void prep_w_k(const float* __restrict__ W, short* __restrict__ Bfs,
                         int K, int N, int NT, int total) {
    int idx = blockIdx.x * blockDim.x + threadIdx.x;
    if (idx >= total) return;  // total = (K/32)*NT*64
    int lane = idx & 63;
    int t = idx >> 6;
    int ntile = t % NT, kstep = t / NT;
    int quad = lane >> 4, nl = lane & 15;
    int n = ntile * 16 + nl;
    bf16_t* dst = (bf16_t*)Bfs + (size_t)idx * 16;
#pragma unroll
    for (int j = 0; j < 8; j++) {
        int k = kstep * 32 + quad * 8 + j;
        float v = W[k * N + n];
        bf16_t h = (bf16_t)v;
        bf16_t l = (bf16_t)(v - (float)h);
        dst[j] = h;
        dst[8 + j] = l;
    }
}

// ---------------- split-bf16 MFMA GEMM ----------------
template <int BM, int WMT, int WNT, int NWM, bool ABF16>
__global__ __launch_bounds__(256) void mfma_gemm_k(
        const void* __restrict__ Av, const short* __restrict__ Bfs,
        float* __restrict__ C, unsigned short* __restrict__ Cb,
        int M, int N, int K, int NT) {
    constexpr int NWN = 4 / NWM;
    constexpr int BN = 16 * WNT * NWN;
    constexpr int KPAD = 40;  // 32 + 8: breaks LDS bank aliasing on b128 reads
    __shared__ __align__(16) bf16_t As_hi[BM * KPAD];
    __shared__ __align__(16) bf16_t As_lo[ABF16 ? 16 : BM * KPAD];
    const bf16_t* Bf = (const bf16_t*)Bfs;

    int tid = threadIdx.x;
    int wave = tid >> 6, lane = tid & 63;
    int quad = lane >> 4, l16 = lane & 15;
    int wm = wave % NWM, wn = wave / NWM;
    int row0 = blockIdx.x * BM;
    int ntile0 = blockIdx.y * (BN / 16) + wn * WNT;

    f32x4 acc[WMT][WNT];
#pragma unroll
    for (int i = 0; i < WMT; i++)
#pragma unroll
        for (int j = 0; j < WNT; j++) acc[i][j] = (f32x4){0.f, 0.f, 0.f, 0.f};

    const int nk = K >> 5;
    const int rA = tid >> 3, kq = tid & 7;  // 8 threads/row, 32 rows/pass

    for (int ks = 0; ks < nk; ks++) {
#pragma unroll
        for (int rr = rA; rr < BM; rr += 32) {
            int grow = row0 + rr;
            if (!ABF16) {
                const float* A = (const float*)Av;
                f32x4 v = (f32x4){0.f, 0.f, 0.f, 0.f};
                if (grow < M)
                    v = *(const f32x4*)(A + (size_t)grow * K + ks * 32 + kq * 4);
                bf16x4 h, l;
#pragma unroll
                for (int j = 0; j < 4; j++) {
                    bf16_t hh = (bf16_t)v[j];
                    h[j] = hh;
                    l[j] = (bf16_t)(v[j] - (float)hh);
                }
                *(bf16x4*)&As_hi[rr * KPAD + kq * 4] = h;
                *(bf16x4*)&As_lo[rr * KPAD + kq * 4] = l;
            } else {
                const unsigned short* A = (const unsigned short*)Av;
                ushort4 v = make_ushort4(0, 0, 0, 0);
                if (grow < M)
                    v = *(const ushort4*)(A + (size_t)grow * K + ks * 32 + kq * 4);
                *(ushort4*)&As_hi[rr * KPAD + kq * 4] = v;
            }
        }
        __syncthreads();

        bf16x8 ah[WMT], al[WMT];
#pragma unroll
        for (int i = 0; i < WMT; i++) {
            int rowl = wm * (WMT * 16) + i * 16 + l16;
            ah[i] = *(const bf16x8*)&As_hi[rowl * KPAD + quad * 8];
            if (!ABF16) al[i] = *(const bf16x8*)&As_lo[rowl * KPAD + quad * 8];
        }
        bf16x8 bh[WNT], bl[WNT];
#pragma unroll
        for (int j = 0; j < WNT; j++) {
            size_t base = ((size_t)(ks * NT + ntile0 + j) * 64 + lane) * 16;
            bh[j] = *(const bf16x8*)&Bf[base];
            bl[j] = *(const bf16x8*)&Bf[base + 8];
        }
#pragma unroll
        for (int i = 0; i < WMT; i++)
#pragma unroll
            for (int j = 0; j < WNT; j++) {
                acc[i][j] = __builtin_amdgcn_mfma_f32_16x16x32_bf16(ah[i], bh[j], acc[i][j], 0, 0, 0);
                if (!ABF16)
                    acc[i][j] = __builtin_amdgcn_mfma_f32_16x16x32_bf16(al[i], bh[j], acc[i][j], 0, 0, 0);
                acc[i][j] = __builtin_amdgcn_mfma_f32_16x16x32_bf16(ah[i], bl[j], acc[i][j], 0, 0, 0);
            }
        __syncthreads();
    }

    // store: D[row = quad*4 + r][col = l16] per 16x16 tile
#pragma unroll
    for (int i = 0; i < WMT; i++) {
        int rbase = row0 + wm * (WMT * 16) + i * 16 + quad * 4;
#pragma unroll
        for (int j = 0; j < WNT; j++) {
            int gcol = (ntile0 + j) * 16 + l16;
#pragma unroll
            for (int r2 = 0; r2 < 4; r2++) {
                int grow = rbase + r2;
                if (grow < M) {
                    float v = acc[i][j][r2];
                    C[(size_t)grow * N + gcol] = v;
                    Cb[(size_t)grow * N + gcol] = bf_bits(v);
                }
            }
        }
    }
}

// ---------------- GEMM (f32 vector, bf16 A) — layer 3 only ----------------
template <int BM, int BN, int BK, int TM, int TN>
__global__ void gemm_k(const unsigned short* __restrict__ Ab, const float* __restrict__ B,
                       float* __restrict__ C, unsigned short* __restrict__ Cb,
                       int M, int Nc, int K) {
    __shared__ float As[BK][BM + 1];
    __shared__ float Bs[BK][BN + 1];
    int tx = threadIdx.x, ty = threadIdx.y;
    int tid = ty * blockDim.x + tx;
    const int nthreads = (BM / TM) * (BN / TN);
    int row0 = blockIdx.x * BM, col0 = blockIdx.y * BN;
    float acc[TM][TN];
#pragma unroll
    for (int i = 0; i < TM; i++)
#pragma unroll
        for (int j = 0; j < TN; j++) acc[i][j] = 0.f;

    for (int k0 = 0; k0 < K; k0 += BK) {
        for (int i = tid; i < BM * BK; i += nthreads) {
            int r = i / BK, kk = i % BK;
            int gr = row0 + r;
            As[kk][r] = (gr < M) ? bf_to_f(Ab[(size_t)gr * K + (k0 + kk)]) : 0.f;
        }
        for (int i = tid; i < BK * BN; i += nthreads) {
            int kk = i / BN, c = i % BN;
            int gc = col0 + c;
            Bs[kk][c] = (gc < Nc) ? B[(long)(k0 + kk) * Nc + gc] : 0.f;
        }
        __syncthreads();
#pragma unroll
        for (int kk = 0; kk < BK; ++kk) {
            float a[TM], b[TN];
#pragma unroll
            for (int i = 0; i < TM; i++) a[i] = As[kk][ty * TM + i];
#pragma unroll
            for (int j = 0; j < TN; j++) b[j] = Bs[kk][tx * TN + j];
#pragma unroll
            for (int i = 0; i < TM; i++)
#pragma unroll
                for (int j = 0; j < TN; j++) acc[i][j] = fmaf(a[i], b[j], acc[i][j]);
        }
        __syncthreads();
    }
#pragma unroll
    for (int i = 0; i < TM; i++) {
        int gr = row0 + ty * TM + i;
        if (gr >= M) continue;
#pragma unroll
        for (int j = 0; j < TN; j++) {
            int gc = col0 + tx * TN + j;
            if (gc < Nc) {
                C[(long)gr * Nc + gc] = acc[i][j];
                Cb[(long)gr * Nc + gc] = bf_bits(acc[i][j]);
            }
        }
    }
}

// ---------------- alpha_src / alpha_dst (reads exact f32 xp) ----------------
template <int H, int C>
__global__ void alpha_k(const float* __restrict__ xp, const float* __restrict__ a_s,
                        const float* __restrict__ a_d, float* __restrict__ out_s,
                        float* __restrict__ out_d, int NH) {
    int i = blockIdx.x * blockDim.x + threadIdx.x;
    if (i >= NH) return;
    int h = i % H;
    const float* v = xp + (long)i * C;
    float ss = 0.f, sd = 0.f;
#pragma unroll
    for (int c = 0; c < C; c++) {
        float x = v[c];
        ss = fmaf(x, a_s[h * C + c], ss);
        sd = fmaf(x, a_d[h * C + c], sd);
    }
    out_s[i] = ss;
    out_d[i] = sd;
}

// ---------------- attention aggregation, H=8: one wave per node ----------------
// cols holds real edges only; the self-loop is implicit.
// C=16: lane owns feats {2*lane, 2*lane+1}; src rows via readlane (scalar addr).
// C=8: two 32-lane halves each process one edge/iter (128B row each).
template <int C, bool DO_ELU>
__global__ void agg8_k(const unsigned short* __restrict__ xpb,
                       const float* __restrict__ asrc, const float* __restrict__ adst,
                       const int* __restrict__ offs, const int* __restrict__ cols,
                       const float* __restrict__ bias, unsigned short* __restrict__ outb,
                       int N) {
    constexpr int HC = 8 * C;
    int gtid = blockIdx.x * blockDim.x + threadIdx.x;
    int n = gtid >> 6;
    if (n >= N) return;
    int lane = threadIdx.x & 63;
    int j = lane >> 3, h = lane & 7;
    int start = offs[n], end = offs[n + 1];

    float ad_l = adst[n * 8 + h];
    float vs = asrc[n * 8 + h] + ad_l;  // self-loop logit for head h
    vs = LEAKY(vs);

    // phase 1: online softmax stats for head h over edge-slots j, j+8, ...
    float m, s;
    if (j == 0) { m = vs; s = 1.f; } else { m = -1e30f; s = 0.f; }
    for (int e = start + j; e < end; e += 8) {
        int src = cols[e];
        float v = asrc[src * 8 + h] + ad_l;
        v = LEAKY(v);
        float mo = fmaxf(m, v);
        s = s * __expf(m - mo) + __expf(v - mo);
        m = mo;
    }
#pragma unroll
    for (int off = 8; off <= 32; off <<= 1) {
        float mo = __shfl_xor(m, off, 64);
        float so = __shfl_xor(s, off, 64);
        float mn = fmaxf(m, mo);
        s = s * __expf(m - mn) + so * __expf(mo - mn);
        m = mn;
    }
    float rs = 1.f / (s + 1e-16f);
    float wself_l = __expf(vs - m) * rs;  // per-head self weight

    if (C == 16) {
        const int h2x4 = (lane >> 3) << 2;  // head byte-addr for bpermute
        float a0 = 0.f, a1 = 0.f;
        {   // implicit self contribution
            float wself = bperm_f(h2x4, wself_l);
            unsigned u = ((const unsigned*)(xpb + (size_t)n * HC))[lane];
            a0 = fmaf(wself, __uint_as_float(u << 16), a0);
            a1 = fmaf(wself, __uint_as_float(u & 0xffff0000u), a1);
        }
        for (int c0 = start; c0 < end; c0 += 8) {
            int e = c0 + j;
            float w_l = 0.f; int src_l = 0;
            if (e < end) {
                src_l = cols[e];
                float v = asrc[src_l * 8 + h] + ad_l;
                v = LEAKY(v);
                w_l = __expf(v - m) * rs;
            }
            int nj = end - c0; if (nj > 8) nj = 8;
            if (nj == 8) {
#pragma unroll
                for (int j2 = 0; j2 < 8; j2++) {
                    int srcj = __builtin_amdgcn_readlane(src_l, j2 * 8);  // uniform
                    float w = bperm_f(h2x4 + j2 * 32, w_l);
                    unsigned u = ((const unsigned*)(xpb + (size_t)srcj * HC))[lane];
                    a0 = fmaf(w, __uint_as_float(u << 16), a0);
                    a1 = fmaf(w, __uint_as_float(u & 0xffff0000u), a1);
                }
            } else {
                for (int j2 = 0; j2 < nj; j2++) {
                    int srcj = __builtin_amdgcn_readlane(src_l, j2 * 8);
                    float w = bperm_f(h2x4 + j2 * 32, w_l);
                    unsigned u = ((const unsigned*)(xpb + (size_t)srcj * HC))[lane];
                    a0 = fmaf(w, __uint_as_float(u << 16), a0);
                    a1 = fmaf(w, __uint_as_float(u & 0xffff0000u), a1);
                }
            }
        }
        float o0 = a0 + bias[2 * lane];
        float o1 = a1 + bias[2 * lane + 1];
        if (DO_ELU) {
            o0 = o0 > 0.f ? o0 : __expf(o0) - 1.f;
            o1 = o1 > 0.f ? o1 : __expf(o1) - 1.f;
        }
        unsigned packed = (unsigned)bf_bits(o0) | ((unsigned)bf_bits(o1) << 16);
        ((unsigned*)(outb + (size_t)n * HC))[lane] = packed;
    } else {  // C == 8: row = 32 uints; half-wave per edge, 2 edges/iter
        const unsigned* xp32 = (const unsigned*)xpb;
        int fp = lane & 31;        // feature-pair index: feats {2fp, 2fp+1}
        int h2 = fp >> 2;          // head of this feature pair
        int half = lane >> 5;      // which edge of the pair
        int woff = half * 32 + h2 * 4;
        int soff = half * 32;      // head-0 lane of this edge slot
        float a0 = 0.f, a1 = 0.f;
        {   // implicit self contribution (half 0 only; halves summed later)
            float wself = bperm_f(h2 * 4, wself_l);
            if (half == 0) {
                unsigned u = xp32[(size_t)n * 32 + fp];
                a0 = fmaf(wself, __uint_as_float(u << 16), a0);
                a1 = fmaf(wself, __uint_as_float(u & 0xffff0000u), a1);
            }
        }
        for (int c0 = start; c0 < end; c0 += 8) {
            int e = c0 + j;
            float w_l = 0.f; int src_l = 0;
            if (e < end) {
                src_l = cols[e];
                float v = asrc[src_l * 8 + h] + ad_l;
                v = LEAKY(v);
                w_l = __expf(v - m) * rs;
            }
            int nj = end - c0; if (nj > 8) nj = 8;
            int npair = (nj + 1) >> 1;
            if (npair == 4) {
#pragma unroll
                for (int j2 = 0; j2 < 4; j2++) {
                    int srcv = __builtin_amdgcn_ds_bpermute(soff + j2 * 64, src_l);
                    float w = bperm_f(woff + j2 * 64, w_l);
                    unsigned u = xp32[(size_t)srcv * 32 + fp];
                    a0 = fmaf(w, __uint_as_float(u << 16), a0);
                    a1 = fmaf(w, __uint_as_float(u & 0xffff0000u), a1);
                }
            } else {
                for (int j2 = 0; j2 < npair; j2++) {
                    int srcv = __builtin_amdgcn_ds_bpermute(soff + j2 * 64, src_l);
                    float w = bperm_f(woff + j2 * 64, w_l);
                    unsigned u = xp32[(size_t)srcv * 32 + fp];
                    a0 = fmaf(w, __uint_as_float(u << 16), a0);
                    a1 = fmaf(w, __uint_as_float(u & 0xffff0000u), a1);
                }
            }
        }
        // combine halves
        a0 += __shfl_xor(a0, 32, 64);
        a1 += __shfl_xor(a1, 32, 64);
        if (half == 0) {
            float o0 = a0 + bias[2 * fp];
            float o1 = a1 + bias[2 * fp + 1];
            if (DO_ELU) {
                o0 = o0 > 0.f ? o0 : __expf(o0) - 1.f;
                o1 = o1 > 0.f ? o1 : __expf(o1) - 1.f;
            }
            unsigned packed = (unsigned)bf_bits(o0) | ((unsigned)bf_bits(o1) << 16);
            ((unsigned*)(outb + (size_t)n * HC))[fp] = packed;
        }
    }
}

// ---------------- aggregation H=1 C=10 + fused log_softmax (layer 3) ----------------
__global__ void agg1h_k(const unsigned short* __restrict__ xpb,
                        const float* __restrict__ asrc, const float* __restrict__ adst,
                        const int* __restrict__ offs, const int* __restrict__ cols,
                        const float* __restrict__ bias, float* __restrict__ out, int N) {
    int gtid = blockIdx.x * blockDim.x + threadIdx.x;
    int n = gtid >> 6;
    if (n >= N) return;
    int lane = threadIdx.x & 63;
    int start = offs[n], end = offs[n + 1];
    float ad = adst[n];
    float vs = asrc[n] + ad;  // implicit self-loop
    vs = LEAKY(vs);

    float m, s;
    if (lane == 0) { m = vs; s = 1.f; } else { m = -1e30f; s = 0.f; }
    for (int e = start + lane; e < end; e += 64) {
        float v = asrc[cols[e]] + ad;
        v = LEAKY(v);
        float mo = fmaxf(m, v);
        s = s * __expf(m - mo) + __expf(v - mo);
        m = mo;
    }
#pragma unroll
    for (int off = 1; off <= 32; off <<= 1) {
        float mo = __shfl_xor(m, off, 64);
        float so = __shfl_xor(s, off, 64);
        float mn = fmaxf(m, mo);
        s = s * __expf(m - mn) + so * __expf(mo - mn);
        m = mn;
    }
    float rs = 1.f / (s + 1e-16f);
    float wself = __expf(vs - m) * rs;

    int j = lane / 10, c = lane - j * 10;
    float acc = 0.f;
    if (j == 0) acc = wself * bf_to_f(xpb[(size_t)n * 10 + c]);  // self term
    for (int c0 = start; c0 < end; c0 += 6) {
        int e = c0 + j;
        if (j < 6 && e < end) {
            int src = cols[e];
            float v = asrc[src] + ad;
            v = LEAKY(v);
            float w = __expf(v - m) * rs;
            acc = fmaf(w, bf_to_f(xpb[(size_t)src * 10 + c]), acc);
        }
    }
    float tot = acc;
#pragma unroll
    for (int k = 1; k < 6; k++) tot += __shfl(acc, lane + 10 * k, 64);

    // fused log_softmax over the 10 classes (valid in lanes 0-9)
    float z = tot + bias[lane < 10 ? lane : 0];
    float mx = -1e30f;
#pragma unroll
    for (int k = 0; k < 10; k++) mx = fmaxf(mx, __shfl(z, k, 64));
    float se = 0.f;
#pragma unroll
    for (int k = 0; k < 10; k++) se += __expf(__shfl(z, k, 64) - mx);
    if (lane < 10) out[(size_t)n * 10 + lane] = z - (__logf(se) + mx);
}

// ---------------- launch ----------------

static inline size_t alignup(size_t x) { return (x + 255) & ~(size_t)255; }

extern "C" void kernel_launch(void* const* d_in, const int* in_sizes, int n_in,
                              void* d_out, int out_size, void* d_ws, size_t ws_size,
                              hipStream_t stream) {
    const float* x   = (const float*)d_in[0];
    const int*   ei  = (const int*)d_in[1];
    const float* W1  = (const float*)d_in[2];
    const float* a1s = (const float*)d_in[3];
    const float* a1d = (const float*)d_in[4];
    const float* b1  = (const float*)d_in[5];
    const float* W2  = (const float*)d_in[6];
    const float* a2s = (const float*)d_in[7];
    const float* a2d = (const float*)d_in[8];
    const float* b2  = (const float*)d_in[9];
    const float* W3  = (const float*)d_in[10];
    const float* a3s = (const float*)d_in[11];
    const float* a3d = (const float*)d_in[12];
    const float* b3  = (const float*)d_in[13];
    float* out = (float*)d_out;

    const int N = in_sizes[0] / 256;
    const int E = in_sizes[1] / 2;
    const int* src = ei;
    const int* dst = ei + E;
    const int NB = (N + 255) >> 8;  // 391 for N=100000 (<= NB_MAX)

    char* p = (char*)d_ws;
    int* offs    = (int*)p; p += alignup(sizeof(int) * (size_t)(N + 1));
    int* bcur    = (int*)p; p += alignup(sizeof(int) * (size_t)(NB_MAX + 1));
    int* ebase   = (int*)p; p += alignup(sizeof(int) * (size_t)(NB_MAX + 1));
    int* cols    = (int*)p; p += alignup(sizeof(int) * (size_t)E);
    unsigned short* xpb   = (unsigned short*)p; p += alignup(2 * (size_t)N * 128);
    unsigned short* hbufb = (unsigned short*)p; p += alignup(2 * (size_t)N * 128);
    float* xp    = (float*)p; p += alignup(sizeof(float) * (size_t)N * 128);
    float* as_   = (float*)p; p += alignup(sizeof(float) * (size_t)N * 8);
    float* ad_   = (float*)p; p += alignup(sizeof(float) * (size_t)N * 8);
    short* Bf1   = (short*)p; p += alignup(sizeof(short) * 8 * 8 * 64 * 16);  // K=256,N=128
    short* Bf2   = (short*)p; p += alignup(sizeof(short) * 4 * 4 * 64 * 16);  // K=128,N=64
    // staged bucket regions alias xp: CSR build finishes before gemm1 writes xp.
    unsigned* staged = (unsigned*)xp;  // NB * BCAP * 4B = 8 MB << 51.2 MB

    const int TB = 256;

    // CSR build: bucketed counting sort (self-loops implicit in agg)
    zero_k<<<(NB + TB - 1) / TB, TB, 0, stream>>>(bcur, NB);
    partition_k<<<(E + 4095) / 4096, 256, 0, stream>>>(src, dst, E, NB, bcur, staged);
    scan_nb_k<<<1, 64, 0, stream>>>(bcur, ebase, NB);
    buildcsr_k<<<NB, 256, 0, stream>>>(staged, bcur, ebase, offs, cols, N, NB);

    // W pre-pack (fragment order, hi|lo)
    prep_w_k<<<(4096 + TB - 1) / TB, TB, 0, stream>>>(W1, Bf1, 256, 128, 8, 4096);
    prep_w_k<<<(1024 + TB - 1) / TB, TB, 0, stream>>>(W2, Bf2, 128, 64, 4, 1024);

    // ---- layer 1: 256 -> 128 (H=8, C=16), ELU
    mfma_gemm_k<128, 4, 4, 2, false><<<dim3((N + 127) / 128, 1), 256, 0, stream>>>(
        x, Bf1, xp, xpb, N, 128, 256, 8);
    alpha_k<8, 16><<<(N * 8 + TB - 1) / TB, TB, 0, stream>>>(xp, a1s, a1d, as_, ad_, N * 8);
    agg8_k<16, true><<<(N * 64 + TB - 1) / TB, TB, 0, stream>>>(
        xpb, as_, ad_, offs, cols, b1, hbufb, N);

    // ---- layer 2: 128 -> 64 (H=8, C=8), ELU  (A is bf16 agg output)
    mfma_gemm_k<128, 2, 4, 4, true><<<dim3((N + 127) / 128, 1), 256, 0, stream>>>(
        hbufb, Bf2, xp, xpb, N, 64, 128, 4);
    alpha_k<8, 8><<<(N * 8 + TB - 1) / TB, TB, 0, stream>>>(xp, a2s, a2d, as_, ad_, N * 8);
    agg8_k<8, true><<<(N * 64 + TB - 1) / TB, TB, 0, stream>>>(
        xpb, as_, ad_, offs, cols, b2, hbufb, N);

    // ---- layer 3: 64 -> 10 (H=1, C=10) + fused log_softmax
    gemm_k<64, 16, 16, 4, 1><<<dim3((N + 63) / 64, 1), dim3(16, 16), 0, stream>>>(
        hbufb, W3, xp, xpb, N, 10, 64);
    alpha_k<1, 10><<<(N + TB - 1) / TB, TB, 0, stream>>>(xp, a3s, a3d, as_, ad_, N);
    agg1h_k<<<(N * 64 + TB - 1) / TB, TB, 0, stream>>>(
        xpb, as_, ad_, offs, cols, b3, out, N);
}

// Round 8
// 528.513 us; speedup vs baseline: 2.5351x; 1.0914x over previous
//
#include <hip/hip_runtime.h>
#include <hip/hip_bf16.h>
#include <math.h>

// ---------------------------------------------------------------------------
// GAT 3-layer forward on MI355X.
//   1. Dest-CSR via 2-pass bucketed counting sort (coalesced writes; LDS
//      bucket-id array instead of per-element binary search).
//      Self-loops are implicit in the aggregation kernels.
//   2. Layers 1-2: split-bf16 MFMA GEMM with alpha_src/dst FUSED into the
//      epilogue (head = 16-col tile for C=16, 8-lane group for C=8); writes
//      bf16 C only. Layer 3: f32 vector GEMM (tiny).
//   3. Single-pass online-softmax aggregation (phase 1 merged into phase 2
//      via running rescale): one walk of cols/asrc, unnormalized accumulate,
//      divide by s at the end. Layer-3 agg fuses log_softmax -> d_out.
//   R8 fix: agg16_k output row stride was 256 shorts (2x) — now 128 shorts.
// ---------------------------------------------------------------------------

#define LEAKY(v) ((v) > 0.f ? (v) : 0.2f * (v))

typedef __bf16 bf16_t;
typedef __bf16 bf16x8 __attribute__((ext_vector_type(8)));
typedef __bf16 bf16x4 __attribute__((ext_vector_type(4)));
typedef float f32x4 __attribute__((ext_vector_type(4)));

static __device__ __forceinline__ unsigned short bf_bits(float f) {
    bf16_t b = (bf16_t)f;
    return __builtin_bit_cast(unsigned short, b);
}
static __device__ __forceinline__ float bf_to_f(unsigned short u) {
    return __uint_as_float(((unsigned int)u) << 16);
}
static __device__ __forceinline__ float bperm_f(int byteaddr, float v) {
    return __uint_as_float((unsigned)__builtin_amdgcn_ds_bpermute(byteaddr, (int)__float_as_uint(v)));
}

// ---------------- CSR build: 2-pass bucket sort ----------------
constexpr int NB_MAX = 400;
constexpr int BCAP = 5120;  // capacity per bucket region; mean load 4096

__global__ void zero_k(int* a, int n) {
    int i = blockIdx.x * blockDim.x + threadIdx.x;
    if (i < n) a[i] = 0;
}

// Pass 1: partition edges into bucket regions with block-local grouping.
__global__ __launch_bounds__(256) void partition_k(
        const int* __restrict__ src, const int* __restrict__ dst, int E, int NB,
        int* __restrict__ bcur, unsigned* __restrict__ staged) {
    __shared__ int hist[NB_MAX];
    __shared__ int bstart[NB_MAX + 1];
    __shared__ int cur[NB_MAX];
    __shared__ int gbase[NB_MAX];
    __shared__ unsigned words[4096];
    __shared__ unsigned short bidl[4096];
    int tid = threadIdx.x;
    int e0 = blockIdx.x * 4096;
    int cnt = E - e0; if (cnt > 4096) cnt = 4096;
    if (cnt <= 0) return;

    for (int b = tid; b < NB; b += 256) hist[b] = 0;
    __syncthreads();
    for (int i = tid; i < cnt; i += 256) atomicAdd(&hist[dst[e0 + i] >> 8], 1);
    __syncthreads();
    if (tid == 0) {
        int run = 0;
        for (int b = 0; b < NB; b++) { bstart[b] = run; run += hist[b]; }
        bstart[NB] = run;
    }
    __syncthreads();
    for (int b = tid; b < NB; b += 256) {
        cur[b] = bstart[b];
        gbase[b] = hist[b] ? atomicAdd(&bcur[b], hist[b]) : 0;
    }
    __syncthreads();
    // group into LDS by bucket, remember bucket id per slot
    for (int i = tid; i < cnt; i += 256) {
        int s = src[e0 + i], d = dst[e0 + i];
        int b = d >> 8;
        unsigned w = (unsigned)s | ((unsigned)(d & 255) << 17);
        int p = atomicAdd(&cur[b], 1);
        words[p] = w;
        bidl[p] = (unsigned short)b;
    }
    __syncthreads();
    // linear sweep -> coalesced runs into global bucket regions
    for (int i = tid; i < cnt; i += 256) {
        int b = bidl[i];
        staged[(size_t)b * BCAP + gbase[b] + (i - bstart[b])] = words[i];
    }
}

// tiny exclusive scan over NB bucket counts (one wave)
__global__ void scan_nb_k(const int* __restrict__ bcur, int* __restrict__ ebase, int NB) {
    int lane = threadIdx.x;  // 64 threads
    int CH = (NB + 63) / 64;
    int b0 = lane * CH;
    int v[8]; int s = 0;
#pragma unroll 8
    for (int k = 0; k < CH; k++) { int b = b0 + k; int t = (b < NB) ? bcur[b] : 0; if (k < 8) v[k] = t; s += t; }
    int orig = s;
    for (int off = 1; off < 64; off <<= 1) {
        int t = __shfl_up(s, off, 64);
        if (lane >= off) s += t;
    }
    int run = s - orig;  // exclusive
    for (int k = 0; k < CH; k++) { int b = b0 + k; if (b < NB) { ebase[b] = run; run += v[k]; } }
    if (lane == 63) ebase[NB] = run;
}

// Pass 2: per-bucket node-level counting sort -> offs + cols (coalesced writes).
__global__ __launch_bounds__(256) void buildcsr_k(
        const unsigned* __restrict__ staged, const int* __restrict__ bcur,
        const int* __restrict__ ebase, int* __restrict__ offs, int* __restrict__ cols,
        int N, int NB) {
    __shared__ int h[256], hs[256], curl[256];
    __shared__ int colsl[BCAP];
    int b = blockIdx.x, tid = threadIdx.x;
    int n0 = b << 8;
    int ecnt = bcur[b];
    int base_g = ebase[b];
    const unsigned* sb = staged + (size_t)b * BCAP;

    h[tid] = 0;
    __syncthreads();
    for (int i = tid; i < ecnt; i += 256) atomicAdd(&h[sb[i] >> 17], 1);
    __syncthreads();
    int val = h[tid];
    hs[tid] = val; __syncthreads();
    for (int off = 1; off < 256; off <<= 1) {
        int t = (tid >= off) ? hs[tid - off] : 0;
        __syncthreads();
        hs[tid] += t;
        __syncthreads();
    }
    int excl = hs[tid] - val;
    curl[tid] = excl;
    if (n0 + tid < N) offs[n0 + tid] = base_g + excl;
    if (b == NB - 1 && tid == 0) offs[N] = base_g + ecnt;
    __syncthreads();
    for (int i = tid; i < ecnt; i += 256) {
        unsigned w = sb[i];
        int p = atomicAdd(&curl[w >> 17], 1);
        colsl[p] = (int)(w & 0x1FFFFu);
    }
    __syncthreads();
    for (int i = tid; i < ecnt; i += 256) cols[base_g + i] = colsl[i];
}

// ---------------- W pre-pack into MFMA B-fragment order (hi|lo) ----------------
__global__ void prep_w_k(const float* __restrict__ W, short* __restrict__ Bfs,
                         int K, int N, int NT, int total) {
    int idx = blockIdx.x * blockDim.x + threadIdx.x;
    if (idx >= total) return;  // total = (K/32)*NT*64
    int lane = idx & 63;
    int t = idx >> 6;
    int ntile = t % NT, kstep = t / NT;
    int quad = lane >> 4, nl = lane & 15;
    int n = ntile * 16 + nl;
    bf16_t* dst = (bf16_t*)Bfs + (size_t)idx * 16;
#pragma unroll
    for (int j = 0; j < 8; j++) {
        int k = kstep * 32 + quad * 8 + j;
        float v = W[k * N + n];
        bf16_t h = (bf16_t)v;
        bf16_t l = (bf16_t)(v - (float)h);
        dst[j] = h;
        dst[8 + j] = l;
    }
}

// ---------------- split-bf16 MFMA GEMM, fused alpha epilogue ----------------
// Writes Cb (bf16) + alpha_src/alpha_dst [M, N/CHEAD] (f32, exact from acc).
template <int BM, int WMT, int WNT, int NWM, bool ABF16, int CHEAD>
__global__ __launch_bounds__(256) void mfma_gemm_k(
        const void* __restrict__ Av, const short* __restrict__ Bfs,
        unsigned short* __restrict__ Cb,
        const float* __restrict__ a_s, const float* __restrict__ a_d,
        float* __restrict__ out_as, float* __restrict__ out_ad,
        int M, int N, int K, int NT) {
    constexpr int NWN = 4 / NWM;
    constexpr int BN = 16 * WNT * NWN;
    constexpr int KPAD = 40;  // 32 + 8: breaks LDS bank aliasing on b128 reads
    __shared__ __align__(16) bf16_t As_hi[BM * KPAD];
    __shared__ __align__(16) bf16_t As_lo[ABF16 ? 16 : BM * KPAD];
    const bf16_t* Bf = (const bf16_t*)Bfs;

    int tid = threadIdx.x;
    int wave = tid >> 6, lane = tid & 63;
    int quad = lane >> 4, l16 = lane & 15;
    int wm = wave % NWM, wn = wave / NWM;
    int row0 = blockIdx.x * BM;
    int ntile0 = blockIdx.y * (BN / 16) + wn * WNT;

    f32x4 acc[WMT][WNT];
#pragma unroll
    for (int i = 0; i < WMT; i++)
#pragma unroll
        for (int j = 0; j < WNT; j++) acc[i][j] = (f32x4){0.f, 0.f, 0.f, 0.f};

    const int nk = K >> 5;
    const int rA = tid >> 3, kq = tid & 7;  // 8 threads/row, 32 rows/pass

    for (int ks = 0; ks < nk; ks++) {
#pragma unroll
        for (int rr = rA; rr < BM; rr += 32) {
            int grow = row0 + rr;
            if (!ABF16) {
                const float* A = (const float*)Av;
                f32x4 v = (f32x4){0.f, 0.f, 0.f, 0.f};
                if (grow < M)
                    v = *(const f32x4*)(A + (size_t)grow * K + ks * 32 + kq * 4);
                bf16x4 h, l;
#pragma unroll
                for (int j = 0; j < 4; j++) {
                    bf16_t hh = (bf16_t)v[j];
                    h[j] = hh;
                    l[j] = (bf16_t)(v[j] - (float)hh);
                }
                *(bf16x4*)&As_hi[rr * KPAD + kq * 4] = h;
                *(bf16x4*)&As_lo[rr * KPAD + kq * 4] = l;
            } else {
                const unsigned short* A = (const unsigned short*)Av;
                ushort4 v = make_ushort4(0, 0, 0, 0);
                if (grow < M)
                    v = *(const ushort4*)(A + (size_t)grow * K + ks * 32 + kq * 4);
                *(ushort4*)&As_hi[rr * KPAD + kq * 4] = v;
            }
        }
        __syncthreads();

        bf16x8 ah[WMT], al[WMT];
#pragma unroll
        for (int i = 0; i < WMT; i++) {
            int rowl = wm * (WMT * 16) + i * 16 + l16;
            ah[i] = *(const bf16x8*)&As_hi[rowl * KPAD + quad * 8];
            if (!ABF16) al[i] = *(const bf16x8*)&As_lo[rowl * KPAD + quad * 8];
        }
        bf16x8 bh[WNT], bl[WNT];
#pragma unroll
        for (int j = 0; j < WNT; j++) {
            size_t base = ((size_t)(ks * NT + ntile0 + j) * 64 + lane) * 16;
            bh[j] = *(const bf16x8*)&Bf[base];
            bl[j] = *(const bf16x8*)&Bf[base + 8];
        }
#pragma unroll
        for (int i = 0; i < WMT; i++)
#pragma unroll
            for (int j = 0; j < WNT; j++) {
                acc[i][j] = __builtin_amdgcn_mfma_f32_16x16x32_bf16(ah[i], bh[j], acc[i][j], 0, 0, 0);
                if (!ABF16)
                    acc[i][j] = __builtin_amdgcn_mfma_f32_16x16x32_bf16(al[i], bh[j], acc[i][j], 0, 0, 0);
                acc[i][j] = __builtin_amdgcn_mfma_f32_16x16x32_bf16(ah[i], bl[j], acc[i][j], 0, 0, 0);
            }
        __syncthreads();
    }

    // bf16 C store: D[row = quad*4 + r][col = l16] per 16x16 tile
#pragma unroll
    for (int i = 0; i < WMT; i++) {
        int rbase = row0 + wm * (WMT * 16) + i * 16 + quad * 4;
#pragma unroll
        for (int j = 0; j < WNT; j++) {
            int gcol = (ntile0 + j) * 16 + l16;
#pragma unroll
            for (int r2 = 0; r2 < 4; r2++) {
                int grow = rbase + r2;
                if (grow < M) Cb[(size_t)grow * N + gcol] = bf_bits(acc[i][j][r2]);
            }
        }
    }

    // fused alpha: per tile j, coef = a_flat[gcol]; reduce over CHEAD-lane groups
    const int Hh = N / CHEAD;
#pragma unroll
    for (int j = 0; j < WNT; j++) {
        int gcol = (ntile0 + j) * 16 + l16;
        float cs = a_s[gcol], cd = a_d[gcol];
#pragma unroll
        for (int i = 0; i < WMT; i++) {
            float ps[4], pd[4];
#pragma unroll
            for (int r2 = 0; r2 < 4; r2++) {
                ps[r2] = acc[i][j][r2] * cs;
                pd[r2] = acc[i][j][r2] * cd;
            }
#pragma unroll
            for (int off = 1; off < CHEAD; off <<= 1) {
#pragma unroll
                for (int r2 = 0; r2 < 4; r2++) {
                    ps[r2] += __shfl_xor(ps[r2], off, 64);
                    pd[r2] += __shfl_xor(pd[r2], off, 64);
                }
            }
            if ((l16 & (CHEAD - 1)) == 0) {
                int hd = gcol / CHEAD;
                int rb = row0 + wm * (WMT * 16) + i * 16 + quad * 4;
#pragma unroll
                for (int r2 = 0; r2 < 4; r2++) {
                    int grow = rb + r2;
                    if (grow < M) {
                        out_as[(size_t)grow * Hh + hd] = ps[r2];
                        out_ad[(size_t)grow * Hh + hd] = pd[r2];
                    }
                }
            }
        }
    }
}

// ---------------- GEMM (f32 vector, bf16 A) — layer 3 only ----------------
template <int BM, int BN, int BK, int TM, int TN>
__global__ void gemm_k(const unsigned short* __restrict__ Ab, const float* __restrict__ B,
                       float* __restrict__ C, unsigned short* __restrict__ Cb,
                       int M, int Nc, int K) {
    __shared__ float As[BK][BM + 1];
    __shared__ float Bs[BK][BN + 1];
    int tx = threadIdx.x, ty = threadIdx.y;
    int tid = ty * blockDim.x + tx;
    const int nthreads = (BM / TM) * (BN / TN);
    int row0 = blockIdx.x * BM, col0 = blockIdx.y * BN;
    float acc[TM][TN];
#pragma unroll
    for (int i = 0; i < TM; i++)
#pragma unroll
        for (int j = 0; j < TN; j++) acc[i][j] = 0.f;

    for (int k0 = 0; k0 < K; k0 += BK) {
        for (int i = tid; i < BM * BK; i += nthreads) {
            int r = i / BK, kk = i % BK;
            int gr = row0 + r;
            As[kk][r] = (gr < M) ? bf_to_f(Ab[(size_t)gr * K + (k0 + kk)]) : 0.f;
        }
        for (int i = tid; i < BK * BN; i += nthreads) {
            int kk = i / BN, c = i % BN;
            int gc = col0 + c;
            Bs[kk][c] = (gc < Nc) ? B[(long)(k0 + kk) * Nc + gc] : 0.f;
        }
        __syncthreads();
#pragma unroll
        for (int kk = 0; kk < BK; ++kk) {
            float a[TM], b[TN];
#pragma unroll
            for (int i = 0; i < TM; i++) a[i] = As[kk][ty * TM + i];
#pragma unroll
            for (int j = 0; j < TN; j++) b[j] = Bs[kk][tx * TN + j];
#pragma unroll
            for (int i = 0; i < TM; i++)
#pragma unroll
                for (int j = 0; j < TN; j++) acc[i][j] = fmaf(a[i], b[j], acc[i][j]);
        }
        __syncthreads();
    }
#pragma unroll
    for (int i = 0; i < TM; i++) {
        int gr = row0 + ty * TM + i;
        if (gr >= M) continue;
#pragma unroll
        for (int j = 0; j < TN; j++) {
            int gc = col0 + tx * TN + j;
            if (gc < Nc) {
                C[(long)gr * Nc + gc] = acc[i][j];
                Cb[(long)gr * Nc + gc] = bf_bits(acc[i][j]);
            }
        }
    }
}

// ---------------- alpha (layer 3 only) ----------------
template <int H, int C>
__global__ void alpha_k(const float* __restrict__ xp, const float* __restrict__ a_s,
                        const float* __restrict__ a_d, float* __restrict__ out_s,
                        float* __restrict__ out_d, int NH) {
    int i = blockIdx.x * blockDim.x + threadIdx.x;
    if (i >= NH) return;
    int h = i % H;
    const float* v = xp + (long)i * C;
    float ss = 0.f, sd = 0.f;
#pragma unroll
    for (int c = 0; c < C; c++) {
        float x = v[c];
        ss = fmaf(x, a_s[h * C + c], ss);
        sd = fmaf(x, a_d[h * C + c], sd);
    }
    out_s[i] = ss;
    out_d[i] = sd;
}

// ---------------- single-pass aggregation, H=8 C=16 (layer 1) ----------------
// One wave per node. Lane role: weight (j=lane>>3, h=lane&7) AND feature
// (feats {2*lane,2*lane+1}, head = lane>>3 = j). Online rescale, unnormalized
// accumulate, divide by s at the end. Self-loop implicit.
template <bool DO_ELU>
__global__ void agg16_k(const unsigned short* __restrict__ xpb,
                        const float* __restrict__ asrc, const float* __restrict__ adst,
                        const int* __restrict__ offs, const int* __restrict__ cols,
                        const float* __restrict__ bias, unsigned short* __restrict__ outb,
                        int N) {
    int gtid = blockIdx.x * blockDim.x + threadIdx.x;
    int n = gtid >> 6;
    if (n >= N) return;
    int lane = threadIdx.x & 63;
    int j = lane >> 3, h = lane & 7;
    const int jb = j << 2;  // bpermute byte addr of (j=0, h=j) lane
    int start = offs[n], end = offs[n + 1];
    const unsigned* xp32 = (const unsigned*)xpb;

    float ad_l = adst[n * 8 + h];
    float vs = asrc[n * 8 + h] + ad_l;
    vs = LEAKY(vs);

    // weight-role state (head h): seeded with implicit self-loop
    float m_w = vs;
    float s = (j == 0) ? 1.f : 0.f;
    // feature-role state (head j): acc = self row (weight exp(vs-vs)=1)
    float m_f = bperm_f(jb, vs);
    unsigned uself = xp32[(size_t)n * 64 + lane];
    float a0 = __uint_as_float(uself << 16);
    float a1 = __uint_as_float(uself & 0xffff0000u);

    for (int c0 = start; c0 < end; c0 += 8) {
        int e = c0 + j;
        bool valid = e < end;
        int src_l = valid ? cols[e] : 0;
        float v = -1e30f;
        if (valid) {
            v = asrc[src_l * 8 + h] + ad_l;
            v = LEAKY(v);
        }
        // chunk max over j (per head h)
        float cm = v;
        cm = fmaxf(cm, __shfl_xor(cm, 8, 64));
        cm = fmaxf(cm, __shfl_xor(cm, 16, 64));
        cm = fmaxf(cm, __shfl_xor(cm, 32, 64));
        // weight-role update
        float mw_new = fmaxf(m_w, cm);
        float w_raw = __expf(v - mw_new);  // 0 for invalid slots
        s = s * __expf(m_w - mw_new) + w_raw;
        m_w = mw_new;
        // feature-role rescale (head j)
        float cmF = bperm_f(jb, cm);
        float mf_new = fmaxf(m_f, cmF);
        float scF = __expf(m_f - mf_new);
        m_f = mf_new;
        a0 *= scF; a1 *= scF;
        // accumulate 8 edges (invalid -> w=0, gathers hot row 0)
#pragma unroll
        for (int j2 = 0; j2 < 8; j2++) {
            int srcj = __builtin_amdgcn_readlane(src_l, j2 * 8);
            float w = bperm_f(jb + j2 * 32, w_raw);
            unsigned u = xp32[(size_t)srcj * 64 + lane];
            a0 = fmaf(w, __uint_as_float(u << 16), a0);
            a1 = fmaf(w, __uint_as_float(u & 0xffff0000u), a1);
        }
    }
    // finalize: total s per head, then normalize
    s += __shfl_xor(s, 8, 64);
    s += __shfl_xor(s, 16, 64);
    s += __shfl_xor(s, 32, 64);
    float rs = 1.f / (s + 1e-16f);
    float rsF = bperm_f(jb, rs);
    float o0 = a0 * rsF + bias[2 * lane];
    float o1 = a1 * rsF + bias[2 * lane + 1];
    if (DO_ELU) {
        o0 = o0 > 0.f ? o0 : __expf(o0) - 1.f;
        o1 = o1 > 0.f ? o1 : __expf(o1) - 1.f;
    }
    unsigned packed = (unsigned)bf_bits(o0) | ((unsigned)bf_bits(o1) << 16);
    ((unsigned*)outb)[(size_t)n * 64 + lane] = packed;  // row = 128 shorts = 64 uints
}

// ---------------- single-pass aggregation, H=8 C=8 (layer 2) ----------------
// Two 32-lane halves each gather one edge row (128B) per inner step.
template <bool DO_ELU>
__global__ void agg8c8_k(const unsigned short* __restrict__ xpb,
                         const float* __restrict__ asrc, const float* __restrict__ adst,
                         const int* __restrict__ offs, const int* __restrict__ cols,
                         const float* __restrict__ bias, unsigned short* __restrict__ outb,
                         int N) {
    int gtid = blockIdx.x * blockDim.x + threadIdx.x;
    int n = gtid >> 6;
    if (n >= N) return;
    int lane = threadIdx.x & 63;
    int j = lane >> 3, h = lane & 7;
    int start = offs[n], end = offs[n + 1];
    const unsigned* xp32 = (const unsigned*)xpb;

    int fp = lane & 31;      // feature pair {2fp, 2fp+1}
    int hF = fp >> 2;        // feature-role head
    int half = lane >> 5;
    int sbase = half * 32;

    float ad_l = adst[n * 8 + h];
    float vs = asrc[n * 8 + h] + ad_l;
    vs = LEAKY(vs);

    float m_w = vs;
    float s = (j == 0) ? 1.f : 0.f;
    float m_f = bperm_f(hF * 4, vs);
    float a0 = 0.f, a1 = 0.f;
    if (half == 0) {  // self contribution in half 0 only
        unsigned u = xp32[(size_t)n * 32 + fp];
        a0 = __uint_as_float(u << 16);
        a1 = __uint_as_float(u & 0xffff0000u);
    }

    for (int c0 = start; c0 < end; c0 += 8) {
        int e = c0 + j;
        bool valid = e < end;
        int src_l = valid ? cols[e] : 0;
        float v = -1e30f;
        if (valid) {
            v = asrc[src_l * 8 + h] + ad_l;
            v = LEAKY(v);
        }
        float cm = v;
        cm = fmaxf(cm, __shfl_xor(cm, 8, 64));
        cm = fmaxf(cm, __shfl_xor(cm, 16, 64));
        cm = fmaxf(cm, __shfl_xor(cm, 32, 64));
        float mw_new = fmaxf(m_w, cm);
        float w_raw = __expf(v - mw_new);
        s = s * __expf(m_w - mw_new) + w_raw;
        m_w = mw_new;
        float cmF = bperm_f(hF * 4, cm);
        float mf_new = fmaxf(m_f, cmF);
        float scF = __expf(m_f - mf_new);
        m_f = mf_new;
        a0 *= scF; a1 *= scF;
        // 4 pairs x 2 halves = 8 edges; invalid -> w=0
#pragma unroll
        for (int j2 = 0; j2 < 4; j2++) {
            int srcv = __builtin_amdgcn_ds_bpermute(sbase + j2 * 64, src_l);
            float w = bperm_f(sbase + hF * 4 + j2 * 64, w_raw);
            unsigned u = xp32[(size_t)srcv * 32 + fp];
            a0 = fmaf(w, __uint_as_float(u << 16), a0);
            a1 = fmaf(w, __uint_as_float(u & 0xffff0000u), a1);
        }
    }
    s += __shfl_xor(s, 8, 64);
    s += __shfl_xor(s, 16, 64);
    s += __shfl_xor(s, 32, 64);
    float rs = 1.f / (s + 1e-16f);
    float rsF = bperm_f(hF * 4, rs);
    // combine halves (same m_f in both halves), then normalize
    a0 += __shfl_xor(a0, 32, 64);
    a1 += __shfl_xor(a1, 32, 64);
    if (half == 0) {
        float o0 = a0 * rsF + bias[2 * fp];
        float o1 = a1 * rsF + bias[2 * fp + 1];
        if (DO_ELU) {
            o0 = o0 > 0.f ? o0 : __expf(o0) - 1.f;
            o1 = o1 > 0.f ? o1 : __expf(o1) - 1.f;
        }
        unsigned packed = (unsigned)bf_bits(o0) | ((unsigned)bf_bits(o1) << 16);
        ((unsigned*)outb)[(size_t)n * 32 + fp] = packed;  // row = 64 shorts = 32 uints
    }
}

// ---------------- aggregation H=1 C=10 + fused log_softmax (layer 3) ----------------
__global__ void agg1h_k(const unsigned short* __restrict__ xpb,
                        const float* __restrict__ asrc, const float* __restrict__ adst,
                        const int* __restrict__ offs, const int* __restrict__ cols,
                        const float* __restrict__ bias, float* __restrict__ out, int N) {
    int gtid = blockIdx.x * blockDim.x + threadIdx.x;
    int n = gtid >> 6;
    if (n >= N) return;
    int lane = threadIdx.x & 63;
    int start = offs[n], end = offs[n + 1];
    float ad = adst[n];
    float vs = asrc[n] + ad;  // implicit self-loop
    vs = LEAKY(vs);

    float m, s;
    if (lane == 0) { m = vs; s = 1.f; } else { m = -1e30f; s = 0.f; }
    for (int e = start + lane; e < end; e += 64) {
        float v = asrc[cols[e]] + ad;
        v = LEAKY(v);
        float mo = fmaxf(m, v);
        s = s * __expf(m - mo) + __expf(v - mo);
        m = mo;
    }
#pragma unroll
    for (int off = 1; off <= 32; off <<= 1) {
        float mo = __shfl_xor(m, off, 64);
        float so = __shfl_xor(s, off, 64);
        float mn = fmaxf(m, mo);
        s = s * __expf(m - mn) + so * __expf(mo - mn);
        m = mn;
    }
    float rs = 1.f / (s + 1e-16f);
    float wself = __expf(vs - m) * rs;

    int j = lane / 10, c = lane - j * 10;
    float acc = 0.f;
    if (j == 0) acc = wself * bf_to_f(xpb[(size_t)n * 10 + c]);  // self term
    for (int c0 = start; c0 < end; c0 += 6) {
        int e = c0 + j;
        if (j < 6 && e < end) {
            int src = cols[e];
            float v = asrc[src] + ad;
            v = LEAKY(v);
            float w = __expf(v - m) * rs;
            acc = fmaf(w, bf_to_f(xpb[(size_t)src * 10 + c]), acc);
        }
    }
    float tot = acc;
#pragma unroll
    for (int k = 1; k < 6; k++) tot += __shfl(acc, lane + 10 * k, 64);

    // fused log_softmax over the 10 classes (valid in lanes 0-9)
    float z = tot + bias[lane < 10 ? lane : 0];
    float mx = -1e30f;
#pragma unroll
    for (int k = 0; k < 10; k++) mx = fmaxf(mx, __shfl(z, k, 64));
    float se = 0.f;
#pragma unroll
    for (int k = 0; k < 10; k++) se += __expf(__shfl(z, k, 64) - mx);
    if (lane < 10) out[(size_t)n * 10 + lane] = z - (__logf(se) + mx);
}

// ---------------- launch ----------------

static inline size_t alignup(size_t x) { return (x + 255) & ~(size_t)255; }

extern "C" void kernel_launch(void* const* d_in, const int* in_sizes, int n_in,
                              void* d_out, int out_size, void* d_ws, size_t ws_size,
                              hipStream_t stream) {
    const float* x   = (const float*)d_in[0];
    const int*   ei  = (const int*)d_in[1];
    const float* W1  = (const float*)d_in[2];
    const float* a1s = (const float*)d_in[3];
    const float* a1d = (const float*)d_in[4];
    const float* b1  = (const float*)d_in[5];
    const float* W2  = (const float*)d_in[6];
    const float* a2s = (const float*)d_in[7];
    const float* a2d = (const float*)d_in[8];
    const float* b2  = (const float*)d_in[9];
    const float* W3  = (const float*)d_in[10];
    const float* a3s = (const float*)d_in[11];
    const float* a3d = (const float*)d_in[12];
    const float* b3  = (const float*)d_in[13];
    float* out = (float*)d_out;

    const int N = in_sizes[0] / 256;
    const int E = in_sizes[1] / 2;
    const int* src = ei;
    const int* dst = ei + E;
    const int NB = (N + 255) >> 8;  // 391 for N=100000 (<= NB_MAX)

    char* p = (char*)d_ws;
    int* offs    = (int*)p; p += alignup(sizeof(int) * (size_t)(N + 1));
    int* bcur    = (int*)p; p += alignup(sizeof(int) * (size_t)(NB_MAX + 1));
    int* ebase   = (int*)p; p += alignup(sizeof(int) * (size_t)(NB_MAX + 1));
    int* cols    = (int*)p; p += alignup(sizeof(int) * (size_t)E);
    unsigned short* xpb   = (unsigned short*)p; p += alignup(2 * (size_t)N * 128);
    unsigned short* hbufb = (unsigned short*)p; p += alignup(2 * (size_t)N * 128);
    float* xp    = (float*)p; p += alignup(sizeof(float) * (size_t)N * 128);
    float* as_   = (float*)p; p += alignup(sizeof(float) * (size_t)N * 8);
    float* ad_   = (float*)p; p += alignup(sizeof(float) * (size_t)N * 8);
    short* Bf1   = (short*)p; p += alignup(sizeof(short) * 8 * 8 * 64 * 16);  // K=256,N=128
    short* Bf2   = (short*)p; p += alignup(sizeof(short) * 4 * 4 * 64 * 16);  // K=128,N=64
    // staged bucket regions alias xp: CSR build finishes before layer-3 writes xp.
    unsigned* staged = (unsigned*)xp;  // NB * BCAP * 4B = 8 MB << 51.2 MB

    const int TB = 256;

    // CSR build: bucketed counting sort (self-loops implicit in agg)
    zero_k<<<(NB + TB - 1) / TB, TB, 0, stream>>>(bcur, NB);
    partition_k<<<(E + 4095) / 4096, 256, 0, stream>>>(src, dst, E, NB, bcur, staged);
    scan_nb_k<<<1, 64, 0, stream>>>(bcur, ebase, NB);
    buildcsr_k<<<NB, 256, 0, stream>>>(staged, bcur, ebase, offs, cols, N, NB);

    // W pre-pack (fragment order, hi|lo)
    prep_w_k<<<(4096 + TB - 1) / TB, TB, 0, stream>>>(W1, Bf1, 256, 128, 8, 4096);
    prep_w_k<<<(1024 + TB - 1) / TB, TB, 0, stream>>>(W2, Bf2, 128, 64, 4, 1024);

    // ---- layer 1: 256 -> 128 (H=8, C=16), ELU
    mfma_gemm_k<128, 4, 4, 2, false, 16><<<dim3((N + 127) / 128, 1), 256, 0, stream>>>(
        x, Bf1, xpb, a1s, a1d, as_, ad_, N, 128, 256, 8);
    agg16_k<true><<<(N * 64 + TB - 1) / TB, TB, 0, stream>>>(
        xpb, as_, ad_, offs, cols, b1, hbufb, N);

    // ---- layer 2: 128 -> 64 (H=8, C=8), ELU  (A is bf16 agg output)
    mfma_gemm_k<128, 2, 4, 4, true, 8><<<dim3((N + 127) / 128, 1), 256, 0, stream>>>(
        hbufb, Bf2, xpb, a2s, a2d, as_, ad_, N, 64, 128, 4);
    agg8c8_k<true><<<(N * 64 + TB - 1) / TB, TB, 0, stream>>>(
        xpb, as_, ad_, offs, cols, b2, hbufb, N);

    // ---- layer 3: 64 -> 10 (H=1, C=10) + fused log_softmax
    gemm_k<64, 16, 16, 4, 1><<<dim3((N + 63) / 64, 1), dim3(16, 16), 0, stream>>>(
        hbufb, W3, xp, xpb, N, 10, 64);
    alpha_k<1, 10><<<(N + TB - 1) / TB, TB, 0, stream>>>(xp, a3s, a3d, as_, ad_, N);
    agg1h_k<<<(N * 64 + TB - 1) / TB, TB, 0, stream>>>(
        xpb, as_, ad_, offs, cols, b3, out, N);
}

// Round 9
// 506.966 us; speedup vs baseline: 2.6429x; 1.0425x over previous
//
#include <hip/hip_runtime.h>
#include <hip/hip_bf16.h>
#include <math.h>

// ---------------------------------------------------------------------------
// GAT 3-layer forward on MI355X.
//   1. Dest-CSR via 2-pass bucketed counting sort (coalesced writes).
//      Self-loops are implicit in the aggregation kernels.
//   2. Layers 1-2: split-bf16 MFMA GEMM with alpha_src/dst FUSED into the
//      epilogue; writes bf16 C only. R9: BM=64 tiles (grid 1563, ~5 blk/CU)
//      — R8 showed BM=128 was occupancy/latency-bound (22% occ, MFMA 7.7%).
//      Layer 3: f32 vector GEMM (tiny).
//   3. Single-pass online-softmax aggregation (one walk of cols/asrc,
//      unnormalized accumulate, divide at end). Layer-3 agg fuses
//      log_softmax -> d_out.
// ---------------------------------------------------------------------------

#define LEAKY(v) ((v) > 0.f ? (v) : 0.2f * (v))

typedef __bf16 bf16_t;
typedef __bf16 bf16x8 __attribute__((ext_vector_type(8)));
typedef __bf16 bf16x4 __attribute__((ext_vector_type(4)));
typedef float f32x4 __attribute__((ext_vector_type(4)));

static __device__ __forceinline__ unsigned short bf_bits(float f) {
    bf16_t b = (bf16_t)f;
    return __builtin_bit_cast(unsigned short, b);
}
static __device__ __forceinline__ float bf_to_f(unsigned short u) {
    return __uint_as_float(((unsigned int)u) << 16);
}
static __device__ __forceinline__ float bperm_f(int byteaddr, float v) {
    return __uint_as_float((unsigned)__builtin_amdgcn_ds_bpermute(byteaddr, (int)__float_as_uint(v)));
}

// ---------------- CSR build: 2-pass bucket sort ----------------
constexpr int NB_MAX = 400;
constexpr int BCAP = 5120;  // capacity per bucket region; mean load 4096

__global__ void zero_k(int* a, int n) {
    int i = blockIdx.x * blockDim.x + threadIdx.x;
    if (i < n) a[i] = 0;
}

// Pass 1: partition edges into bucket regions with block-local grouping.
__global__ __launch_bounds__(256) void partition_k(
        const int* __restrict__ src, const int* __restrict__ dst, int E, int NB,
        int* __restrict__ bcur, unsigned* __restrict__ staged) {
    __shared__ int hist[NB_MAX];
    __shared__ int bstart[NB_MAX + 1];
    __shared__ int cur[NB_MAX];
    __shared__ int gbase[NB_MAX];
    __shared__ unsigned words[4096];
    __shared__ unsigned short bidl[4096];
    int tid = threadIdx.x;
    int e0 = blockIdx.x * 4096;
    int cnt = E - e0; if (cnt > 4096) cnt = 4096;
    if (cnt <= 0) return;

    for (int b = tid; b < NB; b += 256) hist[b] = 0;
    __syncthreads();
    for (int i = tid; i < cnt; i += 256) atomicAdd(&hist[dst[e0 + i] >> 8], 1);
    __syncthreads();
    if (tid == 0) {
        int run = 0;
        for (int b = 0; b < NB; b++) { bstart[b] = run; run += hist[b]; }
        bstart[NB] = run;
    }
    __syncthreads();
    for (int b = tid; b < NB; b += 256) {
        cur[b] = bstart[b];
        gbase[b] = hist[b] ? atomicAdd(&bcur[b], hist[b]) : 0;
    }
    __syncthreads();
    // group into LDS by bucket, remember bucket id per slot
    for (int i = tid; i < cnt; i += 256) {
        int s = src[e0 + i], d = dst[e0 + i];
        int b = d >> 8;
        unsigned w = (unsigned)s | ((unsigned)(d & 255) << 17);
        int p = atomicAdd(&cur[b], 1);
        words[p] = w;
        bidl[p] = (unsigned short)b;
    }
    __syncthreads();
    // linear sweep -> coalesced runs into global bucket regions
    for (int i = tid; i < cnt; i += 256) {
        int b = bidl[i];
        staged[(size_t)b * BCAP + gbase[b] + (i - bstart[b])] = words[i];
    }
}

// tiny exclusive scan over NB bucket counts (one wave)
__global__ void scan_nb_k(const int* __restrict__ bcur, int* __restrict__ ebase, int NB) {
    int lane = threadIdx.x;  // 64 threads
    int CH = (NB + 63) / 64;
    int b0 = lane * CH;
    int v[8]; int s = 0;
#pragma unroll 8
    for (int k = 0; k < CH; k++) { int b = b0 + k; int t = (b < NB) ? bcur[b] : 0; if (k < 8) v[k] = t; s += t; }
    int orig = s;
    for (int off = 1; off < 64; off <<= 1) {
        int t = __shfl_up(s, off, 64);
        if (lane >= off) s += t;
    }
    int run = s - orig;  // exclusive
    for (int k = 0; k < CH; k++) { int b = b0 + k; if (b < NB) { ebase[b] = run; run += v[k]; } }
    if (lane == 63) ebase[NB] = run;
}

// Pass 2: per-bucket node-level counting sort -> offs + cols (coalesced writes).
__global__ __launch_bounds__(256) void buildcsr_k(
        const unsigned* __restrict__ staged, const int* __restrict__ bcur,
        const int* __restrict__ ebase, int* __restrict__ offs, int* __restrict__ cols,
        int N, int NB) {
    __shared__ int h[256], hs[256], curl[256];
    __shared__ int colsl[BCAP];
    int b = blockIdx.x, tid = threadIdx.x;
    int n0 = b << 8;
    int ecnt = bcur[b];
    int base_g = ebase[b];
    const unsigned* sb = staged + (size_t)b * BCAP;

    h[tid] = 0;
    __syncthreads();
    for (int i = tid; i < ecnt; i += 256) atomicAdd(&h[sb[i] >> 17], 1);
    __syncthreads();
    int val = h[tid];
    hs[tid] = val; __syncthreads();
    for (int off = 1; off < 256; off <<= 1) {
        int t = (tid >= off) ? hs[tid - off] : 0;
        __syncthreads();
        hs[tid] += t;
        __syncthreads();
    }
    int excl = hs[tid] - val;
    curl[tid] = excl;
    if (n0 + tid < N) offs[n0 + tid] = base_g + excl;
    if (b == NB - 1 && tid == 0) offs[N] = base_g + ecnt;
    __syncthreads();
    for (int i = tid; i < ecnt; i += 256) {
        unsigned w = sb[i];
        int p = atomicAdd(&curl[w >> 17], 1);
        colsl[p] = (int)(w & 0x1FFFFu);
    }
    __syncthreads();
    for (int i = tid; i < ecnt; i += 256) cols[base_g + i] = colsl[i];
}

// ---------------- W pre-pack into MFMA B-fragment order (hi|lo) ----------------
__global__ void prep_w_k(const float* __restrict__ W, short* __restrict__ Bfs,
                         int K, int N, int NT, int total) {
    int idx = blockIdx.x * blockDim.x + threadIdx.x;
    if (idx >= total) return;  // total = (K/32)*NT*64
    int lane = idx & 63;
    int t = idx >> 6;
    int ntile = t % NT, kstep = t / NT;
    int quad = lane >> 4, nl = lane & 15;
    int n = ntile * 16 + nl;
    bf16_t* dst = (bf16_t*)Bfs + (size_t)idx * 16;
#pragma unroll
    for (int j = 0; j < 8; j++) {
        int k = kstep * 32 + quad * 8 + j;
        float v = W[k * N + n];
        bf16_t h = (bf16_t)v;
        bf16_t l = (bf16_t)(v - (float)h);
        dst[j] = h;
        dst[8 + j] = l;
    }
}

// ---------------- split-bf16 MFMA GEMM, fused alpha epilogue ----------------
// Writes Cb (bf16) + alpha_src/alpha_dst [M, N/CHEAD] (f32, exact from acc).
template <int BM, int WMT, int WNT, int NWM, bool ABF16, int CHEAD>
__global__ __launch_bounds__(256) void mfma_gemm_k(
        const void* __restrict__ Av, const short* __restrict__ Bfs,
        unsigned short* __restrict__ Cb,
        const float* __restrict__ a_s, const float* __restrict__ a_d,
        float* __restrict__ out_as, float* __restrict__ out_ad,
        int M, int N, int K, int NT) {
    constexpr int NWN = 4 / NWM;
    constexpr int BN = 16 * WNT * NWN;
    constexpr int KPAD = 40;  // 32 + 8: breaks LDS bank aliasing on b128 reads
    __shared__ __align__(16) bf16_t As_hi[BM * KPAD];
    __shared__ __align__(16) bf16_t As_lo[ABF16 ? 16 : BM * KPAD];
    const bf16_t* Bf = (const bf16_t*)Bfs;

    int tid = threadIdx.x;
    int wave = tid >> 6, lane = tid & 63;
    int quad = lane >> 4, l16 = lane & 15;
    int wm = wave % NWM, wn = wave / NWM;
    int row0 = blockIdx.x * BM;
    int ntile0 = blockIdx.y * (BN / 16) + wn * WNT;

    f32x4 acc[WMT][WNT];
#pragma unroll
    for (int i = 0; i < WMT; i++)
#pragma unroll
        for (int j = 0; j < WNT; j++) acc[i][j] = (f32x4){0.f, 0.f, 0.f, 0.f};

    const int nk = K >> 5;
    const int rA = tid >> 3, kq = tid & 7;  // 8 threads/row, 32 rows/pass

    for (int ks = 0; ks < nk; ks++) {
#pragma unroll
        for (int rr = rA; rr < BM; rr += 32) {
            int grow = row0 + rr;
            if (!ABF16) {
                const float* A = (const float*)Av;
                f32x4 v = (f32x4){0.f, 0.f, 0.f, 0.f};
                if (grow < M)
                    v = *(const f32x4*)(A + (size_t)grow * K + ks * 32 + kq * 4);
                bf16x4 h, l;
#pragma unroll
                for (int j = 0; j < 4; j++) {
                    bf16_t hh = (bf16_t)v[j];
                    h[j] = hh;
                    l[j] = (bf16_t)(v[j] - (float)hh);
                }
                *(bf16x4*)&As_hi[rr * KPAD + kq * 4] = h;
                *(bf16x4*)&As_lo[rr * KPAD + kq * 4] = l;
            } else {
                const unsigned short* A = (const unsigned short*)Av;
                ushort4 v = make_ushort4(0, 0, 0, 0);
                if (grow < M)
                    v = *(const ushort4*)(A + (size_t)grow * K + ks * 32 + kq * 4);
                *(ushort4*)&As_hi[rr * KPAD + kq * 4] = v;
            }
        }
        __syncthreads();

        bf16x8 ah[WMT], al[WMT];
#pragma unroll
        for (int i = 0; i < WMT; i++) {
            int rowl = wm * (WMT * 16) + i * 16 + l16;
            ah[i] = *(const bf16x8*)&As_hi[rowl * KPAD + quad * 8];
            if (!ABF16) al[i] = *(const bf16x8*)&As_lo[rowl * KPAD + quad * 8];
        }
        bf16x8 bh[WNT], bl[WNT];
#pragma unroll
        for (int j = 0; j < WNT; j++) {
            size_t base = ((size_t)(ks * NT + ntile0 + j) * 64 + lane) * 16;
            bh[j] = *(const bf16x8*)&Bf[base];
            bl[j] = *(const bf16x8*)&Bf[base + 8];
        }
#pragma unroll
        for (int i = 0; i < WMT; i++)
#pragma unroll
            for (int j = 0; j < WNT; j++) {
                acc[i][j] = __builtin_amdgcn_mfma_f32_16x16x32_bf16(ah[i], bh[j], acc[i][j], 0, 0, 0);
                if (!ABF16)
                    acc[i][j] = __builtin_amdgcn_mfma_f32_16x16x32_bf16(al[i], bh[j], acc[i][j], 0, 0, 0);
                acc[i][j] = __builtin_amdgcn_mfma_f32_16x16x32_bf16(ah[i], bl[j], acc[i][j], 0, 0, 0);
            }
        __syncthreads();
    }

    // bf16 C store: D[row = quad*4 + r][col = l16] per 16x16 tile
#pragma unroll
    for (int i = 0; i < WMT; i++) {
        int rbase = row0 + wm * (WMT * 16) + i * 16 + quad * 4;
#pragma unroll
        for (int j = 0; j < WNT; j++) {
            int gcol = (ntile0 + j) * 16 + l16;
#pragma unroll
            for (int r2 = 0; r2 < 4; r2++) {
                int grow = rbase + r2;
                if (grow < M) Cb[(size_t)grow * N + gcol] = bf_bits(acc[i][j][r2]);
            }
        }
    }

    // fused alpha: per tile j, coef = a_flat[gcol]; reduce over CHEAD-lane groups
    const int Hh = N / CHEAD;
#pragma unroll
    for (int j = 0; j < WNT; j++) {
        int gcol = (ntile0 + j) * 16 + l16;
        float cs = a_s[gcol], cd = a_d[gcol];
#pragma unroll
        for (int i = 0; i < WMT; i++) {
            float ps[4], pd[4];
#pragma unroll
            for (int r2 = 0; r2 < 4; r2++) {
                ps[r2] = acc[i][j][r2] * cs;
                pd[r2] = acc[i][j][r2] * cd;
            }
#pragma unroll
            for (int off = 1; off < CHEAD; off <<= 1) {
#pragma unroll
                for (int r2 = 0; r2 < 4; r2++) {
                    ps[r2] += __shfl_xor(ps[r2], off, 64);
                    pd[r2] += __shfl_xor(pd[r2], off, 64);
                }
            }
            if ((l16 & (CHEAD - 1)) == 0) {
                int hd = gcol / CHEAD;
                int rb = row0 + wm * (WMT * 16) + i * 16 + quad * 4;
#pragma unroll
                for (int r2 = 0; r2 < 4; r2++) {
                    int grow = rb + r2;
                    if (grow < M) {
                        out_as[(size_t)grow * Hh + hd] = ps[r2];
                        out_ad[(size_t)grow * Hh + hd] = pd[r2];
                    }
                }
            }
        }
    }
}

// ---------------- GEMM (f32 vector, bf16 A) — layer 3 only ----------------
template <int BM, int BN, int BK, int TM, int TN>
__global__ void gemm_k(const unsigned short* __restrict__ Ab, const float* __restrict__ B,
                       float* __restrict__ C, unsigned short* __restrict__ Cb,
                       int M, int Nc, int K) {
    __shared__ float As[BK][BM + 1];
    __shared__ float Bs[BK][BN + 1];
    int tx = threadIdx.x, ty = threadIdx.y;
    int tid = ty * blockDim.x + tx;
    const int nthreads = (BM / TM) * (BN / TN);
    int row0 = blockIdx.x * BM, col0 = blockIdx.y * BN;
    float acc[TM][TN];
#pragma unroll
    for (int i = 0; i < TM; i++)
#pragma unroll
        for (int j = 0; j < TN; j++) acc[i][j] = 0.f;

    for (int k0 = 0; k0 < K; k0 += BK) {
        for (int i = tid; i < BM * BK; i += nthreads) {
            int r = i / BK, kk = i % BK;
            int gr = row0 + r;
            As[kk][r] = (gr < M) ? bf_to_f(Ab[(size_t)gr * K + (k0 + kk)]) : 0.f;
        }
        for (int i = tid; i < BK * BN; i += nthreads) {
            int kk = i / BN, c = i % BN;
            int gc = col0 + c;
            Bs[kk][c] = (gc < Nc) ? B[(long)(k0 + kk) * Nc + gc] : 0.f;
        }
        __syncthreads();
#pragma unroll
        for (int kk = 0; kk < BK; ++kk) {
            float a[TM], b[TN];
#pragma unroll
            for (int i = 0; i < TM; i++) a[i] = As[kk][ty * TM + i];
#pragma unroll
            for (int j = 0; j < TN; j++) b[j] = Bs[kk][tx * TN + j];
#pragma unroll
            for (int i = 0; i < TM; i++)
#pragma unroll
                for (int j = 0; j < TN; j++) acc[i][j] = fmaf(a[i], b[j], acc[i][j]);
        }
        __syncthreads();
    }
#pragma unroll
    for (int i = 0; i < TM; i++) {
        int gr = row0 + ty * TM + i;
        if (gr >= M) continue;
#pragma unroll
        for (int j = 0; j < TN; j++) {
            int gc = col0 + tx * TN + j;
            if (gc < Nc) {
                C[(long)gr * Nc + gc] = acc[i][j];
                Cb[(long)gr * Nc + gc] = bf_bits(acc[i][j]);
            }
        }
    }
}

// ---------------- alpha (layer 3 only) ----------------
template <int H, int C>
__global__ void alpha_k(const float* __restrict__ xp, const float* __restrict__ a_s,
                        const float* __restrict__ a_d, float* __restrict__ out_s,
                        float* __restrict__ out_d, int NH) {
    int i = blockIdx.x * blockDim.x + threadIdx.x;
    if (i >= NH) return;
    int h = i % H;
    const float* v = xp + (long)i * C;
    float ss = 0.f, sd = 0.f;
#pragma unroll
    for (int c = 0; c < C; c++) {
        float x = v[c];
        ss = fmaf(x, a_s[h * C + c], ss);
        sd = fmaf(x, a_d[h * C + c], sd);
    }
    out_s[i] = ss;
    out_d[i] = sd;
}

// ---------------- single-pass aggregation, H=8 C=16 (layer 1) ----------------
template <bool DO_ELU>
__global__ void agg16_k(const unsigned short* __restrict__ xpb,
                        const float* __restrict__ asrc, const float* __restrict__ adst,
                        const int* __restrict__ offs, const int* __restrict__ cols,
                        const float* __restrict__ bias, unsigned short* __restrict__ outb,
                        int N) {
    int gtid = blockIdx.x * blockDim.x + threadIdx.x;
    int n = gtid >> 6;
    if (n >= N) return;
    int lane = threadIdx.x & 63;
    int j = lane >> 3, h = lane & 7;
    const int jb = j << 2;  // bpermute byte addr of (j=0, h=j) lane
    int start = offs[n], end = offs[n + 1];
    const unsigned* xp32 = (const unsigned*)xpb;

    float ad_l = adst[n * 8 + h];
    float vs = asrc[n * 8 + h] + ad_l;
    vs = LEAKY(vs);

    // weight-role state (head h): seeded with implicit self-loop
    float m_w = vs;
    float s = (j == 0) ? 1.f : 0.f;
    // feature-role state (head j): acc = self row (weight exp(vs-vs)=1)
    float m_f = bperm_f(jb, vs);
    unsigned uself = xp32[(size_t)n * 64 + lane];
    float a0 = __uint_as_float(uself << 16);
    float a1 = __uint_as_float(uself & 0xffff0000u);

    for (int c0 = start; c0 < end; c0 += 8) {
        int e = c0 + j;
        bool valid = e < end;
        int src_l = valid ? cols[e] : 0;
        float v = -1e30f;
        if (valid) {
            v = asrc[src_l * 8 + h] + ad_l;
            v = LEAKY(v);
        }
        // chunk max over j (per head h)
        float cm = v;
        cm = fmaxf(cm, __shfl_xor(cm, 8, 64));
        cm = fmaxf(cm, __shfl_xor(cm, 16, 64));
        cm = fmaxf(cm, __shfl_xor(cm, 32, 64));
        // weight-role update
        float mw_new = fmaxf(m_w, cm);
        float w_raw = __expf(v - mw_new);  // 0 for invalid slots
        s = s * __expf(m_w - mw_new) + w_raw;
        m_w = mw_new;
        // feature-role rescale (head j)
        float cmF = bperm_f(jb, cm);
        float mf_new = fmaxf(m_f, cmF);
        float scF = __expf(m_f - mf_new);
        m_f = mf_new;
        a0 *= scF; a1 *= scF;
        // accumulate 8 edges (invalid -> w=0, gathers hot row 0)
#pragma unroll
        for (int j2 = 0; j2 < 8; j2++) {
            int srcj = __builtin_amdgcn_readlane(src_l, j2 * 8);
            float w = bperm_f(jb + j2 * 32, w_raw);
            unsigned u = xp32[(size_t)srcj * 64 + lane];
            a0 = fmaf(w, __uint_as_float(u << 16), a0);
            a1 = fmaf(w, __uint_as_float(u & 0xffff0000u), a1);
        }
    }
    // finalize: total s per head, then normalize
    s += __shfl_xor(s, 8, 64);
    s += __shfl_xor(s, 16, 64);
    s += __shfl_xor(s, 32, 64);
    float rs = 1.f / (s + 1e-16f);
    float rsF = bperm_f(jb, rs);
    float o0 = a0 * rsF + bias[2 * lane];
    float o1 = a1 * rsF + bias[2 * lane + 1];
    if (DO_ELU) {
        o0 = o0 > 0.f ? o0 : __expf(o0) - 1.f;
        o1 = o1 > 0.f ? o1 : __expf(o1) - 1.f;
    }
    unsigned packed = (unsigned)bf_bits(o0) | ((unsigned)bf_bits(o1) << 16);
    ((unsigned*)outb)[(size_t)n * 64 + lane] = packed;  // row = 128 shorts = 64 uints
}

// ---------------- single-pass aggregation, H=8 C=8 (layer 2) ----------------
template <bool DO_ELU>
__global__ void agg8c8_k(const unsigned short* __restrict__ xpb,
                         const float* __restrict__ asrc, const float* __restrict__ adst,
                         const int* __restrict__ offs, const int* __restrict__ cols,
                         const float* __restrict__ bias, unsigned short* __restrict__ outb,
                         int N) {
    int gtid = blockIdx.x * blockDim.x + threadIdx.x;
    int n = gtid >> 6;
    if (n >= N) return;
    int lane = threadIdx.x & 63;
    int j = lane >> 3, h = lane & 7;
    int start = offs[n], end = offs[n + 1];
    const unsigned* xp32 = (const unsigned*)xpb;

    int fp = lane & 31;      // feature pair {2fp, 2fp+1}
    int hF = fp >> 2;        // feature-role head
    int half = lane >> 5;
    int sbase = half * 32;

    float ad_l = adst[n * 8 + h];
    float vs = asrc[n * 8 + h] + ad_l;
    vs = LEAKY(vs);

    float m_w = vs;
    float s = (j == 0) ? 1.f : 0.f;
    float m_f = bperm_f(hF * 4, vs);
    float a0 = 0.f, a1 = 0.f;
    if (half == 0) {  // self contribution in half 0 only
        unsigned u = xp32[(size_t)n * 32 + fp];
        a0 = __uint_as_float(u << 16);
        a1 = __uint_as_float(u & 0xffff0000u);
    }

    for (int c0 = start; c0 < end; c0 += 8) {
        int e = c0 + j;
        bool valid = e < end;
        int src_l = valid ? cols[e] : 0;
        float v = -1e30f;
        if (valid) {
            v = asrc[src_l * 8 + h] + ad_l;
            v = LEAKY(v);
        }
        float cm = v;
        cm = fmaxf(cm, __shfl_xor(cm, 8, 64));
        cm = fmaxf(cm, __shfl_xor(cm, 16, 64));
        cm = fmaxf(cm, __shfl_xor(cm, 32, 64));
        float mw_new = fmaxf(m_w, cm);
        float w_raw = __expf(v - mw_new);
        s = s * __expf(m_w - mw_new) + w_raw;
        m_w = mw_new;
        float cmF = bperm_f(hF * 4, cm);
        float mf_new = fmaxf(m_f, cmF);
        float scF = __expf(m_f - mf_new);
        m_f = mf_new;
        a0 *= scF; a1 *= scF;
        // 4 pairs x 2 halves = 8 edges; invalid -> w=0
#pragma unroll
        for (int j2 = 0; j2 < 4; j2++) {
            int srcv = __builtin_amdgcn_ds_bpermute(sbase + j2 * 64, src_l);
            float w = bperm_f(sbase + hF * 4 + j2 * 64, w_raw);
            unsigned u = xp32[(size_t)srcv * 32 + fp];
            a0 = fmaf(w, __uint_as_float(u << 16), a0);
            a1 = fmaf(w, __uint_as_float(u & 0xffff0000u), a1);
        }
    }
    s += __shfl_xor(s, 8, 64);
    s += __shfl_xor(s, 16, 64);
    s += __shfl_xor(s, 32, 64);
    float rs = 1.f / (s + 1e-16f);
    float rsF = bperm_f(hF * 4, rs);
    // combine halves (same m_f in both halves), then normalize
    a0 += __shfl_xor(a0, 32, 64);
    a1 += __shfl_xor(a1, 32, 64);
    if (half == 0) {
        float o0 = a0 * rsF + bias[2 * fp];
        float o1 = a1 * rsF + bias[2 * fp + 1];
        if (DO_ELU) {
            o0 = o0 > 0.f ? o0 : __expf(o0) - 1.f;
            o1 = o1 > 0.f ? o1 : __expf(o1) - 1.f;
        }
        unsigned packed = (unsigned)bf_bits(o0) | ((unsigned)bf_bits(o1) << 16);
        ((unsigned*)outb)[(size_t)n * 32 + fp] = packed;  // row = 64 shorts = 32 uints
    }
}

// ---------------- aggregation H=1 C=10 + fused log_softmax (layer 3) ----------------
__global__ void agg1h_k(const unsigned short* __restrict__ xpb,
                        const float* __restrict__ asrc, const float* __restrict__ adst,
                        const int* __restrict__ offs, const int* __restrict__ cols,
                        const float* __restrict__ bias, float* __restrict__ out, int N) {
    int gtid = blockIdx.x * blockDim.x + threadIdx.x;
    int n = gtid >> 6;
    if (n >= N) return;
    int lane = threadIdx.x & 63;
    int start = offs[n], end = offs[n + 1];
    float ad = adst[n];
    float vs = asrc[n] + ad;  // implicit self-loop
    vs = LEAKY(vs);

    float m, s;
    if (lane == 0) { m = vs; s = 1.f; } else { m = -1e30f; s = 0.f; }
    for (int e = start + lane; e < end; e += 64) {
        float v = asrc[cols[e]] + ad;
        v = LEAKY(v);
        float mo = fmaxf(m, v);
        s = s * __expf(m - mo) + __expf(v - mo);
        m = mo;
    }
#pragma unroll
    for (int off = 1; off <= 32; off <<= 1) {
        float mo = __shfl_xor(m, off, 64);
        float so = __shfl_xor(s, off, 64);
        float mn = fmaxf(m, mo);
        s = s * __expf(m - mn) + so * __expf(mo - mn);
        m = mn;
    }
    float rs = 1.f / (s + 1e-16f);
    float wself = __expf(vs - m) * rs;

    int j = lane / 10, c = lane - j * 10;
    float acc = 0.f;
    if (j == 0) acc = wself * bf_to_f(xpb[(size_t)n * 10 + c]);  // self term
    for (int c0 = start; c0 < end; c0 += 6) {
        int e = c0 + j;
        if (j < 6 && e < end) {
            int src = cols[e];
            float v = asrc[src] + ad;
            v = LEAKY(v);
            float w = __expf(v - m) * rs;
            acc = fmaf(w, bf_to_f(xpb[(size_t)src * 10 + c]), acc);
        }
    }
    float tot = acc;
#pragma unroll
    for (int k = 1; k < 6; k++) tot += __shfl(acc, lane + 10 * k, 64);

    // fused log_softmax over the 10 classes (valid in lanes 0-9)
    float z = tot + bias[lane < 10 ? lane : 0];
    float mx = -1e30f;
#pragma unroll
    for (int k = 0; k < 10; k++) mx = fmaxf(mx, __shfl(z, k, 64));
    float se = 0.f;
#pragma unroll
    for (int k = 0; k < 10; k++) se += __expf(__shfl(z, k, 64) - mx);
    if (lane < 10) out[(size_t)n * 10 + lane] = z - (__logf(se) + mx);
}

// ---------------- launch ----------------

static inline size_t alignup(size_t x) { return (x + 255) & ~(size_t)255; }

extern "C" void kernel_launch(void* const* d_in, const int* in_sizes, int n_in,
                              void* d_out, int out_size, void* d_ws, size_t ws_size,
                              hipStream_t stream) {
    const float* x   = (const float*)d_in[0];
    const int*   ei  = (const int*)d_in[1];
    const float* W1  = (const float*)d_in[2];
    const float* a1s = (const float*)d_in[3];
    const float* a1d = (const float*)d_in[4];
    const float* b1  = (const float*)d_in[5];
    const float* W2  = (const float*)d_in[6];
    const float* a2s = (const float*)d_in[7];
    const float* a2d = (const float*)d_in[8];
    const float* b2  = (const float*)d_in[9];
    const float* W3  = (const float*)d_in[10];
    const float* a3s = (const float*)d_in[11];
    const float* a3d = (const float*)d_in[12];
    const float* b3  = (const float*)d_in[13];
    float* out = (float*)d_out;

    const int N = in_sizes[0] / 256;
    const int E = in_sizes[1] / 2;
    const int* src = ei;
    const int* dst = ei + E;
    const int NB = (N + 255) >> 8;  // 391 for N=100000 (<= NB_MAX)

    char* p = (char*)d_ws;
    int* offs    = (int*)p; p += alignup(sizeof(int) * (size_t)(N + 1));
    int* bcur    = (int*)p; p += alignup(sizeof(int) * (size_t)(NB_MAX + 1));
    int* ebase   = (int*)p; p += alignup(sizeof(int) * (size_t)(NB_MAX + 1));
    int* cols    = (int*)p; p += alignup(sizeof(int) * (size_t)E);
    unsigned short* xpb   = (unsigned short*)p; p += alignup(2 * (size_t)N * 128);
    unsigned short* hbufb = (unsigned short*)p; p += alignup(2 * (size_t)N * 128);
    float* xp    = (float*)p; p += alignup(sizeof(float) * (size_t)N * 128);
    float* as_   = (float*)p; p += alignup(sizeof(float) * (size_t)N * 8);
    float* ad_   = (float*)p; p += alignup(sizeof(float) * (size_t)N * 8);
    short* Bf1   = (short*)p; p += alignup(sizeof(short) * 8 * 8 * 64 * 16);  // K=256,N=128
    short* Bf2   = (short*)p; p += alignup(sizeof(short) * 4 * 4 * 64 * 16);  // K=128,N=64
    // staged bucket regions alias xp: CSR build finishes before layer-3 writes xp.
    unsigned* staged = (unsigned*)xp;  // NB * BCAP * 4B = 8 MB << 51.2 MB

    const int TB = 256;

    // CSR build: bucketed counting sort (self-loops implicit in agg)
    zero_k<<<(NB + TB - 1) / TB, TB, 0, stream>>>(bcur, NB);
    partition_k<<<(E + 4095) / 4096, 256, 0, stream>>>(src, dst, E, NB, bcur, staged);
    scan_nb_k<<<1, 64, 0, stream>>>(bcur, ebase, NB);
    buildcsr_k<<<NB, 256, 0, stream>>>(staged, bcur, ebase, offs, cols, N, NB);

    // W pre-pack (fragment order, hi|lo)
    prep_w_k<<<(4096 + TB - 1) / TB, TB, 0, stream>>>(W1, Bf1, 256, 128, 8, 4096);
    prep_w_k<<<(1024 + TB - 1) / TB, TB, 0, stream>>>(W2, Bf2, 128, 64, 4, 1024);

    // ---- layer 1: 256 -> 128 (H=8, C=16), ELU
    // BM=64 tile: grid 1563 -> ~5 blocks/CU co-resident (R8: BM=128 was 22% occ)
    mfma_gemm_k<64, 2, 4, 2, false, 16><<<dim3((N + 63) / 64, 1), 256, 0, stream>>>(
        x, Bf1, xpb, a1s, a1d, as_, ad_, N, 128, 256, 8);
    agg16_k<true><<<(N * 64 + TB - 1) / TB, TB, 0, stream>>>(
        xpb, as_, ad_, offs, cols, b1, hbufb, N);

    // ---- layer 2: 128 -> 64 (H=8, C=8), ELU  (A is bf16 agg output)
    mfma_gemm_k<64, 2, 2, 2, true, 8><<<dim3((N + 63) / 64, 1), 256, 0, stream>>>(
        hbufb, Bf2, xpb, a2s, a2d, as_, ad_, N, 64, 128, 4);
    agg8c8_k<true><<<(N * 64 + TB - 1) / TB, TB, 0, stream>>>(
        xpb, as_, ad_, offs, cols, b2, hbufb, N);

    // ---- layer 3: 64 -> 10 (H=1, C=10) + fused log_softmax
    gemm_k<64, 16, 16, 4, 1><<<dim3((N + 63) / 64, 1), dim3(16, 16), 0, stream>>>(
        hbufb, W3, xp, xpb, N, 10, 64);
    alpha_k<1, 10><<<(N + TB - 1) / TB, TB, 0, stream>>>(xp, a3s, a3d, as_, ad_, N);
    agg1h_k<<<(N * 64 + TB - 1) / TB, TB, 0, stream>>>(
        xpb, as_, ad_, offs, cols, b3, out, N);
}